// Round 1
// baseline (1103.190 us; speedup 1.0000x reference)
//
#include <hip/hip_runtime.h>
#include <math.h>

#define PI_D 3.14159265358979323846
#define PI_F 3.14159265358979f

#define BATCH 128
#define NM1 19    // retained m freqs for B1 (m in [-9,9])
#define NM2 11    // retained freqs for B2 (m in [-5,5])
#define NB_IN 60  // 2*B_IN
#define NB1 20    // 2*B1
#define NB2 12    // 2*B2
#define NL1 10    // B1
#define NL2 6     // B2
#define F1C 20
#define F2C 40

// constant tensor element counts
#define N_WDS2 (NL1*NB_IN*NM1)     // 11400 f32
#define N_Y1   (NL1*24*NM1)        // 4560 cplx
#define N_D1W  (NL1*NB1*NM1*NM1)   // 72200 f32
#define N_D12W (NL2*NB1*NM2*NM2)   // 14520 f32
#define N_D2   (NL2*144*NM2*NM2)   // 104544 cplx
#define N_D2W  (NL2*NB2*NM2*NM2)   // 8712 f32
#define N_W2N  (NB2)               // 12 f32

// ---------------- device helpers for Wigner-d (fp64, matches numpy trace-time math) ----------------
__device__ __forceinline__ double ipow_d(double x, int e) {
  double r = 1.0;
  for (int i = 0; i < e; ++i) r *= x;
  return r;
}

__device__ double wigd(const double* lf, int l, int m, int n, double beta) {
  if (m < -l || m > l || n < -l || n > l) return 0.0;
  double cb = cos(0.5*beta), sb = sin(0.5*beta);
  double pref = 0.5*(lf[l+m]+lf[l-m]+lf[l+n]+lf[l-n]);
  int s0 = (n-m) > 0 ? (n-m) : 0;
  int s1 = (l+n) < (l-m) ? (l+n) : (l-m);
  double acc = 0.0;
  for (int s = s0; s <= s1; ++s) {
    double lc = pref - (lf[l+n-s]+lf[s]+lf[m-n+s]+lf[l-m-s]);
    double t = exp(lc) * ipow_d(cb, 2*l+n-m-2*s) * ipow_d(sb, m-n+2*s);
    acc += ((m-n+s) & 1) ? -t : t;
  }
  return acc;
}

__device__ __forceinline__ double dh_beta_d(int b, int k) { return PI_D*(2*k+1)/(4.0*b); }

__device__ double dh_w_d(int b, int k) {
  double beta = dh_beta_d(b, k), s = 0.0;
  for (int j = 0; j < b; ++j) s += sin((2.0*j+1.0)*beta)/(2.0*j+1.0);
  return (2.0/b)*sin(beta)*s;
}

// ---------------- constants kernel ----------------
__global__ void k_consts(float* __restrict__ wd_s2, float2* __restrict__ Y1,
                         float* __restrict__ d1w, float* __restrict__ d12w,
                         float2* __restrict__ D2, float* __restrict__ d2w,
                         float* __restrict__ w2n) {
  __shared__ double lf[41];
  int t = threadIdx.x;
  if (t < 41) lf[t] = lgamma((double)t + 1.0);
  __syncthreads();
  int gid = blockIdx.x*blockDim.x + t;

  if (gid < N_WDS2) {
    int l = gid/(NB_IN*NM1); int r = gid%(NB_IN*NM1); int k = r/NM1; int mi = r%NM1;
    int m = mi - 9;
    wd_s2[gid] = (float)(dh_w_d(30,k) * wigd(lf, l, m, 0, dh_beta_d(30,k)));
    return;
  }
  gid -= N_WDS2;
  if (gid < N_Y1) {
    int l = gid/(24*NM1); int r = gid%(24*NM1); int p = r/NM1; int mi = r%NM1;
    int m = mi - 9;
    double beta  = (double)(p/8 + 1) * PI_D/24.0;
    double alpha = 2.0*PI_D*(double)(p%8)/8.0;
    double d = wigd(lf, l, m, 0, beta);
    double ph = -(double)m*alpha;
    Y1[gid] = make_float2((float)(d*cos(ph)), (float)(d*sin(ph)));
    return;
  }
  gid -= N_Y1;
  if (gid < N_D1W) {
    int l = gid/(NB1*NM1*NM1); int r = gid%(NB1*NM1*NM1); int j = r/(NM1*NM1); int rr = r%(NM1*NM1);
    int m = rr/NM1 - 9, n = rr%NM1 - 9;
    d1w[gid] = (float)((double)(2*l+1) * wigd(lf, l, m, n, dh_beta_d(10,j)));
    return;
  }
  gid -= N_D1W;
  if (gid < N_D12W) {
    int l = gid/(NB1*NM2*NM2); int r = gid%(NB1*NM2*NM2); int j = r/(NM2*NM2); int rr = r%(NM2*NM2);
    int m = rr/NM2 - 5, n = rr%NM2 - 5;
    d12w[gid] = (float)(dh_w_d(10,j) * wigd(lf, l, m, n, dh_beta_d(10,j)));
    return;
  }
  gid -= N_D12W;
  if (gid < N_D2) {
    int l = gid/(144*NM2*NM2); int r = gid%(144*NM2*NM2); int p = r/(NM2*NM2); int rr = r%(NM2*NM2);
    int m = rr/NM2 - 5, n = rr%NM2 - 5;
    double beta  = (double)(p/48 + 1) * PI_D/24.0;
    double alpha = 2.0*PI_D*(double)((p/6)%8)/8.0;
    double gamma = 2.0*PI_D*(double)(p%6)/6.0;
    double d = wigd(lf, l, m, n, beta);
    double ph = -((double)m*alpha + (double)n*gamma);
    D2[gid] = make_float2((float)(d*cos(ph)), (float)(d*sin(ph)));
    return;
  }
  gid -= N_D2;
  if (gid < N_D2W) {
    int l = gid/(NB2*NM2*NM2); int r = gid%(NB2*NM2*NM2); int j = r/(NM2*NM2); int rr = r%(NM2*NM2);
    int m = rr/NM2 - 5, n = rr%NM2 - 5;
    d2w[gid] = (float)((double)(2*l+1) * wigd(lf, l, m, n, dh_beta_d(6,j)));
    return;
  }
  gid -= N_D2W;
  if (gid < N_W2N) {
    double s = 0.0;
    for (int j = 0; j < NB2; ++j) s += dh_w_d(6,j);
    w2n[gid] = (float)(dh_w_d(6,gid)/s);
    return;
  }
}

// ---------------- K1: azimuthal DFT (60pt, 19 freqs) + Legendre transform -> X[10][128][19] ----------------
__global__ __launch_bounds__(256) void k_s2fft(const float* __restrict__ x,
                                               const float* __restrict__ wd_s2,
                                               float2* __restrict__ X) {
  __shared__ float xs[3600];
  __shared__ float2 xf[NB_IN*NM1];
  __shared__ float c60[60], s60[60];
  const int z = blockIdx.x, t = threadIdx.x;
  if (t < 60) { float s, c; sincosf(2.f*PI_F*(float)t/60.f, &s, &c); c60[t]=c; s60[t]=s; }
  for (int i = t; i < 3600; i += 256) xs[i] = x[z*3600 + i];
  __syncthreads();
  for (int i = t; i < NB_IN*NM1; i += 256) {
    int k = i/NM1, mi = i%NM1; int m = mi - 9;
    float re = 0.f, im = 0.f;
    for (int a = 0; a < 60; ++a) {
      int r = (a*m)%60; if (r < 0) r += 60;
      float v = xs[k*60 + a];
      re = fmaf(v, c60[r], re);
      im = fmaf(-v, s60[r], im);
    }
    xf[i] = make_float2(re, im);
  }
  __syncthreads();
  for (int i = t; i < NL1*NM1; i += 256) {
    int l = i/NM1, mi = i%NM1;
    float re = 0.f, im = 0.f;
    for (int k = 0; k < 60; ++k) {
      float w = wd_s2[(l*60+k)*NM1 + mi];
      float2 v = xf[k*NM1 + mi];
      re = fmaf(w, v.x, re); im = fmaf(w, v.y, im);
    }
    X[(l*BATCH + z)*NM1 + mi] = make_float2(re, im);
  }
}

// ---------------- K2: Psi1[l][o][m] = sum_g psi1[0][o][g] * Y1[l][g][m] ----------------
__global__ void k_psi1(const float* __restrict__ psi1, const float2* __restrict__ Y1,
                       float2* __restrict__ Psi1) {
  int idx = blockIdx.x*blockDim.x + threadIdx.x;
  if (idx >= NL1*F1C*NM1) return;
  int l = idx/(F1C*NM1); int r = idx%(F1C*NM1); int o = r/NM1; int mi = r%NM1;
  float re = 0.f, im = 0.f;
  for (int g = 0; g < 24; ++g) {
    float w = psi1[o*24 + g];
    float2 y = Y1[(l*24+g)*NM1 + mi];
    re = fmaf(w, y.x, re); im = fmaf(w, y.y, im);
  }
  Psi1[idx] = make_float2(re, im);
}

// ---------------- K3: Psi2[l][i][o][k][n] = sum_g psi2[i][o][g] * D2[l][g][k][n] ----------------
__global__ void k_psi2(const float* __restrict__ psi2, const float2* __restrict__ D2,
                       float2* __restrict__ Psi2) {
  int idx = blockIdx.x*blockDim.x + threadIdx.x;
  if (idx >= NL2*F1C*F2C*NM2*NM2) return;
  int mn = idx % (NM2*NM2); int t1 = idx/(NM2*NM2);
  int o = t1 % F2C; int t2 = t1/F2C; int i = t2 % F1C; int l = t2/F1C;
  float re = 0.f, im = 0.f;
  for (int g = 0; g < 144; ++g) {
    float w = psi2[(i*F2C + o)*144 + g];
    float2 dv = D2[(l*144 + g)*(NM2*NM2) + mn];
    re = fmaf(w, dv.x, re); im = fmaf(w, dv.y, im);
  }
  Psi2[idx] = make_float2(re, im);
}

// ---------------- K4: fused stage 1. Block per (z,o). ----------------
// Fh[m,n] = sum_l X[l,z,m]*Psi1[l,o,n]*d1w[l,b,m,n]; y = relu(2D synthesis);
// yf = 2D analysis (11x11); Fx[l2] += d12w[l2,b]*yf; loop over b=0..19.
__global__ __launch_bounds__(256) void k_stage1(const float2* __restrict__ X,
                                                const float2* __restrict__ Psi1,
                                                const float* __restrict__ d1w,
                                                const float* __restrict__ d12w,
                                                float2* __restrict__ Fx) {
  __shared__ float2 Xs[NL1*NM1];
  __shared__ float2 Ps[NL1*NM1];
  __shared__ float2 XP[NL1*NM1*NM1];   // 3610
  __shared__ float2 Fh[NM1*NM1];       // 361
  __shared__ float2 Tt[NM1*NB1];       // 380
  __shared__ float  yb[NB1*NB1];       // 400
  __shared__ float2 Uu[NM2*NB1];       // 220
  __shared__ float2 yfs[NM2*NM2];      // 121
  __shared__ float2 Fxa[NL2*NM2*NM2];  // 726
  __shared__ float ec[NB1], es[NB1];

  const int z = blockIdx.x, o = blockIdx.y, t = threadIdx.x;
  if (t < NB1) { float s, c; sincosf(2.f*PI_F*(float)t/(float)NB1, &s, &c); ec[t]=c; es[t]=s; }
  for (int i = t; i < NL1*NM1; i += 256) {
    int l = i/NM1, mi = i%NM1;
    Xs[i] = X[(l*BATCH + z)*NM1 + mi];
    Ps[i] = Psi1[(l*F1C + o)*NM1 + mi];
  }
  for (int i = t; i < NL2*NM2*NM2; i += 256) Fxa[i] = make_float2(0.f, 0.f);
  __syncthreads();
  for (int i = t; i < NL1*NM1*NM1; i += 256) {
    int l = i/(NM1*NM1); int rr = i%(NM1*NM1); int mi = rr/NM1, ni = rr%NM1;
    float2 a = Xs[l*NM1 + mi], b = Ps[l*NM1 + ni];
    XP[i] = make_float2(a.x*b.x - a.y*b.y, a.x*b.y + a.y*b.x);
  }
  __syncthreads();

  for (int b = 0; b < NB1; ++b) {
    // Fh
    for (int i = t; i < NM1*NM1; i += 256) {
      float re = 0.f, im = 0.f;
      #pragma unroll
      for (int l = 0; l < NL1; ++l) {
        float w = d1w[(l*NB1 + b)*(NM1*NM1) + i];
        float2 v = XP[l*(NM1*NM1) + i];
        re = fmaf(w, v.x, re); im = fmaf(w, v.y, im);
      }
      Fh[i] = make_float2(re, im);
    }
    __syncthreads();
    // T[m][g] = sum_n Fh[m][n] * e^{+i 2pi g n / 20}
    for (int i = t; i < NM1*NB1; i += 256) {
      int mi = i/NB1, g = i%NB1;
      float re = 0.f, im = 0.f;
      for (int ni = 0; ni < NM1; ++ni) {
        int r = (g*(ni-9))%NB1; if (r < 0) r += NB1;
        float2 f = Fh[mi*NM1 + ni];
        float c = ec[r], s = es[r];
        re += f.x*c - f.y*s; im += f.x*s + f.y*c;
      }
      Tt[i] = make_float2(re, im);
    }
    __syncthreads();
    // y[a][g] = relu( Re sum_m e^{+i 2pi a m/20} T[m][g] )
    for (int i = t; i < NB1*NB1; i += 256) {
      int a = i/NB1, g = i%NB1;
      float v = 0.f;
      for (int mi = 0; mi < NM1; ++mi) {
        int r = (a*(mi-9))%NB1; if (r < 0) r += NB1;
        float2 tv = Tt[mi*NB1 + g];
        v += ec[r]*tv.x - es[r]*tv.y;
      }
      yb[i] = fmaxf(v, 0.f);
    }
    __syncthreads();
    // U[m2][g] = sum_a y[a][g] e^{-i 2pi a m2/20}
    for (int i = t; i < NM2*NB1; i += 256) {
      int mi2 = i/NB1, g = i%NB1; int m2 = mi2 - 5;
      float re = 0.f, im = 0.f;
      for (int a = 0; a < NB1; ++a) {
        int r = (a*m2)%NB1; if (r < 0) r += NB1;
        float v = yb[a*NB1 + g];
        re = fmaf(v, ec[r], re); im = fmaf(-v, es[r], im);
      }
      Uu[i] = make_float2(re, im);
    }
    __syncthreads();
    // yf[m2][n2] = sum_g U[m2][g] e^{-i 2pi g n2/20}
    for (int i = t; i < NM2*NM2; i += 256) {
      int mi2 = i/NM2, ni2 = i%NM2; int n2 = ni2 - 5;
      float re = 0.f, im = 0.f;
      for (int g = 0; g < NB1; ++g) {
        int r = (g*n2)%NB1; if (r < 0) r += NB1;
        float2 u = Uu[mi2*NB1 + g];
        float c = ec[r], s = -es[r];
        re += u.x*c - u.y*s; im += u.x*s + u.y*c;
      }
      yfs[i] = make_float2(re, im);
    }
    __syncthreads();
    // Fxa[l2][m2][n2] += d12w[l2][b][m2][n2] * yf
    for (int i = t; i < NL2*NM2*NM2; i += 256) {
      int l2 = i/(NM2*NM2); int mn = i%(NM2*NM2);
      float w = d12w[(l2*NB1 + b)*(NM2*NM2) + mn];
      float2 v = yfs[mn];
      Fxa[i].x = fmaf(w, v.x, Fxa[i].x);
      Fxa[i].y = fmaf(w, v.y, Fxa[i].y);
    }
    __syncthreads();
  }
  for (int i = t; i < NL2*NM2*NM2; i += 256) {
    int l2 = i/(NM2*NM2); int mn = i%(NM2*NM2);
    Fx[((l2*BATCH + z)*F1C + o)*(NM2*NM2) + mn] = Fxa[i];
  }
}

// ---------------- K5: per-l complex matmul Fo[l,z,o,m,n] = sum_{i,k} Fx[l,z,i,m,k]*Psi2[l,i,o,k,n] ----------------
__global__ __launch_bounds__(256) void k_so3mm(const float2* __restrict__ Fx,
                                               const float2* __restrict__ Psi2,
                                               float2* __restrict__ Fo) {
  __shared__ float2 Fxs[F1C*NM2*NM2];   // 2420
  __shared__ float2 Bt[2*F1C*NM2*NM2];  // 4840
  const int z = blockIdx.x, l = blockIdx.y, t = threadIdx.x;
  for (int i = t; i < F1C*NM2*NM2; i += 256)
    Fxs[i] = Fx[(l*BATCH + z)*F1C*NM2*NM2 + i];
  __syncthreads();
  const int mn = t % (NM2*NM2), oo = t / (NM2*NM2);
  const int m = mn / NM2, n = mn % NM2;
  for (int ot = 0; ot < F2C/2; ++ot) {
    for (int i = t; i < 2*F1C*NM2*NM2; i += 256) {
      int o2 = i / (F1C*NM2*NM2); int r = i % (F1C*NM2*NM2);
      int ii = r/(NM2*NM2); int kn = r%(NM2*NM2);
      Bt[i] = Psi2[((l*F1C + ii)*F2C + (ot*2 + o2))*(NM2*NM2) + kn];
    }
    __syncthreads();
    if (t < 2*NM2*NM2) {
      float re = 0.f, im = 0.f;
      for (int i = 0; i < F1C; ++i) {
        const float2* arow = &Fxs[i*(NM2*NM2) + m*NM2];
        const float2* brow = &Bt[oo*(F1C*NM2*NM2) + i*(NM2*NM2) + n];
        #pragma unroll
        for (int k = 0; k < NM2; ++k) {
          float2 a = arow[k];
          float2 bb = brow[k*NM2];
          re += a.x*bb.x - a.y*bb.y;
          im += a.x*bb.y + a.y*bb.x;
        }
      }
      Fo[((l*BATCH + z)*F2C + (ot*2 + oo))*(NM2*NM2) + mn] = make_float2(re, im);
    }
    __syncthreads();
  }
}

// ---------------- K6: fused stage 2 tail. Block per (z,o). ----------------
__global__ __launch_bounds__(128) void k_stage2(const float2* __restrict__ Fo,
                                                const float* __restrict__ d2w,
                                                const float* __restrict__ w2n,
                                                float* __restrict__ feat) {
  __shared__ float2 Fos[NL2*NM2*NM2]; // 726
  __shared__ float2 Fh2[NM2*NM2];     // 121
  __shared__ float2 T2[NB2*NM2];      // 132
  __shared__ float ec[NB2], es[NB2], w2s[NB2];
  __shared__ float red[128];
  const int z = blockIdx.x, o = blockIdx.y, t = threadIdx.x;
  if (t < NB2) {
    float s, c; sincosf(2.f*PI_F*(float)t/(float)NB2, &s, &c);
    ec[t]=c; es[t]=s; w2s[t]=w2n[t];
  }
  for (int i = t; i < NL2*NM2*NM2; i += 128) {
    int l = i/(NM2*NM2); int mn = i%(NM2*NM2);
    Fos[i] = Fo[((l*BATCH + z)*F2C + o)*(NM2*NM2) + mn];
  }
  float accT = 0.f;
  __syncthreads();
  for (int b = 0; b < NB2; ++b) {
    for (int i = t; i < NM2*NM2; i += 128) {
      float re = 0.f, im = 0.f;
      #pragma unroll
      for (int l = 0; l < NL2; ++l) {
        float w = d2w[(l*NB2 + b)*(NM2*NM2) + i];
        float2 v = Fos[l*(NM2*NM2) + i];
        re = fmaf(w, v.x, re); im = fmaf(w, v.y, im);
      }
      Fh2[i] = make_float2(re, im);
    }
    __syncthreads();
    for (int i = t; i < NB2*NM2; i += 128) {
      int a = i/NM2, ni = i%NM2;
      float re = 0.f, im = 0.f;
      for (int mi = 0; mi < NM2; ++mi) {
        int r = (a*(mi-5))%NB2; if (r < 0) r += NB2;
        float2 f = Fh2[mi*NM2 + ni];
        re += ec[r]*f.x - es[r]*f.y;
        im += ec[r]*f.y + es[r]*f.x;
      }
      T2[i] = make_float2(re, im);
    }
    __syncthreads();
    float wb = w2s[b];
    for (int i = t; i < NB2*NB2; i += 128) {
      int a = i/NB2, g = i%NB2;
      float v = 0.f;
      for (int ni = 0; ni < NM2; ++ni) {
        int r = (g*(ni-5))%NB2; if (r < 0) r += NB2;
        float2 tv = T2[a*NM2 + ni];
        v += ec[r]*tv.x - es[r]*tv.y;
      }
      accT += wb*fmaxf(v, 0.f);
    }
    __syncthreads();
  }
  red[t] = accT;
  __syncthreads();
  for (int s = 64; s > 0; s >>= 1) {
    if (t < s) red[t] += red[t + s];
    __syncthreads();
  }
  if (t == 0) feat[z*F2C + o] = red[0] / (float)(NB2*NB2);
}

// ---------------- K7: linear head ----------------
__global__ void k_head(const float* __restrict__ feat, const float* __restrict__ w_lin,
                       const float* __restrict__ b_lin, float* __restrict__ out) {
  int idx = blockIdx.x*blockDim.x + threadIdx.x;
  if (idx >= BATCH*10) return;
  int z = idx/10, f = idx%10;
  float acc = b_lin[f];
  for (int o = 0; o < F2C; ++o) acc = fmaf(feat[z*F2C + o], w_lin[f*F2C + o], acc);
  out[idx] = acc;
}

extern "C" void kernel_launch(void* const* d_in, const int* in_sizes, int n_in,
                              void* d_out, int out_size, void* d_ws, size_t ws_size,
                              hipStream_t stream) {
  const float* x     = (const float*)d_in[0];
  const float* psi1  = (const float*)d_in[1];
  const float* psi2  = (const float*)d_in[2];
  const float* w_lin = (const float*)d_in[3];
  const float* b_lin = (const float*)d_in[4];
  float* out = (float*)d_out;
  float* ws  = (float*)d_ws;

  // workspace layout (element offsets in floats, 16-float aligned)
  size_t off = 0;
  auto alloc = [&](size_t nfloats) { size_t o = off; off += (nfloats + 15) & ~(size_t)15; return o; };
  float*  wd_s2 = ws + alloc(N_WDS2);
  float2* Y1    = (float2*)(ws + alloc(2*(size_t)N_Y1));
  float*  d1w   = ws + alloc(N_D1W);
  float*  d12w  = ws + alloc(N_D12W);
  float2* D2    = (float2*)(ws + alloc(2*(size_t)N_D2));
  float*  d2w   = ws + alloc(N_D2W);
  float*  w2n   = ws + alloc(N_W2N);
  float2* X     = (float2*)(ws + alloc(2*(size_t)NL1*BATCH*NM1));
  float2* Psi1p = (float2*)(ws + alloc(2*(size_t)NL1*F1C*NM1));
  float2* Psi2p = (float2*)(ws + alloc(2*(size_t)NL2*F1C*F2C*NM2*NM2));
  float2* Fxp   = (float2*)(ws + alloc(2*(size_t)NL2*BATCH*F1C*NM2*NM2));
  float2* Fop   = (float2*)(ws + alloc(2*(size_t)NL2*BATCH*F2C*NM2*NM2));
  float*  featp = ws + alloc((size_t)BATCH*F2C);
  if (ws_size < off*sizeof(float)) return;  // ~51 MB needed; fail visibly if ws too small

  const int total_c = N_WDS2 + N_Y1 + N_D1W + N_D12W + N_D2 + N_D2W + N_W2N;
  k_consts<<<(total_c + 255)/256, 256, 0, stream>>>(wd_s2, Y1, d1w, d12w, D2, d2w, w2n);
  k_s2fft<<<BATCH, 256, 0, stream>>>(x, wd_s2, X);
  k_psi1<<<(NL1*F1C*NM1 + 255)/256, 256, 0, stream>>>(psi1, Y1, Psi1p);
  k_psi2<<<(NL2*F1C*F2C*NM2*NM2 + 255)/256, 256, 0, stream>>>(psi2, D2, Psi2p);
  k_stage1<<<dim3(BATCH, F1C), 256, 0, stream>>>(X, Psi1p, d1w, d12w, Fxp);
  k_so3mm<<<dim3(BATCH, NL2), 256, 0, stream>>>(Fxp, Psi2p, Fop);
  k_stage2<<<dim3(BATCH, F2C), 128, 0, stream>>>(Fop, d2w, w2n, featp);
  k_head<<<(BATCH*10 + 255)/256, 256, 0, stream>>>(featp, w_lin, b_lin, out);
}

// Round 2
// 939.446 us; speedup vs baseline: 1.1743x; 1.1743x over previous
//
#include <hip/hip_runtime.h>
#include <math.h>

#define PI_D 3.14159265358979323846
#define PI_F 3.14159265358979f

#define BATCH 128
#define NM1 19    // retained m freqs for B1 (m in [-9,9])
#define NM2 11    // retained freqs for B2 (m in [-5,5])
#define NB_IN 60  // 2*B_IN
#define NB1 20    // 2*B1
#define NB2 12    // 2*B2
#define NL1 10    // B1
#define NL2 6     // B2
#define F1C 20
#define F2C 40
#define NBC 5     // beta chunk for stage1

// constant tensor element counts
#define N_WDS2 (NL1*NB_IN*NM1)     // 11400 f32
#define N_Y1   (NL1*24*NM1)        // 4560 cplx
#define N_D1W  (NL1*NB1*NM1*NM1)   // 72200 f32
#define N_D12W (NL2*NB1*NM2*NM2)   // 14520 f32
#define N_D2   (NL2*144*NM2*NM2)   // 104544 cplx
#define N_D2W  (NL2*NB2*NM2*NM2)   // 8712 f32
#define N_W2N  (NB2)               // 12 f32

// ---------------- device helpers for Wigner-d (fp64, matches numpy trace-time math) ----------------
__device__ __forceinline__ double ipow_d(double x, int e) {
  double r = 1.0;
  for (int i = 0; i < e; ++i) r *= x;
  return r;
}

__device__ double wigd(const double* lf, int l, int m, int n, double beta) {
  if (m < -l || m > l || n < -l || n > l) return 0.0;
  double cb = cos(0.5*beta), sb = sin(0.5*beta);
  double pref = 0.5*(lf[l+m]+lf[l-m]+lf[l+n]+lf[l-n]);
  int s0 = (n-m) > 0 ? (n-m) : 0;
  int s1 = (l+n) < (l-m) ? (l+n) : (l-m);
  double acc = 0.0;
  for (int s = s0; s <= s1; ++s) {
    double lc = pref - (lf[l+n-s]+lf[s]+lf[m-n+s]+lf[l-m-s]);
    double t = exp(lc) * ipow_d(cb, 2*l+n-m-2*s) * ipow_d(sb, m-n+2*s);
    acc += ((m-n+s) & 1) ? -t : t;
  }
  return acc;
}

__device__ __forceinline__ double dh_beta_d(int b, int k) { return PI_D*(2*k+1)/(4.0*b); }

__device__ double dh_w_d(int b, int k) {
  double beta = dh_beta_d(b, k), s = 0.0;
  for (int j = 0; j < b; ++j) s += sin((2.0*j+1.0)*beta)/(2.0*j+1.0);
  return (2.0/b)*sin(beta)*s;
}

// ---------------- constants kernel ----------------
__global__ void k_consts(float* __restrict__ wd_s2, float2* __restrict__ Y1,
                         float* __restrict__ d1w, float* __restrict__ d12w,
                         float2* __restrict__ D2, float* __restrict__ d2w,
                         float* __restrict__ w2n) {
  __shared__ double lf[41];
  int t = threadIdx.x;
  if (t < 41) lf[t] = lgamma((double)t + 1.0);
  __syncthreads();
  int gid = blockIdx.x*blockDim.x + t;

  if (gid < N_WDS2) {
    int l = gid/(NB_IN*NM1); int r = gid%(NB_IN*NM1); int k = r/NM1; int mi = r%NM1;
    int m = mi - 9;
    wd_s2[gid] = (float)(dh_w_d(30,k) * wigd(lf, l, m, 0, dh_beta_d(30,k)));
    return;
  }
  gid -= N_WDS2;
  if (gid < N_Y1) {
    int l = gid/(24*NM1); int r = gid%(24*NM1); int p = r/NM1; int mi = r%NM1;
    int m = mi - 9;
    double beta  = (double)(p/8 + 1) * PI_D/24.0;
    double alpha = 2.0*PI_D*(double)(p%8)/8.0;
    double d = wigd(lf, l, m, 0, beta);
    double ph = -(double)m*alpha;
    Y1[gid] = make_float2((float)(d*cos(ph)), (float)(d*sin(ph)));
    return;
  }
  gid -= N_Y1;
  if (gid < N_D1W) {
    int l = gid/(NB1*NM1*NM1); int r = gid%(NB1*NM1*NM1); int j = r/(NM1*NM1); int rr = r%(NM1*NM1);
    int m = rr/NM1 - 9, n = rr%NM1 - 9;
    d1w[gid] = (float)((double)(2*l+1) * wigd(lf, l, m, n, dh_beta_d(10,j)));
    return;
  }
  gid -= N_D1W;
  if (gid < N_D12W) {
    int l = gid/(NB1*NM2*NM2); int r = gid%(NB1*NM2*NM2); int j = r/(NM2*NM2); int rr = r%(NM2*NM2);
    int m = rr/NM2 - 5, n = rr%NM2 - 5;
    d12w[gid] = (float)(dh_w_d(10,j) * wigd(lf, l, m, n, dh_beta_d(10,j)));
    return;
  }
  gid -= N_D12W;
  if (gid < N_D2) {
    int l = gid/(144*NM2*NM2); int r = gid%(144*NM2*NM2); int p = r/(NM2*NM2); int rr = r%(NM2*NM2);
    int m = rr/NM2 - 5, n = rr%NM2 - 5;
    double beta  = (double)(p/48 + 1) * PI_D/24.0;
    double alpha = 2.0*PI_D*(double)((p/6)%8)/8.0;
    double gamma = 2.0*PI_D*(double)(p%6)/6.0;
    double d = wigd(lf, l, m, n, beta);
    double ph = -((double)m*alpha + (double)n*gamma);
    D2[gid] = make_float2((float)(d*cos(ph)), (float)(d*sin(ph)));
    return;
  }
  gid -= N_D2;
  if (gid < N_D2W) {
    int l = gid/(NB2*NM2*NM2); int r = gid%(NB2*NM2*NM2); int j = r/(NM2*NM2); int rr = r%(NM2*NM2);
    int m = rr/NM2 - 5, n = rr%NM2 - 5;
    d2w[gid] = (float)((double)(2*l+1) * wigd(lf, l, m, n, dh_beta_d(6,j)));
    return;
  }
  gid -= N_D2W;
  if (gid < N_W2N) {
    double s = 0.0;
    for (int j = 0; j < NB2; ++j) s += dh_w_d(6,j);
    w2n[gid] = (float)(dh_w_d(6,gid)/s);
    return;
  }
}

// ---------------- K1: azimuthal DFT (60pt, 19 freqs) + Legendre transform -> X[10][128][19] ----------------
__global__ __launch_bounds__(256) void k_s2fft(const float* __restrict__ x,
                                               const float* __restrict__ wd_s2,
                                               float2* __restrict__ X) {
  __shared__ float xs[3600];
  __shared__ float2 xf[NB_IN*NM1];
  __shared__ float2 tw60[NB_IN*NM1];   // [a][mi] = e^{-i 2pi a(mi-9)/60}
  const int z = blockIdx.x, t = threadIdx.x;
  for (int i = t; i < NB_IN*NM1; i += 256) {
    int a = i/NM1, mi = i%NM1;
    int r = (a*(mi-9)) % NB_IN; if (r < 0) r += NB_IN;
    float s, c; sincosf(2.f*PI_F*(float)r/(float)NB_IN, &s, &c);
    tw60[i] = make_float2(c, -s);
  }
  for (int i = t; i < 3600; i += 256) xs[i] = x[z*3600 + i];
  __syncthreads();
  for (int i = t; i < NB_IN*NM1; i += 256) {
    int k = i/NM1, mi = i%NM1;
    float re = 0.f, im = 0.f;
    const float* xrow = &xs[k*NB_IN];
    for (int a = 0; a < NB_IN; ++a) {
      float v = xrow[a];
      float2 e = tw60[a*NM1 + mi];
      re = fmaf(v, e.x, re);
      im = fmaf(v, e.y, im);
    }
    xf[i] = make_float2(re, im);
  }
  __syncthreads();
  for (int i = t; i < NL1*NM1; i += 256) {
    int l = i/NM1, mi = i%NM1;
    float re = 0.f, im = 0.f;
    for (int k = 0; k < NB_IN; ++k) {
      float w = wd_s2[(l*NB_IN+k)*NM1 + mi];
      float2 v = xf[k*NM1 + mi];
      re = fmaf(w, v.x, re); im = fmaf(w, v.y, im);
    }
    X[(l*BATCH + z)*NM1 + mi] = make_float2(re, im);
  }
}

// ---------------- K2: Psi1[l][o][m] = sum_g psi1[0][o][g] * Y1[l][g][m] ----------------
__global__ void k_psi1(const float* __restrict__ psi1, const float2* __restrict__ Y1,
                       float2* __restrict__ Psi1) {
  int idx = blockIdx.x*blockDim.x + threadIdx.x;
  if (idx >= NL1*F1C*NM1) return;
  int l = idx/(F1C*NM1); int r = idx%(F1C*NM1); int o = r/NM1; int mi = r%NM1;
  float re = 0.f, im = 0.f;
  for (int g = 0; g < 24; ++g) {
    float w = psi1[o*24 + g];
    float2 y = Y1[(l*24+g)*NM1 + mi];
    re = fmaf(w, y.x, re); im = fmaf(w, y.y, im);
  }
  Psi1[idx] = make_float2(re, im);
}

// ---------------- K3: Psi2[l][i][o][k][n] = sum_g psi2[i][o][g] * D2[l][g][k][n] ----------------
__global__ void k_psi2(const float* __restrict__ psi2, const float2* __restrict__ D2,
                       float2* __restrict__ Psi2) {
  int idx = blockIdx.x*blockDim.x + threadIdx.x;
  if (idx >= NL2*F1C*F2C*NM2*NM2) return;
  int mn = idx % (NM2*NM2); int t1 = idx/(NM2*NM2);
  int o = t1 % F2C; int t2 = t1/F2C; int i = t2 % F1C; int l = t2/F1C;
  float re = 0.f, im = 0.f;
  for (int g = 0; g < 144; ++g) {
    float w = psi2[(i*F2C + o)*144 + g];
    float2 dv = D2[(l*144 + g)*(NM2*NM2) + mn];
    re = fmaf(w, dv.x, re); im = fmaf(w, dv.y, im);
  }
  Psi2[idx] = make_float2(re, im);
}

// ---------------- K4: fused stage 1. Block per (z,o), beta processed NBC at a time in parallel. ----------------
__global__ __launch_bounds__(256) void k_stage1(const float2* __restrict__ X,
                                                const float2* __restrict__ Psi1,
                                                const float* __restrict__ d1w,
                                                const float* __restrict__ d12w,
                                                float2* __restrict__ Fx) {
  __shared__ float2 Xs[NL1*NM1];          // 190
  __shared__ float2 Ps[NL1*NM1];          // 190
  __shared__ float2 Esyn[NB1*NM1];        // [k][mi]  e^{+i 2pi k(mi-9)/20}
  __shared__ float2 Eana[NB1*NM2];        // [k][mi2] e^{-i 2pi k(mi2-5)/20}
  __shared__ float2 bufA[NBC*NM1*NM1];    // Fh[bb][m][n]; later aliased as y[bb][a][g] (float)
  __shared__ float2 bufB[NBC*NM1*NB1];    // Tt[bb][m][g]; later aliased as U[bb][m2][g]
  __shared__ float2 yfs[NBC*NM2*NM2];     // 605
  __shared__ float2 Fxa[NL2*NM2*NM2];     // 726

  const int z = blockIdx.x, o = blockIdx.y, t = threadIdx.x;

  for (int i = t; i < NB1*NM1; i += 256) {
    int k = i/NM1, mi = i%NM1;
    int r = (k*(mi-9)) % NB1; if (r < 0) r += NB1;
    float s, c; sincosf(2.f*PI_F*(float)r/(float)NB1, &s, &c);
    Esyn[i] = make_float2(c, s);
  }
  for (int i = t; i < NB1*NM2; i += 256) {
    int k = i/NM2, mi = i%NM2;
    int r = (k*(mi-5)) % NB1; if (r < 0) r += NB1;
    float s, c; sincosf(2.f*PI_F*(float)r/(float)NB1, &s, &c);
    Eana[i] = make_float2(c, -s);
  }
  for (int i = t; i < NL1*NM1; i += 256) {
    int l = i/NM1, mi = i%NM1;
    Xs[i] = X[(l*BATCH + z)*NM1 + mi];
    Ps[i] = Psi1[(l*F1C + o)*NM1 + mi];
  }
  for (int i = t; i < NL2*NM2*NM2; i += 256) Fxa[i] = make_float2(0.f, 0.f);
  __syncthreads();

  float*  yb = (float*)bufA;   // y[bb][a][g]  : NBC*400 floats <= 3610
  float2* Uu = bufB;           // U[bb][m2][g] : NBC*220 cplx  <= 1900

  for (int c = 0; c < NB1/NBC; ++c) {
    const int b0 = c*NBC;
    // phase1: Fh[bb][mn] = sum_l (Xs[l][m]*Ps[l][n]) * d1w[l][b0+bb][mn]
    for (int i = t; i < NBC*NM1*NM1; i += 256) {
      int bb = i/(NM1*NM1); int mn = i%(NM1*NM1);
      int m = mn/NM1, n = mn%NM1;
      float re = 0.f, im = 0.f;
      const float* dw = &d1w[(b0+bb)*(NM1*NM1) + mn];
      #pragma unroll
      for (int l = 0; l < NL1; ++l) {
        float2 xa = Xs[l*NM1+m], pp = Ps[l*NM1+n];
        float xr = xa.x*pp.x - xa.y*pp.y;
        float xi = xa.x*pp.y + xa.y*pp.x;
        float w = dw[l*(NB1*NM1*NM1)];
        re = fmaf(w, xr, re); im = fmaf(w, xi, im);
      }
      bufA[i] = make_float2(re, im);
    }
    __syncthreads();
    // phase2: Tt[bb][m][g] = sum_n Fh[bb][m][n] * Esyn[g][n]
    for (int i = t; i < NBC*NM1*NB1; i += 256) {
      int g = i % NB1; int r = i / NB1; int m = r % NM1; int bb = r / NM1;
      const float2* fh = &bufA[(bb*NM1 + m)*NM1];
      float re = 0.f, im = 0.f;
      #pragma unroll
      for (int n = 0; n < NM1; ++n) {
        float2 f = fh[n]; float2 e = Esyn[g*NM1+n];
        re += f.x*e.x - f.y*e.y;
        im += f.x*e.y + f.y*e.x;
      }
      bufB[i] = make_float2(re, im);
    }
    __syncthreads();
    // phase3: y[bb][a][g] = relu( Re sum_m Esyn[a][m] * Tt[bb][m][g] )
    for (int i = t; i < NBC*NB1*NB1; i += 256) {
      int g = i % NB1; int r = i / NB1; int aa = r % NB1; int bb = r / NB1;
      const float2* tt = &bufB[(bb*NM1)*NB1 + g];
      float v = 0.f;
      #pragma unroll
      for (int m = 0; m < NM1; ++m) {
        float2 tv = tt[m*NB1]; float2 e = Esyn[aa*NM1+m];
        v += e.x*tv.x - e.y*tv.y;
      }
      yb[i] = fmaxf(v, 0.f);
    }
    __syncthreads();
    // phase4: U[bb][m2][g] = sum_a y[bb][a][g] * Eana[a][m2]
    for (int i = t; i < NBC*NM2*NB1; i += 256) {
      int g = i % NB1; int r = i / NB1; int m2 = r % NM2; int bb = r / NM2;
      const float* yrow = &yb[(bb*NB1)*NB1 + g];
      float re = 0.f, im = 0.f;
      #pragma unroll
      for (int aa = 0; aa < NB1; ++aa) {
        float v = yrow[aa*NB1]; float2 e = Eana[aa*NM2+m2];
        re = fmaf(v, e.x, re); im = fmaf(v, e.y, im);
      }
      Uu[i] = make_float2(re, im);
    }
    __syncthreads();
    // phase5: yf[bb][m2][n2] = sum_g U[bb][m2][g] * Eana[g][n2]
    for (int i = t; i < NBC*NM2*NM2; i += 256) {
      int n2 = i % NM2; int r = i / NM2; int m2 = r % NM2; int bb = r / NM2;
      const float2* ur = &Uu[(bb*NM2+m2)*NB1];
      float re = 0.f, im = 0.f;
      #pragma unroll
      for (int g = 0; g < NB1; ++g) {
        float2 u = ur[g]; float2 e = Eana[g*NM2+n2];
        re += u.x*e.x - u.y*e.y;
        im += u.x*e.y + u.y*e.x;
      }
      yfs[i] = make_float2(re, im);
    }
    __syncthreads();
    // phase6: Fxa[l2][mn] += sum_bb d12w[l2][b0+bb][mn] * yf[bb][mn]
    for (int i = t; i < NL2*NM2*NM2; i += 256) {
      int l2 = i/(NM2*NM2); int mn = i%(NM2*NM2);
      float2 acc = Fxa[i];
      #pragma unroll
      for (int bb = 0; bb < NBC; ++bb) {
        float w = d12w[(l2*NB1 + b0 + bb)*(NM2*NM2) + mn];
        float2 v = yfs[bb*(NM2*NM2) + mn];
        acc.x = fmaf(w, v.x, acc.x); acc.y = fmaf(w, v.y, acc.y);
      }
      Fxa[i] = acc;
    }
    __syncthreads();
  }
  for (int i = t; i < NL2*NM2*NM2; i += 256) {
    int l2 = i/(NM2*NM2); int mn = i%(NM2*NM2);
    Fx[((l2*BATCH + z)*F1C + o)*(NM2*NM2) + mn] = Fxa[i];
  }
}

// ---------------- K5: per-l complex matmul Fo[l,z,o,m,n] = sum_{i,k} Fx[l,z,i,m,k]*Psi2[l,i,o,k,n] ----------------
__global__ __launch_bounds__(256) void k_so3mm(const float2* __restrict__ Fx,
                                               const float2* __restrict__ Psi2,
                                               float2* __restrict__ Fo) {
  __shared__ float2 Fxs[F1C*NM2*NM2];   // 2420
  __shared__ float2 Bt[2*F1C*NM2*NM2];  // 4840
  const int z = blockIdx.x, l = blockIdx.y, t = threadIdx.x;
  for (int i = t; i < F1C*NM2*NM2; i += 256)
    Fxs[i] = Fx[(l*BATCH + z)*F1C*NM2*NM2 + i];
  __syncthreads();
  const int mn = t % (NM2*NM2), oo = t / (NM2*NM2);
  const int m = mn / NM2, n = mn % NM2;
  for (int ot = 0; ot < F2C/2; ++ot) {
    for (int i = t; i < 2*F1C*NM2*NM2; i += 256) {
      int o2 = i / (F1C*NM2*NM2); int r = i % (F1C*NM2*NM2);
      int ii = r/(NM2*NM2); int kn = r%(NM2*NM2);
      Bt[i] = Psi2[((l*F1C + ii)*F2C + (ot*2 + o2))*(NM2*NM2) + kn];
    }
    __syncthreads();
    if (t < 2*NM2*NM2) {
      float re = 0.f, im = 0.f;
      for (int i = 0; i < F1C; ++i) {
        const float2* arow = &Fxs[i*(NM2*NM2) + m*NM2];
        const float2* brow = &Bt[oo*(F1C*NM2*NM2) + i*(NM2*NM2) + n];
        #pragma unroll
        for (int k = 0; k < NM2; ++k) {
          float2 a = arow[k];
          float2 bb = brow[k*NM2];
          re += a.x*bb.x - a.y*bb.y;
          im += a.x*bb.y + a.y*bb.x;
        }
      }
      Fo[((l*BATCH + z)*F2C + (ot*2 + oo))*(NM2*NM2) + mn] = make_float2(re, im);
    }
    __syncthreads();
  }
}

// ---------------- K6: fused stage 2 tail. Block per (z,o), beta fully parallel. ----------------
__global__ __launch_bounds__(256) void k_stage2(const float2* __restrict__ Fo,
                                                const float* __restrict__ d2w,
                                                const float* __restrict__ w2n,
                                                float* __restrict__ feat) {
  __shared__ float2 Fos[NL2*NM2*NM2];     // 726
  __shared__ float2 Fh2[NB2*NM2*NM2];     // 1452
  __shared__ float2 T2[NB2*NB2*NM2];      // 1584
  __shared__ float2 Esyn2[NB2*NM2];       // [k][mi] e^{+i 2pi k(mi-5)/12}
  __shared__ float w2s[NB2];
  __shared__ float red[256];
  const int z = blockIdx.x, o = blockIdx.y, t = threadIdx.x;
  for (int i = t; i < NB2*NM2; i += 256) {
    int k = i/NM2, mi = i%NM2;
    int r = (k*(mi-5)) % NB2; if (r < 0) r += NB2;
    float s, c; sincosf(2.f*PI_F*(float)r/(float)NB2, &s, &c);
    Esyn2[i] = make_float2(c, s);
  }
  if (t < NB2) w2s[t] = w2n[t];
  for (int i = t; i < NL2*NM2*NM2; i += 256) {
    int l = i/(NM2*NM2); int mn = i%(NM2*NM2);
    Fos[i] = Fo[((l*BATCH + z)*F2C + o)*(NM2*NM2) + mn];
  }
  __syncthreads();
  // ph1: Fh2[b][mn] = sum_l d2w[l][b][mn]*Fos[l][mn]
  for (int i = t; i < NB2*NM2*NM2; i += 256) {
    int b = i/(NM2*NM2); int mn = i%(NM2*NM2);
    float re = 0.f, im = 0.f;
    #pragma unroll
    for (int l = 0; l < NL2; ++l) {
      float w = d2w[(l*NB2 + b)*(NM2*NM2) + mn];
      float2 v = Fos[l*(NM2*NM2) + mn];
      re = fmaf(w, v.x, re); im = fmaf(w, v.y, im);
    }
    Fh2[i] = make_float2(re, im);
  }
  __syncthreads();
  // ph2: T2[b][a][ni] = sum_mi Esyn2[a][mi]*Fh2[b][mi][ni]
  for (int i = t; i < NB2*NB2*NM2; i += 256) {
    int ni = i % NM2; int r = i / NM2; int aa = r % NB2; int b = r / NB2;
    const float2* fh = &Fh2[b*(NM2*NM2) + ni];
    float re = 0.f, im = 0.f;
    #pragma unroll
    for (int mi = 0; mi < NM2; ++mi) {
      float2 f = fh[mi*NM2]; float2 e = Esyn2[aa*NM2+mi];
      re += e.x*f.x - e.y*f.y;
      im += e.x*f.y + e.y*f.x;
    }
    T2[i] = make_float2(re, im);
  }
  __syncthreads();
  // ph3: accumulate w2s[b]*relu( Re sum_ni Esyn2[g][ni]*T2[b][a][ni] )
  float accT = 0.f;
  for (int i = t; i < NB2*NB2*NB2; i += 256) {
    int g = i % NB2; int r = i / NB2; int aa = r % NB2; int b = r / NB2;
    const float2* trow = &T2[(b*NB2 + aa)*NM2];
    float v = 0.f;
    #pragma unroll
    for (int ni = 0; ni < NM2; ++ni) {
      float2 tv = trow[ni]; float2 e = Esyn2[g*NM2+ni];
      v += e.x*tv.x - e.y*tv.y;
    }
    accT += w2s[b]*fmaxf(v, 0.f);
  }
  red[t] = accT;
  __syncthreads();
  for (int s = 128; s > 0; s >>= 1) {
    if (t < s) red[t] += red[t + s];
    __syncthreads();
  }
  if (t == 0) feat[z*F2C + o] = red[0] / (float)(NB2*NB2);
}

// ---------------- K7: linear head ----------------
__global__ void k_head(const float* __restrict__ feat, const float* __restrict__ w_lin,
                       const float* __restrict__ b_lin, float* __restrict__ out) {
  int idx = blockIdx.x*blockDim.x + threadIdx.x;
  if (idx >= BATCH*10) return;
  int z = idx/10, f = idx%10;
  float acc = b_lin[f];
  for (int o = 0; o < F2C; ++o) acc = fmaf(feat[z*F2C + o], w_lin[f*F2C + o], acc);
  out[idx] = acc;
}

extern "C" void kernel_launch(void* const* d_in, const int* in_sizes, int n_in,
                              void* d_out, int out_size, void* d_ws, size_t ws_size,
                              hipStream_t stream) {
  const float* x     = (const float*)d_in[0];
  const float* psi1  = (const float*)d_in[1];
  const float* psi2  = (const float*)d_in[2];
  const float* w_lin = (const float*)d_in[3];
  const float* b_lin = (const float*)d_in[4];
  float* out = (float*)d_out;
  float* ws  = (float*)d_ws;

  size_t off = 0;
  auto alloc = [&](size_t nfloats) { size_t o = off; off += (nfloats + 15) & ~(size_t)15; return o; };
  float*  wd_s2 = ws + alloc(N_WDS2);
  float2* Y1    = (float2*)(ws + alloc(2*(size_t)N_Y1));
  float*  d1w   = ws + alloc(N_D1W);
  float*  d12w  = ws + alloc(N_D12W);
  float2* D2    = (float2*)(ws + alloc(2*(size_t)N_D2));
  float*  d2w   = ws + alloc(N_D2W);
  float*  w2n   = ws + alloc(N_W2N);
  float2* X     = (float2*)(ws + alloc(2*(size_t)NL1*BATCH*NM1));
  float2* Psi1p = (float2*)(ws + alloc(2*(size_t)NL1*F1C*NM1));
  float2* Psi2p = (float2*)(ws + alloc(2*(size_t)NL2*F1C*F2C*NM2*NM2));
  float2* Fxp   = (float2*)(ws + alloc(2*(size_t)NL2*BATCH*F1C*NM2*NM2));
  float2* Fop   = (float2*)(ws + alloc(2*(size_t)NL2*BATCH*F2C*NM2*NM2));
  float*  featp = ws + alloc((size_t)BATCH*F2C);
  if (ws_size < off*sizeof(float)) return;

  const int total_c = N_WDS2 + N_Y1 + N_D1W + N_D12W + N_D2 + N_D2W + N_W2N;
  k_consts<<<(total_c + 255)/256, 256, 0, stream>>>(wd_s2, Y1, d1w, d12w, D2, d2w, w2n);
  k_s2fft<<<BATCH, 256, 0, stream>>>(x, wd_s2, X);
  k_psi1<<<(NL1*F1C*NM1 + 255)/256, 256, 0, stream>>>(psi1, Y1, Psi1p);
  k_psi2<<<(NL2*F1C*F2C*NM2*NM2 + 255)/256, 256, 0, stream>>>(psi2, D2, Psi2p);
  k_stage1<<<dim3(BATCH, F1C), 256, 0, stream>>>(X, Psi1p, d1w, d12w, Fxp);
  k_so3mm<<<dim3(BATCH, NL2), 256, 0, stream>>>(Fxp, Psi2p, Fop);
  k_stage2<<<dim3(BATCH, F2C), 256, 0, stream>>>(Fop, d2w, w2n, featp);
  k_head<<<(BATCH*10 + 255)/256, 256, 0, stream>>>(featp, w_lin, b_lin, out);
}

// Round 3
// 622.717 us; speedup vs baseline: 1.7716x; 1.5086x over previous
//
#include <hip/hip_runtime.h>
#include <math.h>

#define PI_D 3.14159265358979323846
#define PI_F 3.14159265358979f

#define BATCH 128
#define NM1 19    // retained m freqs for B1 (m in [-9,9])
#define NM2 11    // retained freqs for B2 (m in [-5,5])
#define NB_IN 60  // 2*B_IN
#define NB1 20    // 2*B1
#define NB2 12    // 2*B2
#define NL1 10    // B1
#define NL2 6     // B2
#define F1C 20
#define F2C 40
#define NBC 5     // beta chunk for stage1

// GEMM dims for so3mm: per-l, C[M][N] += A[M][K]*B[K][N] complex
#define GEMM_M (BATCH*NM2)   // 1408
#define GEMM_N (F2C*NM2)     // 440
#define GEMM_K (F1C*NM2)     // 220
#define GM 64
#define GN 64
#define GK 20

// constant tensor element counts
#define N_WDS2 (NL1*NB_IN*NM1)     // 11400 f32
#define N_Y1   (NL1*24*NM1)        // 4560 cplx
#define N_D1W  (NL1*NB1*NM1*NM1)   // 72200 f32
#define N_D12W (NL2*NB1*NM2*NM2)   // 14520 f32
#define N_D2   (NL2*144*NM2*NM2)   // 104544 cplx
#define N_D2W  (NL2*NB2*NM2*NM2)   // 8712 f32
#define N_W2N  (NB2)               // 12 f32

// ---------------- device helpers for Wigner-d (fp64, matches numpy trace-time math) ----------------
__device__ __forceinline__ double ipow_d(double x, int e) {
  double r = 1.0;
  for (int i = 0; i < e; ++i) r *= x;
  return r;
}

__device__ double wigd(const double* lf, int l, int m, int n, double beta) {
  if (m < -l || m > l || n < -l || n > l) return 0.0;
  double cb = cos(0.5*beta), sb = sin(0.5*beta);
  double pref = 0.5*(lf[l+m]+lf[l-m]+lf[l+n]+lf[l-n]);
  int s0 = (n-m) > 0 ? (n-m) : 0;
  int s1 = (l+n) < (l-m) ? (l+n) : (l-m);
  double acc = 0.0;
  for (int s = s0; s <= s1; ++s) {
    double lc = pref - (lf[l+n-s]+lf[s]+lf[m-n+s]+lf[l-m-s]);
    double t = exp(lc) * ipow_d(cb, 2*l+n-m-2*s) * ipow_d(sb, m-n+2*s);
    acc += ((m-n+s) & 1) ? -t : t;
  }
  return acc;
}

__device__ __forceinline__ double dh_beta_d(int b, int k) { return PI_D*(2*k+1)/(4.0*b); }

__device__ double dh_w_d(int b, int k) {
  double beta = dh_beta_d(b, k), s = 0.0;
  for (int j = 0; j < b; ++j) s += sin((2.0*j+1.0)*beta)/(2.0*j+1.0);
  return (2.0/b)*sin(beta)*s;
}

// ---------------- constants kernel ----------------
__global__ void k_consts(float* __restrict__ wd_s2, float2* __restrict__ Y1,
                         float* __restrict__ d1w, float* __restrict__ d12w,
                         float2* __restrict__ D2, float* __restrict__ d2w,
                         float* __restrict__ w2n) {
  __shared__ double lf[41];
  int t = threadIdx.x;
  if (t < 41) lf[t] = lgamma((double)t + 1.0);
  __syncthreads();
  int gid = blockIdx.x*blockDim.x + t;

  if (gid < N_WDS2) {
    int l = gid/(NB_IN*NM1); int r = gid%(NB_IN*NM1); int k = r/NM1; int mi = r%NM1;
    int m = mi - 9;
    wd_s2[gid] = (float)(dh_w_d(30,k) * wigd(lf, l, m, 0, dh_beta_d(30,k)));
    return;
  }
  gid -= N_WDS2;
  if (gid < N_Y1) {
    int l = gid/(24*NM1); int r = gid%(24*NM1); int p = r/NM1; int mi = r%NM1;
    int m = mi - 9;
    double beta  = (double)(p/8 + 1) * PI_D/24.0;
    double alpha = 2.0*PI_D*(double)(p%8)/8.0;
    double d = wigd(lf, l, m, 0, beta);
    double ph = -(double)m*alpha;
    Y1[gid] = make_float2((float)(d*cos(ph)), (float)(d*sin(ph)));
    return;
  }
  gid -= N_Y1;
  if (gid < N_D1W) {
    int l = gid/(NB1*NM1*NM1); int r = gid%(NB1*NM1*NM1); int j = r/(NM1*NM1); int rr = r%(NM1*NM1);
    int m = rr/NM1 - 9, n = rr%NM1 - 9;
    d1w[gid] = (float)((double)(2*l+1) * wigd(lf, l, m, n, dh_beta_d(10,j)));
    return;
  }
  gid -= N_D1W;
  if (gid < N_D12W) {
    int l = gid/(NB1*NM2*NM2); int r = gid%(NB1*NM2*NM2); int j = r/(NM2*NM2); int rr = r%(NM2*NM2);
    int m = rr/NM2 - 5, n = rr%NM2 - 5;
    d12w[gid] = (float)(dh_w_d(10,j) * wigd(lf, l, m, n, dh_beta_d(10,j)));
    return;
  }
  gid -= N_D12W;
  if (gid < N_D2) {
    int l = gid/(144*NM2*NM2); int r = gid%(144*NM2*NM2); int p = r/(NM2*NM2); int rr = r%(NM2*NM2);
    int m = rr/NM2 - 5, n = rr%NM2 - 5;
    double beta  = (double)(p/48 + 1) * PI_D/24.0;
    double alpha = 2.0*PI_D*(double)((p/6)%8)/8.0;
    double gamma = 2.0*PI_D*(double)(p%6)/6.0;
    double d = wigd(lf, l, m, n, beta);
    double ph = -((double)m*alpha + (double)n*gamma);
    D2[gid] = make_float2((float)(d*cos(ph)), (float)(d*sin(ph)));
    return;
  }
  gid -= N_D2;
  if (gid < N_D2W) {
    int l = gid/(NB2*NM2*NM2); int r = gid%(NB2*NM2*NM2); int j = r/(NM2*NM2); int rr = r%(NM2*NM2);
    int m = rr/NM2 - 5, n = rr%NM2 - 5;
    d2w[gid] = (float)((double)(2*l+1) * wigd(lf, l, m, n, dh_beta_d(6,j)));
    return;
  }
  gid -= N_D2W;
  if (gid < N_W2N) {
    double s = 0.0;
    for (int j = 0; j < NB2; ++j) s += dh_w_d(6,j);
    w2n[gid] = (float)(dh_w_d(6,gid)/s);
    return;
  }
}

// ---------------- K1: azimuthal DFT (60pt, 19 freqs) + Legendre transform -> X[10][128][19] ----------------
__global__ __launch_bounds__(256) void k_s2fft(const float* __restrict__ x,
                                               const float* __restrict__ wd_s2,
                                               float2* __restrict__ X) {
  __shared__ float xs[3600];
  __shared__ float2 xf[NB_IN*NM1];
  __shared__ float2 tw60[NB_IN*NM1];   // [a][mi] = e^{-i 2pi a(mi-9)/60}
  const int z = blockIdx.x, t = threadIdx.x;
  for (int i = t; i < NB_IN*NM1; i += 256) {
    int a = i/NM1, mi = i%NM1;
    int r = (a*(mi-9)) % NB_IN; if (r < 0) r += NB_IN;
    float s, c; sincosf(2.f*PI_F*(float)r/(float)NB_IN, &s, &c);
    tw60[i] = make_float2(c, -s);
  }
  for (int i = t; i < 3600; i += 256) xs[i] = x[z*3600 + i];
  __syncthreads();
  for (int i = t; i < NB_IN*NM1; i += 256) {
    int k = i/NM1, mi = i%NM1;
    float re = 0.f, im = 0.f;
    const float* xrow = &xs[k*NB_IN];
    for (int a = 0; a < NB_IN; ++a) {
      float v = xrow[a];
      float2 e = tw60[a*NM1 + mi];
      re = fmaf(v, e.x, re);
      im = fmaf(v, e.y, im);
    }
    xf[i] = make_float2(re, im);
  }
  __syncthreads();
  for (int i = t; i < NL1*NM1; i += 256) {
    int l = i/NM1, mi = i%NM1;
    float re = 0.f, im = 0.f;
    for (int k = 0; k < NB_IN; ++k) {
      float w = wd_s2[(l*NB_IN+k)*NM1 + mi];
      float2 v = xf[k*NM1 + mi];
      re = fmaf(w, v.x, re); im = fmaf(w, v.y, im);
    }
    X[(l*BATCH + z)*NM1 + mi] = make_float2(re, im);
  }
}

// ---------------- K2: Psi1[l][o][m] = sum_g psi1[0][o][g] * Y1[l][g][m] ----------------
__global__ void k_psi1(const float* __restrict__ psi1, const float2* __restrict__ Y1,
                       float2* __restrict__ Psi1) {
  int idx = blockIdx.x*blockDim.x + threadIdx.x;
  if (idx >= NL1*F1C*NM1) return;
  int l = idx/(F1C*NM1); int r = idx%(F1C*NM1); int o = r/NM1; int mi = r%NM1;
  float re = 0.f, im = 0.f;
  for (int g = 0; g < 24; ++g) {
    float w = psi1[o*24 + g];
    float2 y = Y1[(l*24+g)*NM1 + mi];
    re = fmaf(w, y.x, re); im = fmaf(w, y.y, im);
  }
  Psi1[idx] = make_float2(re, im);
}

// ---------------- K3: B[l][(i*11+k)][(o*11+n)] = sum_g psi2[i][o][g] * D2[l][g][k][n] ----------------
__global__ void k_psi2(const float* __restrict__ psi2, const float2* __restrict__ D2,
                       float2* __restrict__ Bm) {
  int idx = blockIdx.x*blockDim.x + threadIdx.x;
  if (idx >= NL2*F1C*F2C*NM2*NM2) return;
  int mn = idx % (NM2*NM2); int t1 = idx/(NM2*NM2);
  int o = t1 % F2C; int t2 = t1/F2C; int i = t2 % F1C; int l = t2/F1C;
  int k = mn / NM2, n = mn % NM2;
  float re = 0.f, im = 0.f;
  for (int g = 0; g < 144; ++g) {
    float w = psi2[(i*F2C + o)*144 + g];
    float2 dv = D2[(l*144 + g)*(NM2*NM2) + mn];
    re = fmaf(w, dv.x, re); im = fmaf(w, dv.y, im);
  }
  Bm[(size_t)l*GEMM_K*GEMM_N + (i*NM2 + k)*GEMM_N + o*NM2 + n] = make_float2(re, im);
}

// ---------------- K4: fused stage 1. Block per (z,o). Writes GEMM A layout [l2][z*11+m][o*11+n] ----------------
__global__ __launch_bounds__(256) void k_stage1(const float2* __restrict__ X,
                                                const float2* __restrict__ Psi1,
                                                const float* __restrict__ d1w,
                                                const float* __restrict__ d12w,
                                                float2* __restrict__ Am) {
  __shared__ float2 Xs[NL1*NM1];          // 190
  __shared__ float2 Ps[NL1*NM1];          // 190
  __shared__ float2 Esyn[NB1*NM1];        // [k][mi]  e^{+i 2pi k(mi-9)/20}
  __shared__ float2 Eana[NB1*NM2];        // [k][mi2] e^{-i 2pi k(mi2-5)/20}
  __shared__ float2 bufA[NBC*NM1*NM1];    // Fh[bb][m][n]; later aliased as y[bb][a][g] (float)
  __shared__ float2 bufB[NBC*NM1*NB1];    // Tt[bb][m][g]; later aliased as U[bb][m2][g]
  __shared__ float2 yfs[NBC*NM2*NM2];     // 605
  __shared__ float2 Fxa[NL2*NM2*NM2];     // 726

  const int z = blockIdx.x, o = blockIdx.y, t = threadIdx.x;

  for (int i = t; i < NB1*NM1; i += 256) {
    int k = i/NM1, mi = i%NM1;
    int r = (k*(mi-9)) % NB1; if (r < 0) r += NB1;
    float s, c; sincosf(2.f*PI_F*(float)r/(float)NB1, &s, &c);
    Esyn[i] = make_float2(c, s);
  }
  for (int i = t; i < NB1*NM2; i += 256) {
    int k = i/NM2, mi = i%NM2;
    int r = (k*(mi-5)) % NB1; if (r < 0) r += NB1;
    float s, c; sincosf(2.f*PI_F*(float)r/(float)NB1, &s, &c);
    Eana[i] = make_float2(c, -s);
  }
  for (int i = t; i < NL1*NM1; i += 256) {
    int l = i/NM1, mi = i%NM1;
    Xs[i] = X[(l*BATCH + z)*NM1 + mi];
    Ps[i] = Psi1[(l*F1C + o)*NM1 + mi];
  }
  for (int i = t; i < NL2*NM2*NM2; i += 256) Fxa[i] = make_float2(0.f, 0.f);
  __syncthreads();

  float*  yb = (float*)bufA;   // y[bb][a][g]  : NBC*400 floats <= 3610
  float2* Uu = bufB;           // U[bb][m2][g] : NBC*220 cplx  <= 1900

  for (int c = 0; c < NB1/NBC; ++c) {
    const int b0 = c*NBC;
    // phase1: Fh[bb][mn] = sum_l (Xs[l][m]*Ps[l][n]) * d1w[l][b0+bb][mn]
    for (int i = t; i < NBC*NM1*NM1; i += 256) {
      int bb = i/(NM1*NM1); int mn = i%(NM1*NM1);
      int m = mn/NM1, n = mn%NM1;
      float re = 0.f, im = 0.f;
      const float* dw = &d1w[(b0+bb)*(NM1*NM1) + mn];
      #pragma unroll
      for (int l = 0; l < NL1; ++l) {
        float2 xa = Xs[l*NM1+m], pp = Ps[l*NM1+n];
        float xr = xa.x*pp.x - xa.y*pp.y;
        float xi = xa.x*pp.y + xa.y*pp.x;
        float w = dw[l*(NB1*NM1*NM1)];
        re = fmaf(w, xr, re); im = fmaf(w, xi, im);
      }
      bufA[i] = make_float2(re, im);
    }
    __syncthreads();
    // phase2: Tt[bb][m][g] = sum_n Fh[bb][m][n] * Esyn[g][n]
    for (int i = t; i < NBC*NM1*NB1; i += 256) {
      int g = i % NB1; int r = i / NB1; int m = r % NM1; int bb = r / NM1;
      const float2* fh = &bufA[(bb*NM1 + m)*NM1];
      float re = 0.f, im = 0.f;
      #pragma unroll
      for (int n = 0; n < NM1; ++n) {
        float2 f = fh[n]; float2 e = Esyn[g*NM1+n];
        re += f.x*e.x - f.y*e.y;
        im += f.x*e.y + f.y*e.x;
      }
      bufB[i] = make_float2(re, im);
    }
    __syncthreads();
    // phase3: y[bb][a][g] = relu( Re sum_m Esyn[a][m] * Tt[bb][m][g] )
    for (int i = t; i < NBC*NB1*NB1; i += 256) {
      int g = i % NB1; int r = i / NB1; int aa = r % NB1; int bb = r / NB1;
      const float2* tt = &bufB[(bb*NM1)*NB1 + g];
      float v = 0.f;
      #pragma unroll
      for (int m = 0; m < NM1; ++m) {
        float2 tv = tt[m*NB1]; float2 e = Esyn[aa*NM1+m];
        v += e.x*tv.x - e.y*tv.y;
      }
      yb[i] = fmaxf(v, 0.f);
    }
    __syncthreads();
    // phase4: U[bb][m2][g] = sum_a y[bb][a][g] * Eana[a][m2]
    for (int i = t; i < NBC*NM2*NB1; i += 256) {
      int g = i % NB1; int r = i / NB1; int m2 = r % NM2; int bb = r / NM2;
      const float* yrow = &yb[(bb*NB1)*NB1 + g];
      float re = 0.f, im = 0.f;
      #pragma unroll
      for (int aa = 0; aa < NB1; ++aa) {
        float v = yrow[aa*NB1]; float2 e = Eana[aa*NM2+m2];
        re = fmaf(v, e.x, re); im = fmaf(v, e.y, im);
      }
      Uu[i] = make_float2(re, im);
    }
    __syncthreads();
    // phase5: yf[bb][m2][n2] = sum_g U[bb][m2][g] * Eana[g][n2]
    for (int i = t; i < NBC*NM2*NM2; i += 256) {
      int n2 = i % NM2; int r = i / NM2; int m2 = r % NM2; int bb = r / NM2;
      const float2* ur = &Uu[(bb*NM2+m2)*NB1];
      float re = 0.f, im = 0.f;
      #pragma unroll
      for (int g = 0; g < NB1; ++g) {
        float2 u = ur[g]; float2 e = Eana[g*NM2+n2];
        re += u.x*e.x - u.y*e.y;
        im += u.x*e.y + u.y*e.x;
      }
      yfs[i] = make_float2(re, im);
    }
    __syncthreads();
    // phase6: Fxa[l2][mn] += sum_bb d12w[l2][b0+bb][mn] * yf[bb][mn]
    for (int i = t; i < NL2*NM2*NM2; i += 256) {
      int l2 = i/(NM2*NM2); int mn = i%(NM2*NM2);
      float2 acc = Fxa[i];
      #pragma unroll
      for (int bb = 0; bb < NBC; ++bb) {
        float w = d12w[(l2*NB1 + b0 + bb)*(NM2*NM2) + mn];
        float2 v = yfs[bb*(NM2*NM2) + mn];
        acc.x = fmaf(w, v.x, acc.x); acc.y = fmaf(w, v.y, acc.y);
      }
      Fxa[i] = acc;
    }
    __syncthreads();
  }
  // write GEMM A: row = z*11+m, col = o*11+n, per l2
  for (int i = t; i < NL2*NM2*NM2; i += 256) {
    int l2 = i/(NM2*NM2); int mn = i%(NM2*NM2);
    int m = mn/NM2, n = mn%NM2;
    Am[(size_t)l2*GEMM_M*GEMM_K + (z*NM2 + m)*GEMM_K + o*NM2 + n] = Fxa[i];
  }
}

// ---------------- K5: per-l complex GEMM C[l][M][N] = A[l][M][K] * B[l][K][N] ----------------
__global__ __launch_bounds__(256) void k_so3mm(const float2* __restrict__ A,
                                               const float2* __restrict__ B,
                                               float2* __restrict__ C) {
  __shared__ float2 As[GM*GK];   // [m][k]
  __shared__ float2 Bs[GK*GN];   // [k][n]
  const int l = blockIdx.z;
  const int row0 = blockIdx.x*GM, col0 = blockIdx.y*GN;
  const int t = threadIdx.x;
  const float2* Ag = A + (size_t)l*GEMM_M*GEMM_K;
  const float2* Bg = B + (size_t)l*GEMM_K*GEMM_N;
  float2* Cg = C + (size_t)l*GEMM_M*GEMM_N;
  const int tn = t & 15, tm = t >> 4;   // 16x16 threads, 4x4 cplx each
  float2 acc[4][4];
  #pragma unroll
  for (int i = 0; i < 4; ++i)
    #pragma unroll
    for (int j = 0; j < 4; ++j) acc[i][j] = make_float2(0.f, 0.f);

  for (int k0 = 0; k0 < GEMM_K; k0 += GK) {
    for (int i = t; i < GM*GK; i += 256) {
      int r = i/GK, kk = i%GK;
      As[i] = Ag[(size_t)(row0 + r)*GEMM_K + k0 + kk];
    }
    for (int i = t; i < GK*GN; i += 256) {
      int kk = i/GN, cc = i%GN;
      int col = col0 + cc;
      Bs[i] = (col < GEMM_N) ? Bg[(size_t)(k0 + kk)*GEMM_N + col] : make_float2(0.f, 0.f);
    }
    __syncthreads();
    #pragma unroll
    for (int kk = 0; kk < GK; ++kk) {
      float2 a[4], b[4];
      #pragma unroll
      for (int i = 0; i < 4; ++i) a[i] = As[(tm*4 + i)*GK + kk];
      #pragma unroll
      for (int j = 0; j < 4; ++j) b[j] = Bs[kk*GN + tn*4 + j];
      #pragma unroll
      for (int i = 0; i < 4; ++i)
        #pragma unroll
        for (int j = 0; j < 4; ++j) {
          acc[i][j].x = fmaf(a[i].x, b[j].x, acc[i][j].x);
          acc[i][j].x = fmaf(-a[i].y, b[j].y, acc[i][j].x);
          acc[i][j].y = fmaf(a[i].x, b[j].y, acc[i][j].y);
          acc[i][j].y = fmaf(a[i].y, b[j].x, acc[i][j].y);
        }
    }
    __syncthreads();
  }
  #pragma unroll
  for (int i = 0; i < 4; ++i) {
    int r = row0 + tm*4 + i;
    #pragma unroll
    for (int j = 0; j < 4; ++j) {
      int cc = col0 + tn*4 + j;
      if (cc < GEMM_N) Cg[(size_t)r*GEMM_N + cc] = acc[i][j];
    }
  }
}

// ---------------- K6: fused stage 2 tail. Block per (z,o), beta fully parallel. ----------------
__global__ __launch_bounds__(256) void k_stage2(const float2* __restrict__ C,
                                                const float* __restrict__ d2w,
                                                const float* __restrict__ w2n,
                                                float* __restrict__ feat) {
  __shared__ float2 Fos[NL2*NM2*NM2];     // 726
  __shared__ float2 Fh2[NB2*NM2*NM2];     // 1452
  __shared__ float2 T2[NB2*NB2*NM2];      // 1584
  __shared__ float2 Esyn2[NB2*NM2];       // [k][mi] e^{+i 2pi k(mi-5)/12}
  __shared__ float w2s[NB2];
  __shared__ float red[256];
  const int z = blockIdx.x, o = blockIdx.y, t = threadIdx.x;
  for (int i = t; i < NB2*NM2; i += 256) {
    int k = i/NM2, mi = i%NM2;
    int r = (k*(mi-5)) % NB2; if (r < 0) r += NB2;
    float s, c; sincosf(2.f*PI_F*(float)r/(float)NB2, &s, &c);
    Esyn2[i] = make_float2(c, s);
  }
  if (t < NB2) w2s[t] = w2n[t];
  for (int i = t; i < NL2*NM2*NM2; i += 256) {
    int l = i/(NM2*NM2); int mn = i%(NM2*NM2);
    int m = mn/NM2, n = mn%NM2;
    Fos[i] = C[(size_t)l*GEMM_M*GEMM_N + (size_t)(z*NM2 + m)*GEMM_N + o*NM2 + n];
  }
  __syncthreads();
  // ph1: Fh2[b][mn] = sum_l d2w[l][b][mn]*Fos[l][mn]
  for (int i = t; i < NB2*NM2*NM2; i += 256) {
    int b = i/(NM2*NM2); int mn = i%(NM2*NM2);
    float re = 0.f, im = 0.f;
    #pragma unroll
    for (int l = 0; l < NL2; ++l) {
      float w = d2w[(l*NB2 + b)*(NM2*NM2) + mn];
      float2 v = Fos[l*(NM2*NM2) + mn];
      re = fmaf(w, v.x, re); im = fmaf(w, v.y, im);
    }
    Fh2[i] = make_float2(re, im);
  }
  __syncthreads();
  // ph2: T2[b][a][ni] = sum_mi Esyn2[a][mi]*Fh2[b][mi][ni]
  for (int i = t; i < NB2*NB2*NM2; i += 256) {
    int ni = i % NM2; int r = i / NM2; int aa = r % NB2; int b = r / NB2;
    const float2* fh = &Fh2[b*(NM2*NM2) + ni];
    float re = 0.f, im = 0.f;
    #pragma unroll
    for (int mi = 0; mi < NM2; ++mi) {
      float2 f = fh[mi*NM2]; float2 e = Esyn2[aa*NM2+mi];
      re += e.x*f.x - e.y*f.y;
      im += e.x*f.y + e.y*f.x;
    }
    T2[i] = make_float2(re, im);
  }
  __syncthreads();
  // ph3: accumulate w2s[b]*relu( Re sum_ni Esyn2[g][ni]*T2[b][a][ni] )
  float accT = 0.f;
  for (int i = t; i < NB2*NB2*NB2; i += 256) {
    int g = i % NB2; int r = i / NB2; int aa = r % NB2; int b = r / NB2;
    const float2* trow = &T2[(b*NB2 + aa)*NM2];
    float v = 0.f;
    #pragma unroll
    for (int ni = 0; ni < NM2; ++ni) {
      float2 tv = trow[ni]; float2 e = Esyn2[g*NM2+ni];
      v += e.x*tv.x - e.y*tv.y;
    }
    accT += w2s[b]*fmaxf(v, 0.f);
  }
  red[t] = accT;
  __syncthreads();
  for (int s = 128; s > 0; s >>= 1) {
    if (t < s) red[t] += red[t + s];
    __syncthreads();
  }
  if (t == 0) feat[z*F2C + o] = red[0] / (float)(NB2*NB2);
}

// ---------------- K7: linear head ----------------
__global__ void k_head(const float* __restrict__ feat, const float* __restrict__ w_lin,
                       const float* __restrict__ b_lin, float* __restrict__ out) {
  int idx = blockIdx.x*blockDim.x + threadIdx.x;
  if (idx >= BATCH*10) return;
  int z = idx/10, f = idx%10;
  float acc = b_lin[f];
  for (int o = 0; o < F2C; ++o) acc = fmaf(feat[z*F2C + o], w_lin[f*F2C + o], acc);
  out[idx] = acc;
}

extern "C" void kernel_launch(void* const* d_in, const int* in_sizes, int n_in,
                              void* d_out, int out_size, void* d_ws, size_t ws_size,
                              hipStream_t stream) {
  const float* x     = (const float*)d_in[0];
  const float* psi1  = (const float*)d_in[1];
  const float* psi2  = (const float*)d_in[2];
  const float* w_lin = (const float*)d_in[3];
  const float* b_lin = (const float*)d_in[4];
  float* out = (float*)d_out;
  float* ws  = (float*)d_ws;

  size_t off = 0;
  auto alloc = [&](size_t nfloats) { size_t o = off; off += (nfloats + 15) & ~(size_t)15; return o; };
  float*  wd_s2 = ws + alloc(N_WDS2);
  float2* Y1    = (float2*)(ws + alloc(2*(size_t)N_Y1));
  float*  d1w   = ws + alloc(N_D1W);
  float*  d12w  = ws + alloc(N_D12W);
  float2* D2    = (float2*)(ws + alloc(2*(size_t)N_D2));
  float*  d2w   = ws + alloc(N_D2W);
  float*  w2n   = ws + alloc(N_W2N);
  float2* X     = (float2*)(ws + alloc(2*(size_t)NL1*BATCH*NM1));
  float2* Psi1p = (float2*)(ws + alloc(2*(size_t)NL1*F1C*NM1));
  float2* Bmat  = (float2*)(ws + alloc(2*(size_t)NL2*GEMM_K*GEMM_N));
  float2* Amat  = (float2*)(ws + alloc(2*(size_t)NL2*GEMM_M*GEMM_K));
  float2* Cmat  = (float2*)(ws + alloc(2*(size_t)NL2*GEMM_M*GEMM_N));
  float*  featp = ws + alloc((size_t)BATCH*F2C);
  if (ws_size < off*sizeof(float)) return;

  const int total_c = N_WDS2 + N_Y1 + N_D1W + N_D12W + N_D2 + N_D2W + N_W2N;
  k_consts<<<(total_c + 255)/256, 256, 0, stream>>>(wd_s2, Y1, d1w, d12w, D2, d2w, w2n);
  k_s2fft<<<BATCH, 256, 0, stream>>>(x, wd_s2, X);
  k_psi1<<<(NL1*F1C*NM1 + 255)/256, 256, 0, stream>>>(psi1, Y1, Psi1p);
  k_psi2<<<(NL2*F1C*F2C*NM2*NM2 + 255)/256, 256, 0, stream>>>(psi2, D2, Bmat);
  k_stage1<<<dim3(BATCH, F1C), 256, 0, stream>>>(X, Psi1p, d1w, d12w, Amat);
  k_so3mm<<<dim3(GEMM_M/GM, (GEMM_N + GN - 1)/GN, NL2), 256, 0, stream>>>(Amat, Bmat, Cmat);
  k_stage2<<<dim3(BATCH, F2C), 256, 0, stream>>>(Cmat, d2w, w2n, featp);
  k_head<<<(BATCH*10 + 255)/256, 256, 0, stream>>>(featp, w_lin, b_lin, out);
}

// Round 4
// 527.987 us; speedup vs baseline: 2.0894x; 1.1794x over previous
//
#include <hip/hip_runtime.h>
#include <math.h>

#define PI_D 3.14159265358979323846
#define PI_F 3.14159265358979f

#define BATCH 128
#define NM1 19    // retained m freqs for B1 (m in [-9,9])
#define NM2 11    // retained freqs for B2 (m in [-5,5])
#define NB_IN 60  // 2*B_IN
#define NB1 20    // 2*B1
#define NB2 12    // 2*B2
#define NL1 10    // B1
#define NL2 6     // B2
#define F1C 20
#define F2C 40
#define NBC 5     // beta chunk for stage1

// GEMM dims for so3mm: per-l, C[M][N] += A[M][K]*B[K][N] complex
#define GEMM_M (BATCH*NM2)   // 1408
#define GEMM_N (F2C*NM2)     // 440
#define GEMM_K (F1C*NM2)     // 220
#define GM 64
#define GN 64
#define GK 20

// constant tensor element counts
#define N_WDS2 (NL1*NB_IN*NM1)     // 11400 f32
#define N_Y1   (NL1*24*NM1)        // 4560 cplx
#define N_D1W  (NL1*NB1*NM1*NM1)   // 72200 f32
#define N_D12W (NL2*NB1*NM2*NM2)   // 14520 f32
#define N_D2   (NL2*144*NM2*NM2)   // 104544 cplx
#define N_D2W  (NL2*NB2*NM2*NM2)   // 8712 f32
#define N_W2N  (NB2)               // 12 f32

// ---------------- device helpers for Wigner-d (fp64, matches numpy trace-time math) ----------------
__device__ __forceinline__ double ipow_d(double x, int e) {
  double r = 1.0;
  for (int i = 0; i < e; ++i) r *= x;
  return r;
}

__device__ double wigd(const double* lf, int l, int m, int n, double beta) {
  if (m < -l || m > l || n < -l || n > l) return 0.0;
  double cb = cos(0.5*beta), sb = sin(0.5*beta);
  double pref = 0.5*(lf[l+m]+lf[l-m]+lf[l+n]+lf[l-n]);
  int s0 = (n-m) > 0 ? (n-m) : 0;
  int s1 = (l+n) < (l-m) ? (l+n) : (l-m);
  double acc = 0.0;
  for (int s = s0; s <= s1; ++s) {
    double lc = pref - (lf[l+n-s]+lf[s]+lf[m-n+s]+lf[l-m-s]);
    double t = exp(lc) * ipow_d(cb, 2*l+n-m-2*s) * ipow_d(sb, m-n+2*s);
    acc += ((m-n+s) & 1) ? -t : t;
  }
  return acc;
}

__device__ __forceinline__ double dh_beta_d(int b, int k) { return PI_D*(2*k+1)/(4.0*b); }

__device__ double dh_w_d(int b, int k) {
  double beta = dh_beta_d(b, k), s = 0.0;
  for (int j = 0; j < b; ++j) s += sin((2.0*j+1.0)*beta)/(2.0*j+1.0);
  return (2.0/b)*sin(beta)*s;
}

// ---------------- constants kernel ----------------
__global__ void k_consts(float* __restrict__ wd_s2, float2* __restrict__ Y1,
                         float* __restrict__ d1w, float* __restrict__ d12w,
                         float2* __restrict__ D2, float* __restrict__ d2w,
                         float* __restrict__ w2n) {
  __shared__ double lf[41];
  int t = threadIdx.x;
  if (t < 41) lf[t] = lgamma((double)t + 1.0);
  __syncthreads();
  int gid = blockIdx.x*blockDim.x + t;

  if (gid < N_WDS2) {
    int l = gid/(NB_IN*NM1); int r = gid%(NB_IN*NM1); int k = r/NM1; int mi = r%NM1;
    int m = mi - 9;
    wd_s2[gid] = (float)(dh_w_d(30,k) * wigd(lf, l, m, 0, dh_beta_d(30,k)));
    return;
  }
  gid -= N_WDS2;
  if (gid < N_Y1) {
    int l = gid/(24*NM1); int r = gid%(24*NM1); int p = r/NM1; int mi = r%NM1;
    int m = mi - 9;
    double beta  = (double)(p/8 + 1) * PI_D/24.0;
    double alpha = 2.0*PI_D*(double)(p%8)/8.0;
    double d = wigd(lf, l, m, 0, beta);
    double ph = -(double)m*alpha;
    Y1[gid] = make_float2((float)(d*cos(ph)), (float)(d*sin(ph)));
    return;
  }
  gid -= N_Y1;
  if (gid < N_D1W) {
    int l = gid/(NB1*NM1*NM1); int r = gid%(NB1*NM1*NM1); int j = r/(NM1*NM1); int rr = r%(NM1*NM1);
    int m = rr/NM1 - 9, n = rr%NM1 - 9;
    d1w[gid] = (float)((double)(2*l+1) * wigd(lf, l, m, n, dh_beta_d(10,j)));
    return;
  }
  gid -= N_D1W;
  if (gid < N_D12W) {
    int l = gid/(NB1*NM2*NM2); int r = gid%(NB1*NM2*NM2); int j = r/(NM2*NM2); int rr = r%(NM2*NM2);
    int m = rr/NM2 - 5, n = rr%NM2 - 5;
    d12w[gid] = (float)(dh_w_d(10,j) * wigd(lf, l, m, n, dh_beta_d(10,j)));
    return;
  }
  gid -= N_D12W;
  if (gid < N_D2) {
    int l = gid/(144*NM2*NM2); int r = gid%(144*NM2*NM2); int p = r/(NM2*NM2); int rr = r%(NM2*NM2);
    int m = rr/NM2 - 5, n = rr%NM2 - 5;
    double beta  = (double)(p/48 + 1) * PI_D/24.0;
    double alpha = 2.0*PI_D*(double)((p/6)%8)/8.0;
    double gamma = 2.0*PI_D*(double)(p%6)/6.0;
    double d = wigd(lf, l, m, n, beta);
    double ph = -((double)m*alpha + (double)n*gamma);
    D2[gid] = make_float2((float)(d*cos(ph)), (float)(d*sin(ph)));
    return;
  }
  gid -= N_D2;
  if (gid < N_D2W) {
    int l = gid/(NB2*NM2*NM2); int r = gid%(NB2*NM2*NM2); int j = r/(NM2*NM2); int rr = r%(NM2*NM2);
    int m = rr/NM2 - 5, n = rr%NM2 - 5;
    d2w[gid] = (float)((double)(2*l+1) * wigd(lf, l, m, n, dh_beta_d(6,j)));
    return;
  }
  gid -= N_D2W;
  if (gid < N_W2N) {
    double s = 0.0;
    for (int j = 0; j < NB2; ++j) s += dh_w_d(6,j);
    w2n[gid] = (float)(dh_w_d(6,gid)/s);
    return;
  }
}

// ---------------- K1: azimuthal DFT (60pt, 19 freqs) + Legendre transform -> X[10][128][19] ----------------
__global__ __launch_bounds__(256) void k_s2fft(const float* __restrict__ x,
                                               const float* __restrict__ wd_s2,
                                               float2* __restrict__ X) {
  __shared__ float xs[3600];
  __shared__ float2 xf[NB_IN*NM1];
  __shared__ float2 tw60[NB_IN*NM1];   // [a][mi] = e^{-i 2pi a(mi-9)/60}
  const int z = blockIdx.x, t = threadIdx.x;
  for (int i = t; i < NB_IN*NM1; i += 256) {
    int a = i/NM1, mi = i%NM1;
    int r = (a*(mi-9)) % NB_IN; if (r < 0) r += NB_IN;
    float s, c; sincosf(2.f*PI_F*(float)r/(float)NB_IN, &s, &c);
    tw60[i] = make_float2(c, -s);
  }
  for (int i = t; i < 3600; i += 256) xs[i] = x[z*3600 + i];
  __syncthreads();
  for (int i = t; i < NB_IN*NM1; i += 256) {
    int k = i/NM1, mi = i%NM1;
    float re = 0.f, im = 0.f;
    const float* xrow = &xs[k*NB_IN];
    for (int a = 0; a < NB_IN; ++a) {
      float v = xrow[a];
      float2 e = tw60[a*NM1 + mi];
      re = fmaf(v, e.x, re);
      im = fmaf(v, e.y, im);
    }
    xf[i] = make_float2(re, im);
  }
  __syncthreads();
  for (int i = t; i < NL1*NM1; i += 256) {
    int l = i/NM1, mi = i%NM1;
    float re = 0.f, im = 0.f;
    for (int k = 0; k < NB_IN; ++k) {
      float w = wd_s2[(l*NB_IN+k)*NM1 + mi];
      float2 v = xf[k*NM1 + mi];
      re = fmaf(w, v.x, re); im = fmaf(w, v.y, im);
    }
    X[(l*BATCH + z)*NM1 + mi] = make_float2(re, im);
  }
}

// ---------------- K2: Psi1[l][o][m] = sum_g psi1[0][o][g] * Y1[l][g][m] ----------------
__global__ void k_psi1(const float* __restrict__ psi1, const float2* __restrict__ Y1,
                       float2* __restrict__ Psi1) {
  int idx = blockIdx.x*blockDim.x + threadIdx.x;
  if (idx >= NL1*F1C*NM1) return;
  int l = idx/(F1C*NM1); int r = idx%(F1C*NM1); int o = r/NM1; int mi = r%NM1;
  float re = 0.f, im = 0.f;
  for (int g = 0; g < 24; ++g) {
    float w = psi1[o*24 + g];
    float2 y = Y1[(l*24+g)*NM1 + mi];
    re = fmaf(w, y.x, re); im = fmaf(w, y.y, im);
  }
  Psi1[idx] = make_float2(re, im);
}

// ---------------- K3: B[l][(i*11+k)][(o*11+n)] = sum_g psi2[i][o][g] * D2[l][g][k][n] ----------------
__global__ void k_psi2(const float* __restrict__ psi2, const float2* __restrict__ D2,
                       float2* __restrict__ Bm) {
  int idx = blockIdx.x*blockDim.x + threadIdx.x;
  if (idx >= NL2*F1C*F2C*NM2*NM2) return;
  int mn = idx % (NM2*NM2); int t1 = idx/(NM2*NM2);
  int o = t1 % F2C; int t2 = t1/F2C; int i = t2 % F1C; int l = t2/F1C;
  int k = mn / NM2, n = mn % NM2;
  float re = 0.f, im = 0.f;
  for (int g = 0; g < 144; ++g) {
    float w = psi2[(i*F2C + o)*144 + g];
    float2 dv = D2[(l*144 + g)*(NM2*NM2) + mn];
    re = fmaf(w, dv.x, re); im = fmaf(w, dv.y, im);
  }
  Bm[(size_t)l*GEMM_K*GEMM_N + (i*NM2 + k)*GEMM_N + o*NM2 + n] = make_float2(re, im);
}

// ---------------- K4: fused stage 1, register-tiled phases. Block per (z,o). ----------------
__global__ __launch_bounds__(256) void k_stage1(const float2* __restrict__ X,
                                                const float2* __restrict__ Psi1,
                                                const float* __restrict__ d1w,
                                                const float* __restrict__ d12w,
                                                float2* __restrict__ Am) {
  __shared__ float2 Xs[NL1*NM1];                       // 190
  __shared__ float2 Ps[NL1*NM1];                       // 190
  __shared__ __align__(16) float2 EsynA[NB1*NM1];      // [a][m]  e^{+i 2pi a(m-9)/20}
  __shared__ __align__(16) float2 EsynT[NM1*NB1];      // [n][g]  e^{+i 2pi g(n-9)/20}
  __shared__ __align__(16) float2 Eana[NB1*NM2 + 2];   // [a][m2] e^{-i 2pi a(m2-5)/20}  (+pad)
  __shared__ __align__(16) float2 Fh[NBC*NM1*NM1];     // 1805  (aliased as yb floats later)
  __shared__ __align__(16) float2 Tt[NBC*NM1*NB1];     // 1900 [bb][m][g] (aliased as Uu later)
  __shared__ float2 yfs[NBC*NM2*NM2];                  // 605
  __shared__ float2 Fxa[NL2*NM2*NM2];                  // 726

  const int z = blockIdx.x, o = blockIdx.y, t = threadIdx.x;

  for (int i = t; i < NB1*NM1; i += 256) {
    int a = i/NM1, m = i%NM1;
    int r = (a*(m-9)) % NB1; if (r < 0) r += NB1;
    float s, c; sincosf(2.f*PI_F*(float)r/(float)NB1, &s, &c);
    EsynA[i] = make_float2(c, s);
    EsynT[m*NB1 + a] = make_float2(c, s);
  }
  for (int i = t; i < NB1*NM2; i += 256) {
    int k = i/NM2, mi = i%NM2;
    int r = (k*(mi-5)) % NB1; if (r < 0) r += NB1;
    float s, c; sincosf(2.f*PI_F*(float)r/(float)NB1, &s, &c);
    Eana[i] = make_float2(c, -s);
  }
  if (t < 2) Eana[NB1*NM2 + t] = make_float2(0.f, 0.f);
  for (int i = t; i < NL1*NM1; i += 256) {
    int l = i/NM1, mi = i%NM1;
    Xs[i] = X[(l*BATCH + z)*NM1 + mi];
    Ps[i] = Psi1[(l*F1C + o)*NM1 + mi];
  }
  for (int i = t; i < NL2*NM2*NM2; i += 256) Fxa[i] = make_float2(0.f, 0.f);
  __syncthreads();

  float*  yb = (float*)Fh;   // y[bb][a][g]  : NBC*400 floats <= 3610  (Fh dead after ph2)
  float2* Uu = Tt;           // U[bb][m2][g] : NBC*220 cplx  <= 1900   (Tt dead after ph3)

  for (int c = 0; c < NB1/NBC; ++c) {
    const int b0 = c*NBC;
    // phase1: Fh[bb][mn] = sum_l (Xs[l][m]*Ps[l][n]) * d1w[l][b0+bb][mn]
    for (int i = t; i < NBC*NM1*NM1; i += 256) {
      int bb = i/(NM1*NM1); int mn = i%(NM1*NM1);
      int m = mn/NM1, n = mn%NM1;
      float re = 0.f, im = 0.f;
      const float* dw = &d1w[(b0+bb)*(NM1*NM1) + mn];
      #pragma unroll
      for (int l = 0; l < NL1; ++l) {
        float2 xa = Xs[l*NM1+m], pp = Ps[l*NM1+n];
        float xr = xa.x*pp.x - xa.y*pp.y;
        float xi = xa.x*pp.y + xa.y*pp.x;
        float w = dw[l*(NB1*NM1*NM1)];
        re = fmaf(w, xr, re); im = fmaf(w, xi, im);
      }
      Fh[i] = make_float2(re, im);
    }
    __syncthreads();
    // phase2: Tt[bb][m][g] = sum_n Fh[bb][m][n]*EsynT[n][g], 4 g per thread (475 items)
    for (int i = t; i < NBC*NM1*5; i += 256) {
      int gq = i % 5; int r = i / 5; int m = r % NM1; int bb = r / NM1;
      int g0 = gq*4;
      const float2* fh = &Fh[(bb*NM1 + m)*NM1];
      float2 a0 = {0.f,0.f}, a1 = {0.f,0.f}, a2 = {0.f,0.f}, a3 = {0.f,0.f};
      #pragma unroll
      for (int n = 0; n < NM1; ++n) {
        float2 f = fh[n];
        float4 e01 = *(const float4*)&EsynT[n*NB1 + g0];
        float4 e23 = *(const float4*)&EsynT[n*NB1 + g0 + 2];
        a0.x += f.x*e01.x - f.y*e01.y; a0.y += f.x*e01.y + f.y*e01.x;
        a1.x += f.x*e01.z - f.y*e01.w; a1.y += f.x*e01.w + f.y*e01.z;
        a2.x += f.x*e23.x - f.y*e23.y; a2.y += f.x*e23.y + f.y*e23.x;
        a3.x += f.x*e23.z - f.y*e23.w; a3.y += f.x*e23.w + f.y*e23.z;
      }
      float2* tr = &Tt[(bb*NM1 + m)*NB1 + g0];
      tr[0] = a0; tr[1] = a1; tr[2] = a2; tr[3] = a3;
    }
    __syncthreads();
    // phase3: y[bb][a][g] = relu(Re sum_m EsynA[a][m]*Tt[bb][m][g]), 2a x 4g per thread (250 items)
    for (int i = t; i < NBC*10*5; i += 256) {
      int gq = i % 5; int r = i / 5; int ap = r % 10; int bb = r / 10;
      int a0 = ap*2, g0 = gq*4;
      float v00=0.f,v01=0.f,v02=0.f,v03=0.f, v10=0.f,v11=0.f,v12=0.f,v13=0.f;
      #pragma unroll
      for (int m = 0; m < NM1; ++m) {
        float4 t01 = *(const float4*)&Tt[(bb*NM1 + m)*NB1 + g0];
        float4 t23 = *(const float4*)&Tt[(bb*NM1 + m)*NB1 + g0 + 2];
        float2 e0 = EsynA[a0*NM1 + m];
        float2 e1 = EsynA[(a0+1)*NM1 + m];
        v00 += e0.x*t01.x - e0.y*t01.y;
        v01 += e0.x*t01.z - e0.y*t01.w;
        v02 += e0.x*t23.x - e0.y*t23.y;
        v03 += e0.x*t23.z - e0.y*t23.w;
        v10 += e1.x*t01.x - e1.y*t01.y;
        v11 += e1.x*t01.z - e1.y*t01.w;
        v12 += e1.x*t23.x - e1.y*t23.y;
        v13 += e1.x*t23.z - e1.y*t23.w;
      }
      float* y0 = &yb[(bb*NB1 + a0)*NB1 + g0];
      float* y1 = &yb[(bb*NB1 + a0 + 1)*NB1 + g0];
      y0[0]=fmaxf(v00,0.f); y0[1]=fmaxf(v01,0.f); y0[2]=fmaxf(v02,0.f); y0[3]=fmaxf(v03,0.f);
      y1[0]=fmaxf(v10,0.f); y1[1]=fmaxf(v11,0.f); y1[2]=fmaxf(v12,0.f); y1[3]=fmaxf(v13,0.f);
    }
    __syncthreads();
    // phase4: U[bb][m2][g] = sum_a y[bb][a][g]*Eana[a][m2], 4 g per thread (275 items)
    for (int i = t; i < NBC*NM2*5; i += 256) {
      int gq = i % 5; int r = i / 5; int m2 = r % NM2; int bb = r / NM2;
      int g0 = gq*4;
      float2 u0 = {0.f,0.f}, u1 = {0.f,0.f}, u2 = {0.f,0.f}, u3 = {0.f,0.f};
      #pragma unroll
      for (int aa = 0; aa < NB1; ++aa) {
        float4 y4 = *(const float4*)&yb[(bb*NB1 + aa)*NB1 + g0];
        float2 e = Eana[aa*NM2 + m2];
        u0.x = fmaf(y4.x, e.x, u0.x); u0.y = fmaf(y4.x, e.y, u0.y);
        u1.x = fmaf(y4.y, e.x, u1.x); u1.y = fmaf(y4.y, e.y, u1.y);
        u2.x = fmaf(y4.z, e.x, u2.x); u2.y = fmaf(y4.z, e.y, u2.y);
        u3.x = fmaf(y4.w, e.x, u3.x); u3.y = fmaf(y4.w, e.y, u3.y);
      }
      float2* ur = &Uu[(bb*NM2 + m2)*NB1 + g0];
      ur[0] = u0; ur[1] = u1; ur[2] = u2; ur[3] = u3;
    }
    __syncthreads();
    // phase5: yf[bb][m2][n2] = sum_g U[bb][m2][g]*Eana[g][n2], 2 n2 per thread (330 items)
    for (int i = t; i < NBC*NM2*6; i += 256) {
      int p = i % 6; int r = i / 6; int m2 = r % NM2; int bb = r / NM2;
      int n0 = p*2;
      const float2* ur = &Uu[(bb*NM2 + m2)*NB1];
      float2 acc0 = {0.f,0.f}, acc1 = {0.f,0.f};
      #pragma unroll
      for (int g = 0; g < NB1; ++g) {
        float2 u = ur[g];
        float2 ea = Eana[g*NM2 + n0];
        float2 eb = Eana[g*NM2 + n0 + 1];   // padded; unused result when n0==10
        acc0.x += u.x*ea.x - u.y*ea.y; acc0.y += u.x*ea.y + u.y*ea.x;
        acc1.x += u.x*eb.x - u.y*eb.y; acc1.y += u.x*eb.y + u.y*eb.x;
      }
      yfs[(bb*NM2 + m2)*NM2 + n0] = acc0;
      if (n0 + 1 < NM2) yfs[(bb*NM2 + m2)*NM2 + n0 + 1] = acc1;
    }
    __syncthreads();
    // phase6: Fxa[l2][mn] += sum_bb d12w[l2][b0+bb][mn] * yf[bb][mn]
    for (int i = t; i < NL2*NM2*NM2; i += 256) {
      int l2 = i/(NM2*NM2); int mn = i%(NM2*NM2);
      float2 acc = Fxa[i];
      #pragma unroll
      for (int bb = 0; bb < NBC; ++bb) {
        float w = d12w[(l2*NB1 + b0 + bb)*(NM2*NM2) + mn];
        float2 v = yfs[bb*(NM2*NM2) + mn];
        acc.x = fmaf(w, v.x, acc.x); acc.y = fmaf(w, v.y, acc.y);
      }
      Fxa[i] = acc;
    }
    __syncthreads();
  }
  // write GEMM A: row = z*11+m, col = o*11+n, per l2
  for (int i = t; i < NL2*NM2*NM2; i += 256) {
    int l2 = i/(NM2*NM2); int mn = i%(NM2*NM2);
    int m = mn/NM2, n = mn%NM2;
    Am[(size_t)l2*GEMM_M*GEMM_K + (z*NM2 + m)*GEMM_K + o*NM2 + n] = Fxa[i];
  }
}

// ---------------- K5: per-l complex GEMM C[l][M][N] = A[l][M][K] * B[l][K][N] ----------------
__global__ __launch_bounds__(256) void k_so3mm(const float2* __restrict__ A,
                                               const float2* __restrict__ B,
                                               float2* __restrict__ C) {
  __shared__ float2 As[GM*GK];   // [m][k]
  __shared__ float2 Bs[GK*GN];   // [k][n]
  const int l = blockIdx.z;
  const int row0 = blockIdx.x*GM, col0 = blockIdx.y*GN;
  const int t = threadIdx.x;
  const float2* Ag = A + (size_t)l*GEMM_M*GEMM_K;
  const float2* Bg = B + (size_t)l*GEMM_K*GEMM_N;
  float2* Cg = C + (size_t)l*GEMM_M*GEMM_N;
  const int tn = t & 15, tm = t >> 4;   // 16x16 threads, 4x4 cplx each
  float2 acc[4][4];
  #pragma unroll
  for (int i = 0; i < 4; ++i)
    #pragma unroll
    for (int j = 0; j < 4; ++j) acc[i][j] = make_float2(0.f, 0.f);

  for (int k0 = 0; k0 < GEMM_K; k0 += GK) {
    for (int i = t; i < GM*GK; i += 256) {
      int r = i/GK, kk = i%GK;
      As[i] = Ag[(size_t)(row0 + r)*GEMM_K + k0 + kk];
    }
    for (int i = t; i < GK*GN; i += 256) {
      int kk = i/GN, cc = i%GN;
      int col = col0 + cc;
      Bs[i] = (col < GEMM_N) ? Bg[(size_t)(k0 + kk)*GEMM_N + col] : make_float2(0.f, 0.f);
    }
    __syncthreads();
    #pragma unroll
    for (int kk = 0; kk < GK; ++kk) {
      float2 a[4], b[4];
      #pragma unroll
      for (int i = 0; i < 4; ++i) a[i] = As[(tm*4 + i)*GK + kk];
      #pragma unroll
      for (int j = 0; j < 4; ++j) b[j] = Bs[kk*GN + tn*4 + j];
      #pragma unroll
      for (int i = 0; i < 4; ++i)
        #pragma unroll
        for (int j = 0; j < 4; ++j) {
          acc[i][j].x = fmaf(a[i].x, b[j].x, acc[i][j].x);
          acc[i][j].x = fmaf(-a[i].y, b[j].y, acc[i][j].x);
          acc[i][j].y = fmaf(a[i].x, b[j].y, acc[i][j].y);
          acc[i][j].y = fmaf(a[i].y, b[j].x, acc[i][j].y);
        }
    }
    __syncthreads();
  }
  #pragma unroll
  for (int i = 0; i < 4; ++i) {
    int r = row0 + tm*4 + i;
    #pragma unroll
    for (int j = 0; j < 4; ++j) {
      int cc = col0 + tn*4 + j;
      if (cc < GEMM_N) Cg[(size_t)r*GEMM_N + cc] = acc[i][j];
    }
  }
}

// ---------------- K6: fused stage 2 tail. Block per (z,o), beta fully parallel. ----------------
__global__ __launch_bounds__(256) void k_stage2(const float2* __restrict__ C,
                                                const float* __restrict__ d2w,
                                                const float* __restrict__ w2n,
                                                float* __restrict__ feat) {
  __shared__ float2 Fos[NL2*NM2*NM2];     // 726
  __shared__ float2 Fh2[NB2*NM2*NM2];     // 1452
  __shared__ float2 T2[NB2*NB2*NM2];      // 1584
  __shared__ float2 Esyn2[NB2*NM2];       // [k][mi] e^{+i 2pi k(mi-5)/12}
  __shared__ float w2s[NB2];
  __shared__ float red[256];
  const int z = blockIdx.x, o = blockIdx.y, t = threadIdx.x;
  for (int i = t; i < NB2*NM2; i += 256) {
    int k = i/NM2, mi = i%NM2;
    int r = (k*(mi-5)) % NB2; if (r < 0) r += NB2;
    float s, c; sincosf(2.f*PI_F*(float)r/(float)NB2, &s, &c);
    Esyn2[i] = make_float2(c, s);
  }
  if (t < NB2) w2s[t] = w2n[t];
  for (int i = t; i < NL2*NM2*NM2; i += 256) {
    int l = i/(NM2*NM2); int mn = i%(NM2*NM2);
    int m = mn/NM2, n = mn%NM2;
    Fos[i] = C[(size_t)l*GEMM_M*GEMM_N + (size_t)(z*NM2 + m)*GEMM_N + o*NM2 + n];
  }
  __syncthreads();
  // ph1: Fh2[b][mn] = sum_l d2w[l][b][mn]*Fos[l][mn]
  for (int i = t; i < NB2*NM2*NM2; i += 256) {
    int b = i/(NM2*NM2); int mn = i%(NM2*NM2);
    float re = 0.f, im = 0.f;
    #pragma unroll
    for (int l = 0; l < NL2; ++l) {
      float w = d2w[(l*NB2 + b)*(NM2*NM2) + mn];
      float2 v = Fos[l*(NM2*NM2) + mn];
      re = fmaf(w, v.x, re); im = fmaf(w, v.y, im);
    }
    Fh2[i] = make_float2(re, im);
  }
  __syncthreads();
  // ph2: T2[b][a][ni] = sum_mi Esyn2[a][mi]*Fh2[b][mi][ni]
  for (int i = t; i < NB2*NB2*NM2; i += 256) {
    int ni = i % NM2; int r = i / NM2; int aa = r % NB2; int b = r / NB2;
    const float2* fh = &Fh2[b*(NM2*NM2) + ni];
    float re = 0.f, im = 0.f;
    #pragma unroll
    for (int mi = 0; mi < NM2; ++mi) {
      float2 f = fh[mi*NM2]; float2 e = Esyn2[aa*NM2+mi];
      re += e.x*f.x - e.y*f.y;
      im += e.x*f.y + e.y*f.x;
    }
    T2[i] = make_float2(re, im);
  }
  __syncthreads();
  // ph3: accumulate w2s[b]*relu( Re sum_ni Esyn2[g][ni]*T2[b][a][ni] )
  float accT = 0.f;
  for (int i = t; i < NB2*NB2*NB2; i += 256) {
    int g = i % NB2; int r = i / NB2; int aa = r % NB2; int b = r / NB2;
    const float2* trow = &T2[(b*NB2 + aa)*NM2];
    float v = 0.f;
    #pragma unroll
    for (int ni = 0; ni < NM2; ++ni) {
      float2 tv = trow[ni]; float2 e = Esyn2[g*NM2+ni];
      v += e.x*tv.x - e.y*tv.y;
    }
    accT += w2s[b]*fmaxf(v, 0.f);
  }
  red[t] = accT;
  __syncthreads();
  for (int s = 128; s > 0; s >>= 1) {
    if (t < s) red[t] += red[t + s];
    __syncthreads();
  }
  if (t == 0) feat[z*F2C + o] = red[0] / (float)(NB2*NB2);
}

// ---------------- K7: linear head ----------------
__global__ void k_head(const float* __restrict__ feat, const float* __restrict__ w_lin,
                       const float* __restrict__ b_lin, float* __restrict__ out) {
  int idx = blockIdx.x*blockDim.x + threadIdx.x;
  if (idx >= BATCH*10) return;
  int z = idx/10, f = idx%10;
  float acc = b_lin[f];
  for (int o = 0; o < F2C; ++o) acc = fmaf(feat[z*F2C + o], w_lin[f*F2C + o], acc);
  out[idx] = acc;
}

extern "C" void kernel_launch(void* const* d_in, const int* in_sizes, int n_in,
                              void* d_out, int out_size, void* d_ws, size_t ws_size,
                              hipStream_t stream) {
  const float* x     = (const float*)d_in[0];
  const float* psi1  = (const float*)d_in[1];
  const float* psi2  = (const float*)d_in[2];
  const float* w_lin = (const float*)d_in[3];
  const float* b_lin = (const float*)d_in[4];
  float* out = (float*)d_out;
  float* ws  = (float*)d_ws;

  size_t off = 0;
  auto alloc = [&](size_t nfloats) { size_t o = off; off += (nfloats + 15) & ~(size_t)15; return o; };
  float*  wd_s2 = ws + alloc(N_WDS2);
  float2* Y1    = (float2*)(ws + alloc(2*(size_t)N_Y1));
  float*  d1w   = ws + alloc(N_D1W);
  float*  d12w  = ws + alloc(N_D12W);
  float2* D2    = (float2*)(ws + alloc(2*(size_t)N_D2));
  float*  d2w   = ws + alloc(N_D2W);
  float*  w2n   = ws + alloc(N_W2N);
  float2* X     = (float2*)(ws + alloc(2*(size_t)NL1*BATCH*NM1));
  float2* Psi1p = (float2*)(ws + alloc(2*(size_t)NL1*F1C*NM1));
  float2* Bmat  = (float2*)(ws + alloc(2*(size_t)NL2*GEMM_K*GEMM_N));
  float2* Amat  = (float2*)(ws + alloc(2*(size_t)NL2*GEMM_M*GEMM_K));
  float2* Cmat  = (float2*)(ws + alloc(2*(size_t)NL2*GEMM_M*GEMM_N));
  float*  featp = ws + alloc((size_t)BATCH*F2C);
  if (ws_size < off*sizeof(float)) return;

  const int total_c = N_WDS2 + N_Y1 + N_D1W + N_D12W + N_D2 + N_D2W + N_W2N;
  k_consts<<<(total_c + 255)/256, 256, 0, stream>>>(wd_s2, Y1, d1w, d12w, D2, d2w, w2n);
  k_s2fft<<<BATCH, 256, 0, stream>>>(x, wd_s2, X);
  k_psi1<<<(NL1*F1C*NM1 + 255)/256, 256, 0, stream>>>(psi1, Y1, Psi1p);
  k_psi2<<<(NL2*F1C*F2C*NM2*NM2 + 255)/256, 256, 0, stream>>>(psi2, D2, Bmat);
  k_stage1<<<dim3(BATCH, F1C), 256, 0, stream>>>(X, Psi1p, d1w, d12w, Amat);
  k_so3mm<<<dim3(GEMM_M/GM, (GEMM_N + GN - 1)/GN, NL2), 256, 0, stream>>>(Amat, Bmat, Cmat);
  k_stage2<<<dim3(BATCH, F2C), 256, 0, stream>>>(Cmat, d2w, w2n, featp);
  k_head<<<(BATCH*10 + 255)/256, 256, 0, stream>>>(featp, w_lin, b_lin, out);
}

// Round 5
// 384.311 us; speedup vs baseline: 2.8706x; 1.3739x over previous
//
#include <hip/hip_runtime.h>
#include <math.h>

#define PI_D 3.14159265358979323846
#define PI_F 3.14159265358979f

#define BATCH 128
#define NM1 19    // full m range for B1 (m in [-9,9])
#define NMP1 10   // nonneg m freqs (m in [0,9])
#define NM2 11    // full freqs for B2 (m in [-5,5])
#define NMP2 6    // nonneg (m2 in [0,5])
#define NB_IN 60
#define NB1 20
#define NB2 12
#define NL1 10
#define NL2 6
#define F1C 20
#define F2C 40
#define NBC 5

// GEMM dims for so3mm: per-l, C[M][N] += A[M][K]*B[K][N] complex
#define GEMM_M (BATCH*NM2)   // 1408
#define GEMM_N (F2C*NM2)     // 440
#define GEMM_K (F1C*NM2)     // 220
#define GM 64
#define GN 64
#define GK 20

// constant tensor element counts
#define N_WDS2 (NL1*NB_IN*NM1)     // 11400 f32
#define N_Y1   (NL1*24*NM1)        // 4560 cplx
#define N_D1W  (NL1*NB1*NM1*NM1)   // 72200 f32
#define N_D12W (NL2*NB1*NM2*NM2)   // 14520 f32
#define N_D2   (NL2*144*NM2*NM2)   // 104544 cplx
#define N_D2W  (NL2*NB2*NM2*NM2)   // 8712 f32
#define N_W2N  (NB2)               // 12 f32

// ---------------- device helpers for Wigner-d (fp64, matches numpy trace-time math) ----------------
__device__ __forceinline__ double ipow_d(double x, int e) {
  double r = 1.0;
  for (int i = 0; i < e; ++i) r *= x;
  return r;
}

__device__ double wigd(const double* lf, int l, int m, int n, double beta) {
  if (m < -l || m > l || n < -l || n > l) return 0.0;
  double cb = cos(0.5*beta), sb = sin(0.5*beta);
  double pref = 0.5*(lf[l+m]+lf[l-m]+lf[l+n]+lf[l-n]);
  int s0 = (n-m) > 0 ? (n-m) : 0;
  int s1 = (l+n) < (l-m) ? (l+n) : (l-m);
  double acc = 0.0;
  for (int s = s0; s <= s1; ++s) {
    double lc = pref - (lf[l+n-s]+lf[s]+lf[m-n+s]+lf[l-m-s]);
    double t = exp(lc) * ipow_d(cb, 2*l+n-m-2*s) * ipow_d(sb, m-n+2*s);
    acc += ((m-n+s) & 1) ? -t : t;
  }
  return acc;
}

__device__ __forceinline__ double dh_beta_d(int b, int k) { return PI_D*(2*k+1)/(4.0*b); }

__device__ double dh_w_d(int b, int k) {
  double beta = dh_beta_d(b, k), s = 0.0;
  for (int j = 0; j < b; ++j) s += sin((2.0*j+1.0)*beta)/(2.0*j+1.0);
  return (2.0/b)*sin(beta)*s;
}

// ---------------- K0: quadrature weight tables (fp64) ----------------
__global__ void k_weights(double* __restrict__ dhw30, double* __restrict__ dhw10,
                          double* __restrict__ dhw6) {
  int t = threadIdx.x;
  if (t < 60) dhw30[t] = dh_w_d(30, t);
  else if (t < 80) dhw10[t-60] = dh_w_d(10, t-60);
  else if (t < 92) dhw6[t-80] = dh_w_d(6, t-80);
}

// ---------------- constants kernel ----------------
__global__ void k_consts(const double* __restrict__ dhw30, const double* __restrict__ dhw10,
                         const double* __restrict__ dhw6,
                         float* __restrict__ wd_s2, float2* __restrict__ Y1,
                         float* __restrict__ d1w, float* __restrict__ d12w,
                         float2* __restrict__ D2, float* __restrict__ d2w,
                         float* __restrict__ w2n) {
  __shared__ double lf[41];
  int t = threadIdx.x;
  if (t < 41) lf[t] = lgamma((double)t + 1.0);
  __syncthreads();
  int gid = blockIdx.x*blockDim.x + t;

  if (gid < N_WDS2) {
    int l = gid/(NB_IN*NM1); int r = gid%(NB_IN*NM1); int k = r/NM1; int mi = r%NM1;
    int m = mi - 9;
    wd_s2[gid] = (float)(dhw30[k] * wigd(lf, l, m, 0, dh_beta_d(30,k)));
    return;
  }
  gid -= N_WDS2;
  if (gid < N_Y1) {
    int l = gid/(24*NM1); int r = gid%(24*NM1); int p = r/NM1; int mi = r%NM1;
    int m = mi - 9;
    double beta  = (double)(p/8 + 1) * PI_D/24.0;
    double alpha = 2.0*PI_D*(double)(p%8)/8.0;
    double d = wigd(lf, l, m, 0, beta);
    double ph = -(double)m*alpha;
    Y1[gid] = make_float2((float)(d*cos(ph)), (float)(d*sin(ph)));
    return;
  }
  gid -= N_Y1;
  if (gid < N_D1W) {
    int l = gid/(NB1*NM1*NM1); int r = gid%(NB1*NM1*NM1); int j = r/(NM1*NM1); int rr = r%(NM1*NM1);
    int m = rr/NM1 - 9, n = rr%NM1 - 9;
    d1w[gid] = (float)((double)(2*l+1) * wigd(lf, l, m, n, dh_beta_d(10,j)));
    return;
  }
  gid -= N_D1W;
  if (gid < N_D12W) {
    int l = gid/(NB1*NM2*NM2); int r = gid%(NB1*NM2*NM2); int j = r/(NM2*NM2); int rr = r%(NM2*NM2);
    int m = rr/NM2 - 5, n = rr%NM2 - 5;
    d12w[gid] = (float)(dhw10[j] * wigd(lf, l, m, n, dh_beta_d(10,j)));
    return;
  }
  gid -= N_D12W;
  if (gid < N_D2) {
    int l = gid/(144*NM2*NM2); int r = gid%(144*NM2*NM2); int p = r/(NM2*NM2); int rr = r%(NM2*NM2);
    int m = rr/NM2 - 5, n = rr%NM2 - 5;
    double beta  = (double)(p/48 + 1) * PI_D/24.0;
    double alpha = 2.0*PI_D*(double)((p/6)%8)/8.0;
    double gamma = 2.0*PI_D*(double)(p%6)/6.0;
    double d = wigd(lf, l, m, n, beta);
    double ph = -((double)m*alpha + (double)n*gamma);
    D2[gid] = make_float2((float)(d*cos(ph)), (float)(d*sin(ph)));
    return;
  }
  gid -= N_D2;
  if (gid < N_D2W) {
    int l = gid/(NB2*NM2*NM2); int r = gid%(NB2*NM2*NM2); int j = r/(NM2*NM2); int rr = r%(NM2*NM2);
    int m = rr/NM2 - 5, n = rr%NM2 - 5;
    d2w[gid] = (float)((double)(2*l+1) * wigd(lf, l, m, n, dh_beta_d(6,j)));
    return;
  }
  gid -= N_D2W;
  if (gid < N_W2N) {
    double s = 0.0;
    for (int j = 0; j < NB2; ++j) s += dhw6[j];
    w2n[gid] = (float)(dhw6[gid]/s);
    return;
  }
}

// ---------------- K1: azimuthal DFT (60pt, 10 nonneg freqs) + Legendre -> X[10][128][10] ----------------
__global__ __launch_bounds__(256) void k_s2fft(const float* __restrict__ x,
                                               const float* __restrict__ wd_s2,
                                               float2* __restrict__ X) {
  __shared__ float xs[3600];
  __shared__ float2 xf[NB_IN*NMP1];
  __shared__ float2 tw60[NB_IN*NMP1];   // [a][mp] = e^{-i 2pi a mp/60}
  const int z = blockIdx.x, t = threadIdx.x;
  for (int i = t; i < NB_IN*NMP1; i += 256) {
    int a = i/NMP1, mp = i%NMP1;
    int r = (a*mp) % NB_IN;
    float s, c; sincosf(2.f*PI_F*(float)r/(float)NB_IN, &s, &c);
    tw60[i] = make_float2(c, -s);
  }
  for (int i = t; i < 3600; i += 256) xs[i] = x[z*3600 + i];
  __syncthreads();
  for (int i = t; i < NB_IN*NMP1; i += 256) {
    int k = i/NMP1, mp = i%NMP1;
    float re = 0.f, im = 0.f;
    const float* xrow = &xs[k*NB_IN];
    for (int a = 0; a < NB_IN; ++a) {
      float v = xrow[a];
      float2 e = tw60[a*NMP1 + mp];
      re = fmaf(v, e.x, re);
      im = fmaf(v, e.y, im);
    }
    xf[i] = make_float2(re, im);
  }
  __syncthreads();
  for (int i = t; i < NL1*NMP1; i += 256) {
    int l = i/NMP1, mp = i%NMP1;
    float re = 0.f, im = 0.f;
    for (int k = 0; k < NB_IN; ++k) {
      float w = wd_s2[(l*NB_IN+k)*NM1 + mp + 9];
      float2 v = xf[k*NMP1 + mp];
      re = fmaf(w, v.x, re); im = fmaf(w, v.y, im);
    }
    X[(l*BATCH + z)*NMP1 + mp] = make_float2(re, im);
  }
}

// ---------------- K2: Psi1[l][o][m] = sum_g psi1[0][o][g] * Y1[l][g][m]  (full m range) ----------------
__global__ void k_psi1(const float* __restrict__ psi1, const float2* __restrict__ Y1,
                       float2* __restrict__ Psi1) {
  int idx = blockIdx.x*blockDim.x + threadIdx.x;
  if (idx >= NL1*F1C*NM1) return;
  int l = idx/(F1C*NM1); int r = idx%(F1C*NM1); int o = r/NM1; int mi = r%NM1;
  float re = 0.f, im = 0.f;
  for (int g = 0; g < 24; ++g) {
    float w = psi1[o*24 + g];
    float2 y = Y1[(l*24+g)*NM1 + mi];
    re = fmaf(w, y.x, re); im = fmaf(w, y.y, im);
  }
  Psi1[idx] = make_float2(re, im);
}

// ---------------- K3: B[l][(i*11+k)][(o*11+n)] = sum_g psi2[i][o][g] * D2[l][g][k][n] ----------------
__global__ void k_psi2(const float* __restrict__ psi2, const float2* __restrict__ D2,
                       float2* __restrict__ Bm) {
  int idx = blockIdx.x*blockDim.x + threadIdx.x;
  if (idx >= NL2*F1C*F2C*NM2*NM2) return;
  int mn = idx % (NM2*NM2); int t1 = idx/(NM2*NM2);
  int o = t1 % F2C; int t2 = t1/F2C; int i = t2 % F1C; int l = t2/F1C;
  int k = mn / NM2, n = mn % NM2;
  float re = 0.f, im = 0.f;
  for (int g = 0; g < 144; ++g) {
    float w = psi2[(i*F2C + o)*144 + g];
    float2 dv = D2[(l*144 + g)*(NM2*NM2) + mn];
    re = fmaf(w, dv.x, re); im = fmaf(w, dv.y, im);
  }
  Bm[(size_t)l*GEMM_K*GEMM_N + (i*NM2 + k)*GEMM_N + o*NM2 + n] = make_float2(re, im);
}

// ---------------- K4: fused stage 1, Hermitian-halved. Block per (z,o). ----------------
__global__ __launch_bounds__(256) void k_stage1(const float2* __restrict__ X,
                                                const float2* __restrict__ Psi1,
                                                const float* __restrict__ d1w,
                                                const float* __restrict__ d12w,
                                                float2* __restrict__ Am) {
  __shared__ float2 Xs[NL1*NMP1];                      // 100, m>=0 only
  __shared__ float2 Ps[NL1*NM1];                       // 190, full n
  __shared__ __align__(16) float2 EsynT[NM1*NB1];      // [n][g]  e^{+i 2pi g(n-9)/20}   380
  __shared__ __align__(16) float2 EsynA[NB1*NMP1];     // [a][mp] e^{+i 2pi a mp/20}     200
  __shared__ __align__(16) float2 EanaA[NB1*NMP2];     // [a][m2p] e^{-i 2pi a m2p/20}   120
  __shared__ __align__(16) float2 EanaG[NB1*12];       // [g][n2i] e^{-i 2pi g(n2i-5)/20}, col11=0  240
  __shared__ __align__(16) float2 bufA[NBC*200];       // Fh[bb][mp][n] (950) / yb floats (2000f)
  __shared__ __align__(16) float2 bufB[NBC*200];       // Tt[bb][mp][g] (1000) / Uu[bb][m2p][g] (600)
  __shared__ float2 yfs[NBC*NMP2*NM2];                 // 330: yf rows m2>=0
  __shared__ float2 Fxa[NL2*NM2*NM2];                  // 726

  const int z = blockIdx.x, o = blockIdx.y, t = threadIdx.x;

  for (int i = t; i < NM1*NB1; i += 256) {
    int n = i/NB1, g = i%NB1;
    int r = (g*(n-9)) % NB1; if (r < 0) r += NB1;
    float s, c; sincosf(2.f*PI_F*(float)r/(float)NB1, &s, &c);
    EsynT[i] = make_float2(c, s);
  }
  for (int i = t; i < NB1*NMP1; i += 256) {
    int a = i/NMP1, mp = i%NMP1;
    int r = (a*mp) % NB1;
    float s, c; sincosf(2.f*PI_F*(float)r/(float)NB1, &s, &c);
    EsynA[i] = make_float2(c, s);
  }
  for (int i = t; i < NB1*NMP2; i += 256) {
    int a = i/NMP2, m2p = i%NMP2;
    int r = (a*m2p) % NB1;
    float s, c; sincosf(2.f*PI_F*(float)r/(float)NB1, &s, &c);
    EanaA[i] = make_float2(c, -s);
  }
  for (int i = t; i < NB1*12; i += 256) {
    int g = i/12, cI = i%12;
    if (cI == 11) { EanaG[i] = make_float2(0.f, 0.f); }
    else {
      int r = (g*(cI-5)) % NB1; if (r < 0) r += NB1;
      float s, c; sincosf(2.f*PI_F*(float)r/(float)NB1, &s, &c);
      EanaG[i] = make_float2(c, -s);
    }
  }
  for (int i = t; i < NL1*NMP1; i += 256) {
    int l = i/NMP1, mp = i%NMP1;
    Xs[i] = X[(l*BATCH + z)*NMP1 + mp];
  }
  for (int i = t; i < NL1*NM1; i += 256) {
    int l = i/NM1, mi = i%NM1;
    Ps[i] = Psi1[(l*F1C + o)*NM1 + mi];
  }
  for (int i = t; i < NL2*NM2*NM2; i += 256) Fxa[i] = make_float2(0.f, 0.f);
  __syncthreads();

  float2* Fh = bufA;           // [bb][mp][n] : NBC*10*19 = 950
  float2* Tt = bufB;           // [bb][mp][g] : NBC*10*20 = 1000
  float*  yb = (float*)bufA;   // [bb][a][g]  : NBC*400 = 2000 floats
  float2* Uu = bufB;           // [bb][m2p][g]: NBC*6*20 = 600

  for (int c = 0; c < NB1/NBC; ++c) {
    const int b0 = c*NBC;
    // ph1: Fh[bb][mp][n] = sum_l Xs[l][mp]*Ps[l][n]*d1w[l][b][mp+9][n], mp>=0
    for (int i = t; i < NBC*NMP1*NM1; i += 256) {
      int bb = i/(NMP1*NM1); int rr = i%(NMP1*NM1);
      int mp = rr/NM1, n = rr%NM1;
      float re = 0.f, im = 0.f;
      const float* dw = &d1w[(b0+bb)*(NM1*NM1) + (mp+9)*NM1 + n];
      #pragma unroll
      for (int l = 0; l < NL1; ++l) {
        float2 xa = Xs[l*NMP1+mp], pp = Ps[l*NM1+n];
        float xr = xa.x*pp.x - xa.y*pp.y;
        float xi = xa.x*pp.y + xa.y*pp.x;
        float w = dw[l*(NB1*NM1*NM1)];
        re = fmaf(w, xr, re); im = fmaf(w, xi, im);
      }
      Fh[(bb*NMP1 + mp)*NM1 + n] = make_float2(re, im);
    }
    __syncthreads();
    // ph2: Tt[bb][mp][g] = sum_n Fh[bb][mp][n]*EsynT[n][g], 4 g per thread (250 items)
    for (int i = t; i < NBC*NMP1*5; i += 256) {
      int gq = i % 5; int r = i / 5; int mp = r % NMP1; int bb = r / NMP1;
      int g0 = gq*4;
      const float2* fh = &Fh[(bb*NMP1 + mp)*NM1];
      float2 a0 = {0.f,0.f}, a1 = {0.f,0.f}, a2 = {0.f,0.f}, a3 = {0.f,0.f};
      #pragma unroll
      for (int n = 0; n < NM1; ++n) {
        float2 f = fh[n];
        float4 e01 = *(const float4*)&EsynT[n*NB1 + g0];
        float4 e23 = *(const float4*)&EsynT[n*NB1 + g0 + 2];
        a0.x += f.x*e01.x - f.y*e01.y; a0.y += f.x*e01.y + f.y*e01.x;
        a1.x += f.x*e01.z - f.y*e01.w; a1.y += f.x*e01.w + f.y*e01.z;
        a2.x += f.x*e23.x - f.y*e23.y; a2.y += f.x*e23.y + f.y*e23.x;
        a3.x += f.x*e23.z - f.y*e23.w; a3.y += f.x*e23.w + f.y*e23.z;
      }
      float2* tr = &Tt[(bb*NMP1 + mp)*NB1 + g0];
      tr[0] = a0; tr[1] = a1; tr[2] = a2; tr[3] = a3;
    }
    __syncthreads();
    // ph3: y[bb][a][g] = relu( Tt[bb][0][g].x + 2*sum_{mp=1..9} Re(EsynA[a][mp]*Tt[bb][mp][g]) )
    //      2a x 4g per thread (250 items)
    for (int i = t; i < NBC*10*5; i += 256) {
      int gq = i % 5; int r = i / 5; int ap = r % 10; int bb = r / 10;
      int a0 = ap*2, g0 = gq*4;
      float4 t01 = *(const float4*)&Tt[(bb*NMP1)*NB1 + g0];       // mp = 0
      float4 t23 = *(const float4*)&Tt[(bb*NMP1)*NB1 + g0 + 2];
      float s00=0.f,s01=0.f,s02=0.f,s03=0.f, s10=0.f,s11=0.f,s12=0.f,s13=0.f;
      #pragma unroll
      for (int mp = 1; mp < NMP1; ++mp) {
        float4 u01 = *(const float4*)&Tt[(bb*NMP1 + mp)*NB1 + g0];
        float4 u23 = *(const float4*)&Tt[(bb*NMP1 + mp)*NB1 + g0 + 2];
        float2 e0 = EsynA[a0*NMP1 + mp];
        float2 e1 = EsynA[(a0+1)*NMP1 + mp];
        s00 += e0.x*u01.x - e0.y*u01.y;
        s01 += e0.x*u01.z - e0.y*u01.w;
        s02 += e0.x*u23.x - e0.y*u23.y;
        s03 += e0.x*u23.z - e0.y*u23.w;
        s10 += e1.x*u01.x - e1.y*u01.y;
        s11 += e1.x*u01.z - e1.y*u01.w;
        s12 += e1.x*u23.x - e1.y*u23.y;
        s13 += e1.x*u23.z - e1.y*u23.w;
      }
      float* y0 = &yb[(bb*NB1 + a0)*NB1 + g0];
      float* y1 = &yb[(bb*NB1 + a0 + 1)*NB1 + g0];
      y0[0]=fmaxf(fmaf(2.f,s00,t01.x),0.f); y0[1]=fmaxf(fmaf(2.f,s01,t01.z),0.f);
      y0[2]=fmaxf(fmaf(2.f,s02,t23.x),0.f); y0[3]=fmaxf(fmaf(2.f,s03,t23.z),0.f);
      y1[0]=fmaxf(fmaf(2.f,s10,t01.x),0.f); y1[1]=fmaxf(fmaf(2.f,s11,t01.z),0.f);
      y1[2]=fmaxf(fmaf(2.f,s12,t23.x),0.f); y1[3]=fmaxf(fmaf(2.f,s13,t23.z),0.f);
    }
    __syncthreads();
    // ph4: U[bb][m2p][g] = sum_a y[bb][a][g]*EanaA[a][m2p], m2>=0, 4 g per thread (150 items)
    for (int i = t; i < NBC*NMP2*5; i += 256) {
      int gq = i % 5; int r = i / 5; int m2p = r % NMP2; int bb = r / NMP2;
      int g0 = gq*4;
      float2 u0 = {0.f,0.f}, u1 = {0.f,0.f}, u2 = {0.f,0.f}, u3 = {0.f,0.f};
      #pragma unroll
      for (int aa = 0; aa < NB1; ++aa) {
        float4 y4 = *(const float4*)&yb[(bb*NB1 + aa)*NB1 + g0];
        float2 e = EanaA[aa*NMP2 + m2p];
        u0.x = fmaf(y4.x, e.x, u0.x); u0.y = fmaf(y4.x, e.y, u0.y);
        u1.x = fmaf(y4.y, e.x, u1.x); u1.y = fmaf(y4.y, e.y, u1.y);
        u2.x = fmaf(y4.z, e.x, u2.x); u2.y = fmaf(y4.z, e.y, u2.y);
        u3.x = fmaf(y4.w, e.x, u3.x); u3.y = fmaf(y4.w, e.y, u3.y);
      }
      float2* ur = &Uu[(bb*NMP2 + m2p)*NB1 + g0];
      ur[0] = u0; ur[1] = u1; ur[2] = u2; ur[3] = u3;
    }
    __syncthreads();
    // ph5: yf[bb][m2p][n2] = sum_g U[bb][m2p][g]*EanaG[g][n2], 2 n2 per thread (180 items)
    for (int i = t; i < NBC*NMP2*6; i += 256) {
      int p = i % 6; int r = i / 6; int m2p = r % NMP2; int bb = r / NMP2;
      int n0 = p*2;
      const float2* ur = &Uu[(bb*NMP2 + m2p)*NB1];
      float2 acc0 = {0.f,0.f}, acc1 = {0.f,0.f};
      #pragma unroll
      for (int g = 0; g < NB1; ++g) {
        float2 u = ur[g];
        float4 e = *(const float4*)&EanaG[g*12 + n0];
        acc0.x += u.x*e.x - u.y*e.y; acc0.y += u.x*e.y + u.y*e.x;
        acc1.x += u.x*e.z - u.y*e.w; acc1.y += u.x*e.w + u.y*e.z;
      }
      yfs[(bb*NMP2 + m2p)*NM2 + n0] = acc0;
      if (n0 + 1 < NM2) yfs[(bb*NMP2 + m2p)*NM2 + n0 + 1] = acc1;
    }
    __syncthreads();
    // ph6: Fxa[l2][m2i][n2i] += sum_bb d12w * yf (negative m2 rows via conj-mirror)
    for (int i = t; i < NL2*NM2*NM2; i += 256) {
      int l2 = i/(NM2*NM2); int mn = i%(NM2*NM2);
      int m2i = mn/NM2, n2i = mn%NM2;
      int src; float sgn;
      if (m2i >= 5) { src = (m2i-5)*NM2 + n2i; sgn = 1.f; }
      else          { src = (5-m2i)*NM2 + (10-n2i); sgn = -1.f; }
      float2 acc = Fxa[i];
      #pragma unroll
      for (int bb = 0; bb < NBC; ++bb) {
        float w = d12w[(l2*NB1 + b0 + bb)*(NM2*NM2) + mn];
        float2 v = yfs[bb*(NMP2*NM2) + src];
        acc.x = fmaf(w, v.x, acc.x);
        acc.y = fmaf(w, sgn*v.y, acc.y);
      }
      Fxa[i] = acc;
    }
    __syncthreads();
  }
  // write GEMM A: row = z*11+m, col = o*11+n, per l2
  for (int i = t; i < NL2*NM2*NM2; i += 256) {
    int l2 = i/(NM2*NM2); int mn = i%(NM2*NM2);
    int m = mn/NM2, n = mn%NM2;
    Am[(size_t)l2*GEMM_M*GEMM_K + (z*NM2 + m)*GEMM_K + o*NM2 + n] = Fxa[i];
  }
}

// ---------------- K5: per-l complex GEMM C[l][M][N] = A[l][M][K] * B[l][K][N] ----------------
__global__ __launch_bounds__(256) void k_so3mm(const float2* __restrict__ A,
                                               const float2* __restrict__ B,
                                               float2* __restrict__ C) {
  __shared__ float2 As[GM*GK];   // [m][k]
  __shared__ float2 Bs[GK*GN];   // [k][n]
  const int l = blockIdx.z;
  const int row0 = blockIdx.x*GM, col0 = blockIdx.y*GN;
  const int t = threadIdx.x;
  const float2* Ag = A + (size_t)l*GEMM_M*GEMM_K;
  const float2* Bg = B + (size_t)l*GEMM_K*GEMM_N;
  float2* Cg = C + (size_t)l*GEMM_M*GEMM_N;
  const int tn = t & 15, tm = t >> 4;   // 16x16 threads, 4x4 cplx each
  float2 acc[4][4];
  #pragma unroll
  for (int i = 0; i < 4; ++i)
    #pragma unroll
    for (int j = 0; j < 4; ++j) acc[i][j] = make_float2(0.f, 0.f);

  for (int k0 = 0; k0 < GEMM_K; k0 += GK) {
    for (int i = t; i < GM*GK; i += 256) {
      int r = i/GK, kk = i%GK;
      As[i] = Ag[(size_t)(row0 + r)*GEMM_K + k0 + kk];
    }
    for (int i = t; i < GK*GN; i += 256) {
      int kk = i/GN, cc = i%GN;
      int col = col0 + cc;
      Bs[i] = (col < GEMM_N) ? Bg[(size_t)(k0 + kk)*GEMM_N + col] : make_float2(0.f, 0.f);
    }
    __syncthreads();
    #pragma unroll
    for (int kk = 0; kk < GK; ++kk) {
      float2 a[4], b[4];
      #pragma unroll
      for (int i = 0; i < 4; ++i) a[i] = As[(tm*4 + i)*GK + kk];
      #pragma unroll
      for (int j = 0; j < 4; ++j) b[j] = Bs[kk*GN + tn*4 + j];
      #pragma unroll
      for (int i = 0; i < 4; ++i)
        #pragma unroll
        for (int j = 0; j < 4; ++j) {
          acc[i][j].x = fmaf(a[i].x, b[j].x, acc[i][j].x);
          acc[i][j].x = fmaf(-a[i].y, b[j].y, acc[i][j].x);
          acc[i][j].y = fmaf(a[i].x, b[j].y, acc[i][j].y);
          acc[i][j].y = fmaf(a[i].y, b[j].x, acc[i][j].y);
        }
    }
    __syncthreads();
  }
  #pragma unroll
  for (int i = 0; i < 4; ++i) {
    int r = row0 + tm*4 + i;
    #pragma unroll
    for (int j = 0; j < 4; ++j) {
      int cc = col0 + tn*4 + j;
      if (cc < GEMM_N) Cg[(size_t)r*GEMM_N + cc] = acc[i][j];
    }
  }
}

// ---------------- K6: fused stage 2 tail. Block per (z,o), beta fully parallel. ----------------
__global__ __launch_bounds__(256) void k_stage2(const float2* __restrict__ C,
                                                const float* __restrict__ d2w,
                                                const float* __restrict__ w2n,
                                                float* __restrict__ feat) {
  __shared__ float2 Fos[NL2*NM2*NM2];     // 726
  __shared__ float2 Fh2[NB2*NM2*NM2];     // 1452
  __shared__ float2 T2[NB2*NB2*NM2];      // 1584
  __shared__ float2 Esyn2[NB2*NM2];       // [k][mi] e^{+i 2pi k(mi-5)/12}
  __shared__ float w2s[NB2];
  __shared__ float red[256];
  const int z = blockIdx.x, o = blockIdx.y, t = threadIdx.x;
  for (int i = t; i < NB2*NM2; i += 256) {
    int k = i/NM2, mi = i%NM2;
    int r = (k*(mi-5)) % NB2; if (r < 0) r += NB2;
    float s, c; sincosf(2.f*PI_F*(float)r/(float)NB2, &s, &c);
    Esyn2[i] = make_float2(c, s);
  }
  if (t < NB2) w2s[t] = w2n[t];
  for (int i = t; i < NL2*NM2*NM2; i += 256) {
    int l = i/(NM2*NM2); int mn = i%(NM2*NM2);
    int m = mn/NM2, n = mn%NM2;
    Fos[i] = C[(size_t)l*GEMM_M*GEMM_N + (size_t)(z*NM2 + m)*GEMM_N + o*NM2 + n];
  }
  __syncthreads();
  // ph1: Fh2[b][mn] = sum_l d2w[l][b][mn]*Fos[l][mn]
  for (int i = t; i < NB2*NM2*NM2; i += 256) {
    int b = i/(NM2*NM2); int mn = i%(NM2*NM2);
    float re = 0.f, im = 0.f;
    #pragma unroll
    for (int l = 0; l < NL2; ++l) {
      float w = d2w[(l*NB2 + b)*(NM2*NM2) + mn];
      float2 v = Fos[l*(NM2*NM2) + mn];
      re = fmaf(w, v.x, re); im = fmaf(w, v.y, im);
    }
    Fh2[i] = make_float2(re, im);
  }
  __syncthreads();
  // ph2: T2[b][a][ni] = sum_mi Esyn2[a][mi]*Fh2[b][mi][ni]
  for (int i = t; i < NB2*NB2*NM2; i += 256) {
    int ni = i % NM2; int r = i / NM2; int aa = r % NB2; int b = r / NB2;
    const float2* fh = &Fh2[b*(NM2*NM2) + ni];
    float re = 0.f, im = 0.f;
    #pragma unroll
    for (int mi = 0; mi < NM2; ++mi) {
      float2 f = fh[mi*NM2]; float2 e = Esyn2[aa*NM2+mi];
      re += e.x*f.x - e.y*f.y;
      im += e.x*f.y + e.y*f.x;
    }
    T2[i] = make_float2(re, im);
  }
  __syncthreads();
  // ph3: accumulate w2s[b]*relu( Re sum_ni Esyn2[g][ni]*T2[b][a][ni] )
  float accT = 0.f;
  for (int i = t; i < NB2*NB2*NB2; i += 256) {
    int g = i % NB2; int r = i / NB2; int aa = r % NB2; int b = r / NB2;
    const float2* trow = &T2[(b*NB2 + aa)*NM2];
    float v = 0.f;
    #pragma unroll
    for (int ni = 0; ni < NM2; ++ni) {
      float2 tv = trow[ni]; float2 e = Esyn2[g*NM2+ni];
      v += e.x*tv.x - e.y*tv.y;
    }
    accT += w2s[b]*fmaxf(v, 0.f);
  }
  red[t] = accT;
  __syncthreads();
  for (int s = 128; s > 0; s >>= 1) {
    if (t < s) red[t] += red[t + s];
    __syncthreads();
  }
  if (t == 0) feat[z*F2C + o] = red[0] / (float)(NB2*NB2);
}

// ---------------- K7: linear head ----------------
__global__ void k_head(const float* __restrict__ feat, const float* __restrict__ w_lin,
                       const float* __restrict__ b_lin, float* __restrict__ out) {
  int idx = blockIdx.x*blockDim.x + threadIdx.x;
  if (idx >= BATCH*10) return;
  int z = idx/10, f = idx%10;
  float acc = b_lin[f];
  for (int o = 0; o < F2C; ++o) acc = fmaf(feat[z*F2C + o], w_lin[f*F2C + o], acc);
  out[idx] = acc;
}

extern "C" void kernel_launch(void* const* d_in, const int* in_sizes, int n_in,
                              void* d_out, int out_size, void* d_ws, size_t ws_size,
                              hipStream_t stream) {
  const float* x     = (const float*)d_in[0];
  const float* psi1  = (const float*)d_in[1];
  const float* psi2  = (const float*)d_in[2];
  const float* w_lin = (const float*)d_in[3];
  const float* b_lin = (const float*)d_in[4];
  float* out = (float*)d_out;
  float* ws  = (float*)d_ws;

  size_t off = 0;
  auto alloc = [&](size_t nfloats) { size_t o = off; off += (nfloats + 15) & ~(size_t)15; return o; };
  double* dhw30 = (double*)(ws + alloc(2*60));
  double* dhw10 = (double*)(ws + alloc(2*20));
  double* dhw6  = (double*)(ws + alloc(2*12));
  float*  wd_s2 = ws + alloc(N_WDS2);
  float2* Y1    = (float2*)(ws + alloc(2*(size_t)N_Y1));
  float*  d1w   = ws + alloc(N_D1W);
  float*  d12w  = ws + alloc(N_D12W);
  float2* D2    = (float2*)(ws + alloc(2*(size_t)N_D2));
  float*  d2w   = ws + alloc(N_D2W);
  float*  w2n   = ws + alloc(N_W2N);
  float2* X     = (float2*)(ws + alloc(2*(size_t)NL1*BATCH*NMP1));
  float2* Psi1p = (float2*)(ws + alloc(2*(size_t)NL1*F1C*NM1));
  float2* Bmat  = (float2*)(ws + alloc(2*(size_t)NL2*GEMM_K*GEMM_N));
  float2* Amat  = (float2*)(ws + alloc(2*(size_t)NL2*GEMM_M*GEMM_K));
  float2* Cmat  = (float2*)(ws + alloc(2*(size_t)NL2*GEMM_M*GEMM_N));
  float*  featp = ws + alloc((size_t)BATCH*F2C);
  if (ws_size < off*sizeof(float)) return;

  const int total_c = N_WDS2 + N_Y1 + N_D1W + N_D12W + N_D2 + N_D2W + N_W2N;
  k_weights<<<1, 128, 0, stream>>>(dhw30, dhw10, dhw6);
  k_consts<<<(total_c + 255)/256, 256, 0, stream>>>(dhw30, dhw10, dhw6,
                                                    wd_s2, Y1, d1w, d12w, D2, d2w, w2n);
  k_s2fft<<<BATCH, 256, 0, stream>>>(x, wd_s2, X);
  k_psi1<<<(NL1*F1C*NM1 + 255)/256, 256, 0, stream>>>(psi1, Y1, Psi1p);
  k_psi2<<<(NL2*F1C*F2C*NM2*NM2 + 255)/256, 256, 0, stream>>>(psi2, D2, Bmat);
  k_stage1<<<dim3(BATCH, F1C), 256, 0, stream>>>(X, Psi1p, d1w, d12w, Amat);
  k_so3mm<<<dim3(GEMM_M/GM, (GEMM_N + GN - 1)/GN, NL2), 256, 0, stream>>>(Amat, Bmat, Cmat);
  k_stage2<<<dim3(BATCH, F2C), 256, 0, stream>>>(Cmat, d2w, w2n, featp);
  k_head<<<(BATCH*10 + 255)/256, 256, 0, stream>>>(featp, w_lin, b_lin, out);
}

// Round 6
// 349.410 us; speedup vs baseline: 3.1573x; 1.0999x over previous
//
#include <hip/hip_runtime.h>
#include <math.h>

#define PI_D 3.14159265358979323846
#define PI_F 3.14159265358979f

#define BATCH 128
#define NM1 19    // full m range for B1 (m in [-9,9])
#define NMP1 10   // nonneg m freqs (m in [0,9])
#define NM2 11    // full freqs for B2 (m in [-5,5])
#define NMP2 6    // nonneg (m2 in [0,5])
#define NB_IN 60
#define NB1 20
#define NB2 12
#define NL1 10
#define NL2 6
#define F1C 20
#define F2C 40
#define NBC 5

// GEMM dims for so3mm: per-l, C[M][N] += A[M][K]*B[K][N] complex, Hermitian-halved M
#define GEMM_MH (BATCH*NMP2)  // 768 (rows m2>=0 only)
#define GEMM_N (F2C*NM2)      // 440
#define GEMM_K (F1C*NM2)      // 220
#define GM 64
#define GN 64
#define GK 20
#define ASTR 21               // padded As row stride (bank-conflict fix)

// constant tensor element counts
#define N_WDS2 (NL1*NB_IN*NM1)     // 11400 f32
#define N_Y1   (NL1*24*NM1)        // 4560 cplx
#define N_D1W  (NL1*NB1*NM1*NM1)   // 72200 f32
#define N_D12W (NL2*NB1*NM2*NM2)   // 14520 f32
#define N_D2   (NL2*144*NM2*NM2)   // 104544 cplx
#define N_D2W  (NL2*NB2*NM2*NM2)   // 8712 f32
#define N_W2N  (NB2)               // 12 f32

// ---------------- device helpers for Wigner-d (fp64, matches numpy trace-time math) ----------------
__device__ __forceinline__ double ipow_d(double x, int e) {
  double r = 1.0;
  for (int i = 0; i < e; ++i) r *= x;
  return r;
}

__device__ double wigd(const double* lf, int l, int m, int n, double beta) {
  if (m < -l || m > l || n < -l || n > l) return 0.0;
  double cb = cos(0.5*beta), sb = sin(0.5*beta);
  double pref = 0.5*(lf[l+m]+lf[l-m]+lf[l+n]+lf[l-n]);
  int s0 = (n-m) > 0 ? (n-m) : 0;
  int s1 = (l+n) < (l-m) ? (l+n) : (l-m);
  double acc = 0.0;
  for (int s = s0; s <= s1; ++s) {
    double lc = pref - (lf[l+n-s]+lf[s]+lf[m-n+s]+lf[l-m-s]);
    double t = exp(lc) * ipow_d(cb, 2*l+n-m-2*s) * ipow_d(sb, m-n+2*s);
    acc += ((m-n+s) & 1) ? -t : t;
  }
  return acc;
}

__device__ __forceinline__ double dh_beta_d(int b, int k) { return PI_D*(2*k+1)/(4.0*b); }

__device__ double dh_w_d(int b, int k) {
  double beta = dh_beta_d(b, k), s = 0.0;
  for (int j = 0; j < b; ++j) s += sin((2.0*j+1.0)*beta)/(2.0*j+1.0);
  return (2.0/b)*sin(beta)*s;
}

// ---------------- K0: quadrature weight tables (fp64) ----------------
__global__ void k_weights(double* __restrict__ dhw30, double* __restrict__ dhw10,
                          double* __restrict__ dhw6) {
  int t = threadIdx.x;
  if (t < 60) dhw30[t] = dh_w_d(30, t);
  else if (t < 80) dhw10[t-60] = dh_w_d(10, t-60);
  else if (t < 92) dhw6[t-80] = dh_w_d(6, t-80);
}

// ---------------- constants kernel ----------------
__global__ void k_consts(const double* __restrict__ dhw30, const double* __restrict__ dhw10,
                         const double* __restrict__ dhw6,
                         float* __restrict__ wd_s2, float2* __restrict__ Y1,
                         float* __restrict__ d1w, float* __restrict__ d12w,
                         float2* __restrict__ D2, float* __restrict__ d2w,
                         float* __restrict__ w2n) {
  __shared__ double lf[41];
  int t = threadIdx.x;
  if (t < 41) lf[t] = lgamma((double)t + 1.0);
  __syncthreads();
  int gid = blockIdx.x*blockDim.x + t;

  if (gid < N_WDS2) {
    int l = gid/(NB_IN*NM1); int r = gid%(NB_IN*NM1); int k = r/NM1; int mi = r%NM1;
    int m = mi - 9;
    wd_s2[gid] = (float)(dhw30[k] * wigd(lf, l, m, 0, dh_beta_d(30,k)));
    return;
  }
  gid -= N_WDS2;
  if (gid < N_Y1) {
    int l = gid/(24*NM1); int r = gid%(24*NM1); int p = r/NM1; int mi = r%NM1;
    int m = mi - 9;
    double beta  = (double)(p/8 + 1) * PI_D/24.0;
    double alpha = 2.0*PI_D*(double)(p%8)/8.0;
    double d = wigd(lf, l, m, 0, beta);
    double ph = -(double)m*alpha;
    Y1[gid] = make_float2((float)(d*cos(ph)), (float)(d*sin(ph)));
    return;
  }
  gid -= N_Y1;
  if (gid < N_D1W) {
    int l = gid/(NB1*NM1*NM1); int r = gid%(NB1*NM1*NM1); int j = r/(NM1*NM1); int rr = r%(NM1*NM1);
    int m = rr/NM1 - 9, n = rr%NM1 - 9;
    d1w[gid] = (float)((double)(2*l+1) * wigd(lf, l, m, n, dh_beta_d(10,j)));
    return;
  }
  gid -= N_D1W;
  if (gid < N_D12W) {
    int l = gid/(NB1*NM2*NM2); int r = gid%(NB1*NM2*NM2); int j = r/(NM2*NM2); int rr = r%(NM2*NM2);
    int m = rr/NM2 - 5, n = rr%NM2 - 5;
    d12w[gid] = (float)(dhw10[j] * wigd(lf, l, m, n, dh_beta_d(10,j)));
    return;
  }
  gid -= N_D12W;
  if (gid < N_D2) {
    int l = gid/(144*NM2*NM2); int r = gid%(144*NM2*NM2); int p = r/(NM2*NM2); int rr = r%(NM2*NM2);
    int m = rr/NM2 - 5, n = rr%NM2 - 5;
    double beta  = (double)(p/48 + 1) * PI_D/24.0;
    double alpha = 2.0*PI_D*(double)((p/6)%8)/8.0;
    double gamma = 2.0*PI_D*(double)(p%6)/6.0;
    double d = wigd(lf, l, m, n, beta);
    double ph = -((double)m*alpha + (double)n*gamma);
    D2[gid] = make_float2((float)(d*cos(ph)), (float)(d*sin(ph)));
    return;
  }
  gid -= N_D2;
  if (gid < N_D2W) {
    int l = gid/(NB2*NM2*NM2); int r = gid%(NB2*NM2*NM2); int j = r/(NM2*NM2); int rr = r%(NM2*NM2);
    int m = rr/NM2 - 5, n = rr%NM2 - 5;
    d2w[gid] = (float)((double)(2*l+1) * wigd(lf, l, m, n, dh_beta_d(6,j)));
    return;
  }
  gid -= N_D2W;
  if (gid < N_W2N) {
    double s = 0.0;
    for (int j = 0; j < NB2; ++j) s += dhw6[j];
    w2n[gid] = (float)(dhw6[gid]/s);
    return;
  }
}

// ---------------- K1: azimuthal DFT (60pt, 10 nonneg freqs) + Legendre -> X[10][128][10] ----------------
__global__ __launch_bounds__(256) void k_s2fft(const float* __restrict__ x,
                                               const float* __restrict__ wd_s2,
                                               float2* __restrict__ X) {
  __shared__ float xs[3600];
  __shared__ float2 xf[NB_IN*NMP1];
  __shared__ float2 tw60[NB_IN*NMP1];   // [a][mp] = e^{-i 2pi a mp/60}
  const int z = blockIdx.x, t = threadIdx.x;
  for (int i = t; i < NB_IN*NMP1; i += 256) {
    int a = i/NMP1, mp = i%NMP1;
    int r = (a*mp) % NB_IN;
    float s, c; sincosf(2.f*PI_F*(float)r/(float)NB_IN, &s, &c);
    tw60[i] = make_float2(c, -s);
  }
  for (int i = t; i < 3600; i += 256) xs[i] = x[z*3600 + i];
  __syncthreads();
  for (int i = t; i < NB_IN*NMP1; i += 256) {
    int k = i/NMP1, mp = i%NMP1;
    float re = 0.f, im = 0.f;
    const float* xrow = &xs[k*NB_IN];
    for (int a = 0; a < NB_IN; ++a) {
      float v = xrow[a];
      float2 e = tw60[a*NMP1 + mp];
      re = fmaf(v, e.x, re);
      im = fmaf(v, e.y, im);
    }
    xf[i] = make_float2(re, im);
  }
  __syncthreads();
  for (int i = t; i < NL1*NMP1; i += 256) {
    int l = i/NMP1, mp = i%NMP1;
    float re = 0.f, im = 0.f;
    for (int k = 0; k < NB_IN; ++k) {
      float w = wd_s2[(l*NB_IN+k)*NM1 + mp + 9];
      float2 v = xf[k*NMP1 + mp];
      re = fmaf(w, v.x, re); im = fmaf(w, v.y, im);
    }
    X[(l*BATCH + z)*NMP1 + mp] = make_float2(re, im);
  }
}

// ---------------- K2: Psi1[l][o][m] = sum_g psi1[0][o][g] * Y1[l][g][m]  (full m range) ----------------
__global__ void k_psi1(const float* __restrict__ psi1, const float2* __restrict__ Y1,
                       float2* __restrict__ Psi1) {
  int idx = blockIdx.x*blockDim.x + threadIdx.x;
  if (idx >= NL1*F1C*NM1) return;
  int l = idx/(F1C*NM1); int r = idx%(F1C*NM1); int o = r/NM1; int mi = r%NM1;
  float re = 0.f, im = 0.f;
  for (int g = 0; g < 24; ++g) {
    float w = psi1[o*24 + g];
    float2 y = Y1[(l*24+g)*NM1 + mi];
    re = fmaf(w, y.x, re); im = fmaf(w, y.y, im);
  }
  Psi1[idx] = make_float2(re, im);
}

// ---------------- K3: B[l][(i*11+k)][(o*11+n)] = sum_g psi2[i][o][g] * D2[l][g][k][n] ----------------
__global__ void k_psi2(const float* __restrict__ psi2, const float2* __restrict__ D2,
                       float2* __restrict__ Bm) {
  int idx = blockIdx.x*blockDim.x + threadIdx.x;
  if (idx >= NL2*F1C*F2C*NM2*NM2) return;
  int mn = idx % (NM2*NM2); int t1 = idx/(NM2*NM2);
  int o = t1 % F2C; int t2 = t1/F2C; int i = t2 % F1C; int l = t2/F1C;
  int k = mn / NM2, n = mn % NM2;
  float re = 0.f, im = 0.f;
  for (int g = 0; g < 144; ++g) {
    float w = psi2[(i*F2C + o)*144 + g];
    float2 dv = D2[(l*144 + g)*(NM2*NM2) + mn];
    re = fmaf(w, dv.x, re); im = fmaf(w, dv.y, im);
  }
  Bm[(size_t)l*GEMM_K*GEMM_N + (i*NM2 + k)*GEMM_N + o*NM2 + n] = make_float2(re, im);
}

// ---------------- K4: fused stage 1, Hermitian-halved, XP hoisted. Block per (z,o). ----------------
__global__ __launch_bounds__(256) void k_stage1(const float2* __restrict__ X,
                                                const float2* __restrict__ Psi1,
                                                const float* __restrict__ d1w,
                                                const float* __restrict__ d12w,
                                                float2* __restrict__ Am) {
  __shared__ float2 Xs[NL1*NMP1];                      // 100
  __shared__ float2 Ps[NL1*NM1];                       // 190
  __shared__ float2 XP[NL1*NMP1*NM1];                  // 1900: X[l][mp]*Ps[l][n], b-invariant
  __shared__ __align__(16) float2 EsynT[NM1*NB1];      // [n][g]  e^{+i 2pi g(n-9)/20}   380
  __shared__ __align__(16) float2 EsynA[NB1*NMP1];     // [a][mp] e^{+i 2pi a mp/20}     200
  __shared__ __align__(16) float2 EanaA[NB1*NMP2];     // [a][m2p] e^{-i 2pi a m2p/20}   120
  __shared__ __align__(16) float2 EanaG[NB1*12];       // [g][n2i] e^{-i 2pi g(n2i-5)/20}, col11=0  240
  __shared__ __align__(16) float2 bufA[NBC*200];       // Fh[bb][mp][n] (950) / yb floats (2000f)
  __shared__ __align__(16) float2 bufB[NBC*200];       // Tt[bb][mp][g] (1000) / Uu[bb][m2p][g] (600)
  __shared__ float2 yfs[NBC*NMP2*NM2];                 // 330
  __shared__ float2 Fxa[NL2*NMP2*NM2];                 // 396: rows m2>=0 only

  const int z = blockIdx.x, o = blockIdx.y, t = threadIdx.x;

  for (int i = t; i < NM1*NB1; i += 256) {
    int n = i/NB1, g = i%NB1;
    int r = (g*(n-9)) % NB1; if (r < 0) r += NB1;
    float s, c; sincosf(2.f*PI_F*(float)r/(float)NB1, &s, &c);
    EsynT[i] = make_float2(c, s);
  }
  for (int i = t; i < NB1*NMP1; i += 256) {
    int a = i/NMP1, mp = i%NMP1;
    int r = (a*mp) % NB1;
    float s, c; sincosf(2.f*PI_F*(float)r/(float)NB1, &s, &c);
    EsynA[i] = make_float2(c, s);
  }
  for (int i = t; i < NB1*NMP2; i += 256) {
    int a = i/NMP2, m2p = i%NMP2;
    int r = (a*m2p) % NB1;
    float s, c; sincosf(2.f*PI_F*(float)r/(float)NB1, &s, &c);
    EanaA[i] = make_float2(c, -s);
  }
  for (int i = t; i < NB1*12; i += 256) {
    int g = i/12, cI = i%12;
    if (cI == 11) { EanaG[i] = make_float2(0.f, 0.f); }
    else {
      int r = (g*(cI-5)) % NB1; if (r < 0) r += NB1;
      float s, c; sincosf(2.f*PI_F*(float)r/(float)NB1, &s, &c);
      EanaG[i] = make_float2(c, -s);
    }
  }
  for (int i = t; i < NL1*NMP1; i += 256) {
    int l = i/NMP1, mp = i%NMP1;
    Xs[i] = X[(l*BATCH + z)*NMP1 + mp];
  }
  for (int i = t; i < NL1*NM1; i += 256) {
    int l = i/NM1, mi = i%NM1;
    Ps[i] = Psi1[(l*F1C + o)*NM1 + mi];
  }
  for (int i = t; i < NL2*NMP2*NM2; i += 256) Fxa[i] = make_float2(0.f, 0.f);
  __syncthreads();

  // XP[l][mp][n] = Xs[l][mp] * Ps[l][n]  (hoisted out of the beta loop)
  for (int i = t; i < NL1*NMP1*NM1; i += 256) {
    int l = i/(NMP1*NM1); int rr = i%(NMP1*NM1);
    int mp = rr/NM1, n = rr%NM1;
    float2 xa = Xs[l*NMP1+mp], pp = Ps[l*NM1+n];
    XP[i] = make_float2(xa.x*pp.x - xa.y*pp.y, xa.x*pp.y + xa.y*pp.x);
  }
  __syncthreads();

  float2* Fh = bufA;           // [bb][mp][n] : 950
  float2* Tt = bufB;           // [bb][mp][g] : 1000
  float*  yb = (float*)bufA;   // [bb][a][g]  : 2000 floats
  float2* Uu = bufB;           // [bb][m2p][g]: 600

  for (int c = 0; c < NB1/NBC; ++c) {
    const int b0 = c*NBC;
    // ph1: Fh[bb][mp][n] = sum_l XP[l][mp][n] * d1w[l][b][mp+9][n]
    for (int i = t; i < NBC*NMP1*NM1; i += 256) {
      int bb = i/(NMP1*NM1); int rr = i%(NMP1*NM1);
      int mp = rr/NM1, n = rr%NM1;
      float re = 0.f, im = 0.f;
      const float* dw = &d1w[(b0+bb)*(NM1*NM1) + (mp+9)*NM1 + n];
      const float2* xp = &XP[rr];
      #pragma unroll
      for (int l = 0; l < NL1; ++l) {
        float w = dw[l*(NB1*NM1*NM1)];
        float2 v = xp[l*(NMP1*NM1)];
        re = fmaf(w, v.x, re); im = fmaf(w, v.y, im);
      }
      Fh[(bb*NMP1 + mp)*NM1 + n] = make_float2(re, im);
    }
    __syncthreads();
    // ph2: Tt[bb][mp][g] = sum_n Fh[bb][mp][n]*EsynT[n][g], 4 g per thread (250 items)
    for (int i = t; i < NBC*NMP1*5; i += 256) {
      int gq = i % 5; int r = i / 5; int mp = r % NMP1; int bb = r / NMP1;
      int g0 = gq*4;
      const float2* fh = &Fh[(bb*NMP1 + mp)*NM1];
      float2 a0 = {0.f,0.f}, a1 = {0.f,0.f}, a2 = {0.f,0.f}, a3 = {0.f,0.f};
      #pragma unroll
      for (int n = 0; n < NM1; ++n) {
        float2 f = fh[n];
        float4 e01 = *(const float4*)&EsynT[n*NB1 + g0];
        float4 e23 = *(const float4*)&EsynT[n*NB1 + g0 + 2];
        a0.x += f.x*e01.x - f.y*e01.y; a0.y += f.x*e01.y + f.y*e01.x;
        a1.x += f.x*e01.z - f.y*e01.w; a1.y += f.x*e01.w + f.y*e01.z;
        a2.x += f.x*e23.x - f.y*e23.y; a2.y += f.x*e23.y + f.y*e23.x;
        a3.x += f.x*e23.z - f.y*e23.w; a3.y += f.x*e23.w + f.y*e23.z;
      }
      float2* tr = &Tt[(bb*NMP1 + mp)*NB1 + g0];
      tr[0] = a0; tr[1] = a1; tr[2] = a2; tr[3] = a3;
    }
    __syncthreads();
    // ph3: y[bb][a][g] = relu( Tt[bb][0][g].x + 2*sum_{mp=1..9} Re(EsynA[a][mp]*Tt[bb][mp][g]) )
    for (int i = t; i < NBC*10*5; i += 256) {
      int gq = i % 5; int r = i / 5; int ap = r % 10; int bb = r / 10;
      int a0 = ap*2, g0 = gq*4;
      float4 t01 = *(const float4*)&Tt[(bb*NMP1)*NB1 + g0];       // mp = 0
      float4 t23 = *(const float4*)&Tt[(bb*NMP1)*NB1 + g0 + 2];
      float s00=0.f,s01=0.f,s02=0.f,s03=0.f, s10=0.f,s11=0.f,s12=0.f,s13=0.f;
      #pragma unroll
      for (int mp = 1; mp < NMP1; ++mp) {
        float4 u01 = *(const float4*)&Tt[(bb*NMP1 + mp)*NB1 + g0];
        float4 u23 = *(const float4*)&Tt[(bb*NMP1 + mp)*NB1 + g0 + 2];
        float2 e0 = EsynA[a0*NMP1 + mp];
        float2 e1 = EsynA[(a0+1)*NMP1 + mp];
        s00 += e0.x*u01.x - e0.y*u01.y;
        s01 += e0.x*u01.z - e0.y*u01.w;
        s02 += e0.x*u23.x - e0.y*u23.y;
        s03 += e0.x*u23.z - e0.y*u23.w;
        s10 += e1.x*u01.x - e1.y*u01.y;
        s11 += e1.x*u01.z - e1.y*u01.w;
        s12 += e1.x*u23.x - e1.y*u23.y;
        s13 += e1.x*u23.z - e1.y*u23.w;
      }
      float* y0 = &yb[(bb*NB1 + a0)*NB1 + g0];
      float* y1 = &yb[(bb*NB1 + a0 + 1)*NB1 + g0];
      y0[0]=fmaxf(fmaf(2.f,s00,t01.x),0.f); y0[1]=fmaxf(fmaf(2.f,s01,t01.z),0.f);
      y0[2]=fmaxf(fmaf(2.f,s02,t23.x),0.f); y0[3]=fmaxf(fmaf(2.f,s03,t23.z),0.f);
      y1[0]=fmaxf(fmaf(2.f,s10,t01.x),0.f); y1[1]=fmaxf(fmaf(2.f,s11,t01.z),0.f);
      y1[2]=fmaxf(fmaf(2.f,s12,t23.x),0.f); y1[3]=fmaxf(fmaf(2.f,s13,t23.z),0.f);
    }
    __syncthreads();
    // ph4: U[bb][m2p][g] = sum_a y[bb][a][g]*EanaA[a][m2p], 4 g per thread (150 items)
    for (int i = t; i < NBC*NMP2*5; i += 256) {
      int gq = i % 5; int r = i / 5; int m2p = r % NMP2; int bb = r / NMP2;
      int g0 = gq*4;
      float2 u0 = {0.f,0.f}, u1 = {0.f,0.f}, u2 = {0.f,0.f}, u3 = {0.f,0.f};
      #pragma unroll
      for (int aa = 0; aa < NB1; ++aa) {
        float4 y4 = *(const float4*)&yb[(bb*NB1 + aa)*NB1 + g0];
        float2 e = EanaA[aa*NMP2 + m2p];
        u0.x = fmaf(y4.x, e.x, u0.x); u0.y = fmaf(y4.x, e.y, u0.y);
        u1.x = fmaf(y4.y, e.x, u1.x); u1.y = fmaf(y4.y, e.y, u1.y);
        u2.x = fmaf(y4.z, e.x, u2.x); u2.y = fmaf(y4.z, e.y, u2.y);
        u3.x = fmaf(y4.w, e.x, u3.x); u3.y = fmaf(y4.w, e.y, u3.y);
      }
      float2* ur = &Uu[(bb*NMP2 + m2p)*NB1 + g0];
      ur[0] = u0; ur[1] = u1; ur[2] = u2; ur[3] = u3;
    }
    __syncthreads();
    // ph5: yf[bb][m2p][n2] = sum_g U[bb][m2p][g]*EanaG[g][n2], 2 n2 per thread (180 items)
    for (int i = t; i < NBC*NMP2*6; i += 256) {
      int p = i % 6; int r = i / 6; int m2p = r % NMP2; int bb = r / NMP2;
      int n0 = p*2;
      const float2* ur = &Uu[(bb*NMP2 + m2p)*NB1];
      float2 acc0 = {0.f,0.f}, acc1 = {0.f,0.f};
      #pragma unroll
      for (int g = 0; g < NB1; ++g) {
        float2 u = ur[g];
        float4 e = *(const float4*)&EanaG[g*12 + n0];
        acc0.x += u.x*e.x - u.y*e.y; acc0.y += u.x*e.y + u.y*e.x;
        acc1.x += u.x*e.z - u.y*e.w; acc1.y += u.x*e.w + u.y*e.z;
      }
      yfs[(bb*NMP2 + m2p)*NM2 + n0] = acc0;
      if (n0 + 1 < NM2) yfs[(bb*NMP2 + m2p)*NM2 + n0 + 1] = acc1;
    }
    __syncthreads();
    // ph6: Fxa[l2][m2p][n2i] += sum_bb d12w[l2][b][(m2p+5)*11+n2i] * yf[bb][m2p][n2i]  (m2>=0 only)
    for (int i = t; i < NL2*NMP2*NM2; i += 256) {
      int l2 = i/(NMP2*NM2); int r = i%(NMP2*NM2);
      int mnf = r + 5*NM2;     // (m2p+5)*11 + n2i
      float2 acc = Fxa[i];
      #pragma unroll
      for (int bb = 0; bb < NBC; ++bb) {
        float w = d12w[(l2*NB1 + b0 + bb)*(NM2*NM2) + mnf];
        float2 v = yfs[bb*(NMP2*NM2) + r];
        acc.x = fmaf(w, v.x, acc.x); acc.y = fmaf(w, v.y, acc.y);
      }
      Fxa[i] = acc;
    }
    __syncthreads();
  }
  // write GEMM A (Hermitian-halved): row = z*6+m2p, col = o*11+n
  for (int i = t; i < NL2*NMP2*NM2; i += 256) {
    int l2 = i/(NMP2*NM2); int r = i%(NMP2*NM2);
    int mp = r/NM2, n = r%NM2;
    Am[(size_t)l2*GEMM_MH*GEMM_K + (z*NMP2 + mp)*GEMM_K + o*NM2 + n] = Fxa[i];
  }
}

// ---------------- K5: per-l complex GEMM C[l][768][440] = A[l][768][220] * B[l][220][440] ----------------
__global__ __launch_bounds__(256) void k_so3mm(const float2* __restrict__ A,
                                               const float2* __restrict__ B,
                                               float2* __restrict__ C) {
  __shared__ float2 As[GM*ASTR];   // [m][k], padded stride 21 (conflict-free)
  __shared__ float2 Bs[GK*GN];     // interleaved [kk][j][tn]
  const int l = blockIdx.z;
  const int row0 = blockIdx.x*GM, col0 = blockIdx.y*GN;
  const int t = threadIdx.x;
  const float2* Ag = A + (size_t)l*GEMM_MH*GEMM_K;
  const float2* Bg = B + (size_t)l*GEMM_K*GEMM_N;
  float2* Cg = C + (size_t)l*GEMM_MH*GEMM_N;
  const int tn = t & 15, tm = t >> 4;   // 16x16 threads, 4x4 cplx each
  float2 acc[4][4];
  #pragma unroll
  for (int i = 0; i < 4; ++i)
    #pragma unroll
    for (int j = 0; j < 4; ++j) acc[i][j] = make_float2(0.f, 0.f);

  for (int k0 = 0; k0 < GEMM_K; k0 += GK) {
    for (int i = t; i < GM*GK; i += 256) {
      int r = i/GK, kk = i%GK;
      As[r*ASTR + kk] = Ag[(size_t)(row0 + r)*GEMM_K + k0 + kk];
    }
    for (int i = t; i < GK*GN; i += 256) {
      int kk = i/GN, cc = i%GN;
      int col = col0 + cc;
      float2 v = (col < GEMM_N) ? Bg[(size_t)(k0 + kk)*GEMM_N + col] : make_float2(0.f, 0.f);
      Bs[(kk*4 + (cc & 3))*16 + (cc >> 2)] = v;   // [kk][j][tn]
    }
    __syncthreads();
    #pragma unroll
    for (int kk = 0; kk < GK; ++kk) {
      float2 a[4], b[4];
      #pragma unroll
      for (int i = 0; i < 4; ++i) a[i] = As[(tm*4 + i)*ASTR + kk];
      #pragma unroll
      for (int j = 0; j < 4; ++j) b[j] = Bs[(kk*4 + j)*16 + tn];
      #pragma unroll
      for (int i = 0; i < 4; ++i)
        #pragma unroll
        for (int j = 0; j < 4; ++j) {
          acc[i][j].x = fmaf(a[i].x, b[j].x, acc[i][j].x);
          acc[i][j].x = fmaf(-a[i].y, b[j].y, acc[i][j].x);
          acc[i][j].y = fmaf(a[i].x, b[j].y, acc[i][j].y);
          acc[i][j].y = fmaf(a[i].y, b[j].x, acc[i][j].y);
        }
    }
    __syncthreads();
  }
  #pragma unroll
  for (int i = 0; i < 4; ++i) {
    int r = row0 + tm*4 + i;
    #pragma unroll
    for (int j = 0; j < 4; ++j) {
      int cc = col0 + tn*4 + j;
      if (cc < GEMM_N) Cg[(size_t)r*GEMM_N + cc] = acc[i][j];
    }
  }
}

// ---------------- K6: fused stage 2 tail. Block per (z,o). Hermitian C reconstruction. ----------------
__global__ __launch_bounds__(256) void k_stage2(const float2* __restrict__ C,
                                                const float* __restrict__ d2w,
                                                const float* __restrict__ w2n,
                                                float* __restrict__ feat) {
  __shared__ float2 Fos[NL2*NM2*NM2];     // 726
  __shared__ float2 Fh2[NB2*NM2*NM2];     // 1452
  __shared__ float2 T2[NB2*NB2*NM2];      // 1584
  __shared__ float2 Esyn2[NB2*NM2];       // [k][mi] e^{+i 2pi k(mi-5)/12}
  __shared__ float w2s[NB2];
  __shared__ float red[256];
  const int z = blockIdx.x, o = blockIdx.y, t = threadIdx.x;
  for (int i = t; i < NB2*NM2; i += 256) {
    int k = i/NM2, mi = i%NM2;
    int r = (k*(mi-5)) % NB2; if (r < 0) r += NB2;
    float s, c; sincosf(2.f*PI_F*(float)r/(float)NB2, &s, &c);
    Esyn2[i] = make_float2(c, s);
  }
  if (t < NB2) w2s[t] = w2n[t];
  for (int i = t; i < NL2*NM2*NM2; i += 256) {
    int l = i/(NM2*NM2); int mn = i%(NM2*NM2);
    int m = mn/NM2, n = mn%NM2;
    float2 v;
    if (m >= 5) {
      v = C[(size_t)l*GEMM_MH*GEMM_N + (size_t)(z*NMP2 + m - 5)*GEMM_N + o*NM2 + n];
    } else {
      float2 cc = C[(size_t)l*GEMM_MH*GEMM_N + (size_t)(z*NMP2 + 5 - m)*GEMM_N + o*NM2 + (10 - n)];
      float s = ((m - n) & 1) ? -1.f : 1.f;
      v = make_float2(s*cc.x, -s*cc.y);
    }
    Fos[i] = v;
  }
  __syncthreads();
  // ph1: Fh2[b][mn] = sum_l d2w[l][b][mn]*Fos[l][mn]
  for (int i = t; i < NB2*NM2*NM2; i += 256) {
    int b = i/(NM2*NM2); int mn = i%(NM2*NM2);
    float re = 0.f, im = 0.f;
    #pragma unroll
    for (int l = 0; l < NL2; ++l) {
      float w = d2w[(l*NB2 + b)*(NM2*NM2) + mn];
      float2 v = Fos[l*(NM2*NM2) + mn];
      re = fmaf(w, v.x, re); im = fmaf(w, v.y, im);
    }
    Fh2[i] = make_float2(re, im);
  }
  __syncthreads();
  // ph2: T2[b][a][ni] = sum_mi Esyn2[a][mi]*Fh2[b][mi][ni]
  for (int i = t; i < NB2*NB2*NM2; i += 256) {
    int ni = i % NM2; int r = i / NM2; int aa = r % NB2; int b = r / NB2;
    const float2* fh = &Fh2[b*(NM2*NM2) + ni];
    float re = 0.f, im = 0.f;
    #pragma unroll
    for (int mi = 0; mi < NM2; ++mi) {
      float2 f = fh[mi*NM2]; float2 e = Esyn2[aa*NM2+mi];
      re += e.x*f.x - e.y*f.y;
      im += e.x*f.y + e.y*f.x;
    }
    T2[i] = make_float2(re, im);
  }
  __syncthreads();
  // ph3: accumulate w2s[b]*relu( Re sum_ni Esyn2[g][ni]*T2[b][a][ni] )
  float accT = 0.f;
  for (int i = t; i < NB2*NB2*NB2; i += 256) {
    int g = i % NB2; int r = i / NB2; int aa = r % NB2; int b = r / NB2;
    const float2* trow = &T2[(b*NB2 + aa)*NM2];
    float v = 0.f;
    #pragma unroll
    for (int ni = 0; ni < NM2; ++ni) {
      float2 tv = trow[ni]; float2 e = Esyn2[g*NM2+ni];
      v += e.x*tv.x - e.y*tv.y;
    }
    accT += w2s[b]*fmaxf(v, 0.f);
  }
  red[t] = accT;
  __syncthreads();
  for (int s = 128; s > 0; s >>= 1) {
    if (t < s) red[t] += red[t + s];
    __syncthreads();
  }
  if (t == 0) feat[z*F2C + o] = red[0] / (float)(NB2*NB2);
}

// ---------------- K7: linear head ----------------
__global__ void k_head(const float* __restrict__ feat, const float* __restrict__ w_lin,
                       const float* __restrict__ b_lin, float* __restrict__ out) {
  int idx = blockIdx.x*blockDim.x + threadIdx.x;
  if (idx >= BATCH*10) return;
  int z = idx/10, f = idx%10;
  float acc = b_lin[f];
  for (int o = 0; o < F2C; ++o) acc = fmaf(feat[z*F2C + o], w_lin[f*F2C + o], acc);
  out[idx] = acc;
}

extern "C" void kernel_launch(void* const* d_in, const int* in_sizes, int n_in,
                              void* d_out, int out_size, void* d_ws, size_t ws_size,
                              hipStream_t stream) {
  const float* x     = (const float*)d_in[0];
  const float* psi1  = (const float*)d_in[1];
  const float* psi2  = (const float*)d_in[2];
  const float* w_lin = (const float*)d_in[3];
  const float* b_lin = (const float*)d_in[4];
  float* out = (float*)d_out;
  float* ws  = (float*)d_ws;

  size_t off = 0;
  auto alloc = [&](size_t nfloats) { size_t o = off; off += (nfloats + 15) & ~(size_t)15; return o; };
  double* dhw30 = (double*)(ws + alloc(2*60));
  double* dhw10 = (double*)(ws + alloc(2*20));
  double* dhw6  = (double*)(ws + alloc(2*12));
  float*  wd_s2 = ws + alloc(N_WDS2);
  float2* Y1    = (float2*)(ws + alloc(2*(size_t)N_Y1));
  float*  d1w   = ws + alloc(N_D1W);
  float*  d12w  = ws + alloc(N_D12W);
  float2* D2    = (float2*)(ws + alloc(2*(size_t)N_D2));
  float*  d2w   = ws + alloc(N_D2W);
  float*  w2n   = ws + alloc(N_W2N);
  float2* X     = (float2*)(ws + alloc(2*(size_t)NL1*BATCH*NMP1));
  float2* Psi1p = (float2*)(ws + alloc(2*(size_t)NL1*F1C*NM1));
  float2* Bmat  = (float2*)(ws + alloc(2*(size_t)NL2*GEMM_K*GEMM_N));
  float2* Amat  = (float2*)(ws + alloc(2*(size_t)NL2*GEMM_MH*GEMM_K));
  float2* Cmat  = (float2*)(ws + alloc(2*(size_t)NL2*GEMM_MH*GEMM_N));
  float*  featp = ws + alloc((size_t)BATCH*F2C);
  if (ws_size < off*sizeof(float)) return;

  const int total_c = N_WDS2 + N_Y1 + N_D1W + N_D12W + N_D2 + N_D2W + N_W2N;
  k_weights<<<1, 128, 0, stream>>>(dhw30, dhw10, dhw6);
  k_consts<<<(total_c + 255)/256, 256, 0, stream>>>(dhw30, dhw10, dhw6,
                                                    wd_s2, Y1, d1w, d12w, D2, d2w, w2n);
  k_s2fft<<<BATCH, 256, 0, stream>>>(x, wd_s2, X);
  k_psi1<<<(NL1*F1C*NM1 + 255)/256, 256, 0, stream>>>(psi1, Y1, Psi1p);
  k_psi2<<<(NL2*F1C*F2C*NM2*NM2 + 255)/256, 256, 0, stream>>>(psi2, D2, Bmat);
  k_stage1<<<dim3(BATCH, F1C), 256, 0, stream>>>(X, Psi1p, d1w, d12w, Amat);
  k_so3mm<<<dim3(GEMM_MH/GM, (GEMM_N + GN - 1)/GN, NL2), 256, 0, stream>>>(Amat, Bmat, Cmat);
  k_stage2<<<dim3(BATCH, F2C), 256, 0, stream>>>(Cmat, d2w, w2n, featp);
  k_head<<<(BATCH*10 + 255)/256, 256, 0, stream>>>(featp, w_lin, b_lin, out);
}

// Round 7
// 324.736 us; speedup vs baseline: 3.3972x; 1.0760x over previous
//
#include <hip/hip_runtime.h>
#include <math.h>

#define PI_D 3.14159265358979323846
#define PI_F 3.14159265358979f

#define BATCH 128
#define NM1 19    // full m range for B1 (m in [-9,9])
#define NMP1 10   // nonneg m freqs (m in [0,9])
#define NM2 11    // full freqs for B2 (m in [-5,5])
#define NMP2 6    // nonneg (m2 in [0,5])
#define NB_IN 60
#define NB1 20
#define NB2 12
#define NL1 10
#define NL2 6
#define F1C 20
#define F2C 40
#define NBC 5

// GEMM dims for so3mm: per-l, C[M][N] += A[M][K]*B[K][N] complex, Hermitian-halved M
#define GEMM_MH (BATCH*NMP2)  // 768
#define GEMM_N (F2C*NM2)      // 440
#define GEMM_K (F1C*NM2)      // 220
#define GM 32
#define GN 64
#define GK 20
#define ASTR 21               // padded As row stride

// twiddle table global layout (float2 offsets)
#define TW_SYNT 0       // [19][20] e^{+i 2pi g(n-9)/20}
#define TW_SYNA 380     // [20][10] e^{+i 2pi a mp/20}
#define TW_ANAA 580     // [20][6]  e^{-i 2pi a m2p/20}
#define TW_ANAG 700     // [20][12] e^{-i 2pi g(n2i-5)/20}, col 11 = 0
#define TW_S2   940     // [12][11] e^{+i 2pi k(mi-5)/12}
#define TW_60   1072    // [60][10] e^{-i 2pi a mp/60}
#define TW_TOT  1672

// constant tensor element counts
#define N_WDS2 (NL1*NB_IN*NM1)     // 11400 f32
#define N_Y1   (NL1*24*NM1)        // 4560 cplx
#define N_D1W  (NL1*NB1*NM1*NM1)   // 72200 f32
#define N_D12W (NL2*NB1*NM2*NM2)   // 14520 f32
#define N_D2   (NL2*144*NM2*NM2)   // 104544 cplx
#define N_D2W  (NL2*NB2*NM2*NM2)   // 8712 f32
#define N_W2N  (NB2)               // 12 f32

// ---------------- device helpers for Wigner-d (fp64, matches numpy trace-time math) ----------------
__device__ __forceinline__ double ipow_d(double x, int e) {
  double r = 1.0;
  for (int i = 0; i < e; ++i) r *= x;
  return r;
}

__device__ double wigd(const double* lf, int l, int m, int n, double beta) {
  if (m < -l || m > l || n < -l || n > l) return 0.0;
  double cb = cos(0.5*beta), sb = sin(0.5*beta);
  double pref = 0.5*(lf[l+m]+lf[l-m]+lf[l+n]+lf[l-n]);
  int s0 = (n-m) > 0 ? (n-m) : 0;
  int s1 = (l+n) < (l-m) ? (l+n) : (l-m);
  double acc = 0.0;
  for (int s = s0; s <= s1; ++s) {
    double lc = pref - (lf[l+n-s]+lf[s]+lf[m-n+s]+lf[l-m-s]);
    double t = exp(lc) * ipow_d(cb, 2*l+n-m-2*s) * ipow_d(sb, m-n+2*s);
    acc += ((m-n+s) & 1) ? -t : t;
  }
  return acc;
}

__device__ __forceinline__ double dh_beta_d(int b, int k) { return PI_D*(2*k+1)/(4.0*b); }

__device__ double dh_w_d(int b, int k) {
  double beta = dh_beta_d(b, k), s = 0.0;
  for (int j = 0; j < b; ++j) s += sin((2.0*j+1.0)*beta)/(2.0*j+1.0);
  return (2.0/b)*sin(beta)*s;
}

// ---------------- K0: quadrature weights (fp64) + fp32 twiddle tables ----------------
__global__ void k_weights(double* __restrict__ dhw30, double* __restrict__ dhw10,
                          double* __restrict__ dhw6, float2* __restrict__ Tg) {
  int t = threadIdx.x;
  if (t < 60) dhw30[t] = dh_w_d(30, t);
  else if (t < 80) dhw10[t-60] = dh_w_d(10, t-60);
  else if (t < 92) dhw6[t-80] = dh_w_d(6, t-80);
  for (int i = t; i < TW_TOT; i += 256) {
    float2 v;
    if (i < TW_SYNA) {                       // [n][g] e^{+i 2pi g(n-9)/20}
      int j = i, n = j/NB1, g = j%NB1;
      int r = (g*(n-9)) % NB1; if (r < 0) r += NB1;
      float s, c; sincosf(2.f*PI_F*(float)r/(float)NB1, &s, &c);
      v = make_float2(c, s);
    } else if (i < TW_ANAA) {                // [a][mp] e^{+i 2pi a mp/20}
      int j = i - TW_SYNA, a = j/NMP1, mp = j%NMP1;
      int r = (a*mp) % NB1;
      float s, c; sincosf(2.f*PI_F*(float)r/(float)NB1, &s, &c);
      v = make_float2(c, s);
    } else if (i < TW_ANAG) {                // [a][m2p] e^{-i 2pi a m2p/20}
      int j = i - TW_ANAA, a = j/NMP2, m2p = j%NMP2;
      int r = (a*m2p) % NB1;
      float s, c; sincosf(2.f*PI_F*(float)r/(float)NB1, &s, &c);
      v = make_float2(c, -s);
    } else if (i < TW_S2) {                  // [g][n2i] e^{-i 2pi g(n2i-5)/20}, col11=0
      int j = i - TW_ANAG, g = j/12, cI = j%12;
      if (cI == 11) v = make_float2(0.f, 0.f);
      else {
        int r = (g*(cI-5)) % NB1; if (r < 0) r += NB1;
        float s, c; sincosf(2.f*PI_F*(float)r/(float)NB1, &s, &c);
        v = make_float2(c, -s);
      }
    } else if (i < TW_60) {                  // [k][mi] e^{+i 2pi k(mi-5)/12}
      int j = i - TW_S2, k = j/NM2, mi = j%NM2;
      int r = (k*(mi-5)) % NB2; if (r < 0) r += NB2;
      float s, c; sincosf(2.f*PI_F*(float)r/(float)NB2, &s, &c);
      v = make_float2(c, s);
    } else {                                 // [a][mp] e^{-i 2pi a mp/60}
      int j = i - TW_60, a = j/NMP1, mp = j%NMP1;
      int r = (a*mp) % NB_IN;
      float s, c; sincosf(2.f*PI_F*(float)r/(float)NB_IN, &s, &c);
      v = make_float2(c, -s);
    }
    Tg[i] = v;
  }
}

// ---------------- constants kernel ----------------
__global__ void k_consts(const double* __restrict__ dhw30, const double* __restrict__ dhw10,
                         const double* __restrict__ dhw6,
                         float* __restrict__ wd_s2, float2* __restrict__ Y1,
                         float* __restrict__ d1w, float* __restrict__ d12w,
                         float2* __restrict__ D2, float* __restrict__ d2w,
                         float* __restrict__ w2n) {
  __shared__ double lf[41];
  int t = threadIdx.x;
  if (t < 41) lf[t] = lgamma((double)t + 1.0);
  __syncthreads();
  int gid = blockIdx.x*blockDim.x + t;

  if (gid < N_WDS2) {
    int l = gid/(NB_IN*NM1); int r = gid%(NB_IN*NM1); int k = r/NM1; int mi = r%NM1;
    int m = mi - 9;
    wd_s2[gid] = (float)(dhw30[k] * wigd(lf, l, m, 0, dh_beta_d(30,k)));
    return;
  }
  gid -= N_WDS2;
  if (gid < N_Y1) {
    int l = gid/(24*NM1); int r = gid%(24*NM1); int p = r/NM1; int mi = r%NM1;
    int m = mi - 9;
    double beta  = (double)(p/8 + 1) * PI_D/24.0;
    double alpha = 2.0*PI_D*(double)(p%8)/8.0;
    double d = wigd(lf, l, m, 0, beta);
    double ph = -(double)m*alpha;
    Y1[gid] = make_float2((float)(d*cos(ph)), (float)(d*sin(ph)));
    return;
  }
  gid -= N_Y1;
  if (gid < N_D1W) {
    int l = gid/(NB1*NM1*NM1); int r = gid%(NB1*NM1*NM1); int j = r/(NM1*NM1); int rr = r%(NM1*NM1);
    int m = rr/NM1 - 9, n = rr%NM1 - 9;
    d1w[gid] = (float)((double)(2*l+1) * wigd(lf, l, m, n, dh_beta_d(10,j)));
    return;
  }
  gid -= N_D1W;
  if (gid < N_D12W) {
    int l = gid/(NB1*NM2*NM2); int r = gid%(NB1*NM2*NM2); int j = r/(NM2*NM2); int rr = r%(NM2*NM2);
    int m = rr/NM2 - 5, n = rr%NM2 - 5;
    d12w[gid] = (float)(dhw10[j] * wigd(lf, l, m, n, dh_beta_d(10,j)));
    return;
  }
  gid -= N_D12W;
  if (gid < N_D2) {
    int l = gid/(144*NM2*NM2); int r = gid%(144*NM2*NM2); int p = r/(NM2*NM2); int rr = r%(NM2*NM2);
    int m = rr/NM2 - 5, n = rr%NM2 - 5;
    double beta  = (double)(p/48 + 1) * PI_D/24.0;
    double alpha = 2.0*PI_D*(double)((p/6)%8)/8.0;
    double gamma = 2.0*PI_D*(double)(p%6)/6.0;
    double d = wigd(lf, l, m, n, beta);
    double ph = -((double)m*alpha + (double)n*gamma);
    D2[gid] = make_float2((float)(d*cos(ph)), (float)(d*sin(ph)));
    return;
  }
  gid -= N_D2;
  if (gid < N_D2W) {
    int l = gid/(NB2*NM2*NM2); int r = gid%(NB2*NM2*NM2); int j = r/(NM2*NM2); int rr = r%(NM2*NM2);
    int m = rr/NM2 - 5, n = rr%NM2 - 5;
    d2w[gid] = (float)((double)(2*l+1) * wigd(lf, l, m, n, dh_beta_d(6,j)));
    return;
  }
  gid -= N_D2W;
  if (gid < N_W2N) {
    double s = 0.0;
    for (int j = 0; j < NB2; ++j) s += dhw6[j];
    w2n[gid] = (float)(dhw6[gid]/s);
    return;
  }
}

// ---------------- K1: azimuthal DFT (60pt, 10 nonneg freqs) + Legendre -> X[10][128][10] ----------------
__global__ __launch_bounds__(256) void k_s2fft(const float* __restrict__ x,
                                               const float* __restrict__ wd_s2,
                                               const float2* __restrict__ Tg,
                                               float2* __restrict__ X) {
  __shared__ float xs[3600];
  __shared__ float2 xf[NB_IN*NMP1];
  __shared__ float2 tw60[NB_IN*NMP1];
  const int z = blockIdx.x, t = threadIdx.x;
  for (int i = t; i < NB_IN*NMP1; i += 256) tw60[i] = Tg[TW_60 + i];
  for (int i = t; i < 3600; i += 256) xs[i] = x[z*3600 + i];
  __syncthreads();
  for (int i = t; i < NB_IN*NMP1; i += 256) {
    int k = i/NMP1, mp = i%NMP1;
    float re = 0.f, im = 0.f;
    const float* xrow = &xs[k*NB_IN];
    for (int a = 0; a < NB_IN; ++a) {
      float v = xrow[a];
      float2 e = tw60[a*NMP1 + mp];
      re = fmaf(v, e.x, re);
      im = fmaf(v, e.y, im);
    }
    xf[i] = make_float2(re, im);
  }
  __syncthreads();
  for (int i = t; i < NL1*NMP1; i += 256) {
    int l = i/NMP1, mp = i%NMP1;
    float re = 0.f, im = 0.f;
    for (int k = 0; k < NB_IN; ++k) {
      float w = wd_s2[(l*NB_IN+k)*NM1 + mp + 9];
      float2 v = xf[k*NMP1 + mp];
      re = fmaf(w, v.x, re); im = fmaf(w, v.y, im);
    }
    X[(l*BATCH + z)*NMP1 + mp] = make_float2(re, im);
  }
}

// ---------------- K2: Psi1[l][o][m] = sum_g psi1[0][o][g] * Y1[l][g][m] ----------------
__global__ void k_psi1(const float* __restrict__ psi1, const float2* __restrict__ Y1,
                       float2* __restrict__ Psi1) {
  int idx = blockIdx.x*blockDim.x + threadIdx.x;
  if (idx >= NL1*F1C*NM1) return;
  int l = idx/(F1C*NM1); int r = idx%(F1C*NM1); int o = r/NM1; int mi = r%NM1;
  float re = 0.f, im = 0.f;
  for (int g = 0; g < 24; ++g) {
    float w = psi1[o*24 + g];
    float2 y = Y1[(l*24+g)*NM1 + mi];
    re = fmaf(w, y.x, re); im = fmaf(w, y.y, im);
  }
  Psi1[idx] = make_float2(re, im);
}

// ---------------- K3: LDS-tiled: B[l][(i*11+k)][(o*11+n)] = sum_g psi2[io][g]*D2[l][g][kn] ----------------
#define P2IO 40   // io rows per block
#define P2GC 24   // g chunk
__global__ __launch_bounds__(256) void k_psi2(const float* __restrict__ psi2,
                                              const float2* __restrict__ D2,
                                              float2* __restrict__ Bm) {
  __shared__ __align__(16) float2 Ds[P2GC*122];   // padded row 122 (aligned b128)
  __shared__ float Ws[P2IO*P2GC];
  const int io0 = blockIdx.x*P2IO, l = blockIdx.y, t = threadIdx.x;
  const int tio = t/31, tmn = t%31;               // active: tio<8
  const int mn0 = tmn*4;
  float2 acc[5][4];
  #pragma unroll
  for (int i = 0; i < 5; ++i)
    #pragma unroll
    for (int j = 0; j < 4; ++j) acc[i][j] = make_float2(0.f, 0.f);

  for (int gc = 0; gc < 144; gc += P2GC) {
    for (int i = t; i < P2GC*121; i += 256) {
      int g = i/121, mn = i%121;
      Ds[g*122 + mn] = D2[(size_t)(l*144 + gc + g)*121 + mn];
    }
    for (int i = t; i < P2IO*P2GC; i += 256) {
      int io = i/P2GC, g = i%P2GC;
      Ws[i] = psi2[(io0 + io)*144 + gc + g];
    }
    __syncthreads();
    if (tio < 8) {
      for (int g = 0; g < P2GC; ++g) {
        float4 d01 = *(const float4*)&Ds[g*122 + mn0];
        float4 d23 = *(const float4*)&Ds[g*122 + mn0 + 2];
        float w0 = Ws[(tio*5 + 0)*P2GC + g];
        float w1 = Ws[(tio*5 + 1)*P2GC + g];
        float w2 = Ws[(tio*5 + 2)*P2GC + g];
        float w3 = Ws[(tio*5 + 3)*P2GC + g];
        float w4 = Ws[(tio*5 + 4)*P2GC + g];
        float dx[4] = {d01.x, d01.z, d23.x, d23.z};
        float dy[4] = {d01.y, d01.w, d23.y, d23.w};
        float wv[5] = {w0, w1, w2, w3, w4};
        #pragma unroll
        for (int i = 0; i < 5; ++i)
          #pragma unroll
          for (int j = 0; j < 4; ++j) {
            acc[i][j].x = fmaf(wv[i], dx[j], acc[i][j].x);
            acc[i][j].y = fmaf(wv[i], dy[j], acc[i][j].y);
          }
      }
    }
    __syncthreads();
  }
  if (tio < 8) {
    #pragma unroll
    for (int i = 0; i < 5; ++i) {
      int io = io0 + tio*5 + i;
      int ii = io/F2C, oo = io%F2C;
      #pragma unroll
      for (int j = 0; j < 4; ++j) {
        int mn = mn0 + j;
        if (mn < 121) {
          int k = mn/NM2, n = mn%NM2;
          Bm[(size_t)l*GEMM_K*GEMM_N + (ii*NM2 + k)*GEMM_N + oo*NM2 + n] = acc[i][j];
        }
      }
    }
  }
}

// ---------------- K4: fused stage 1, Hermitian-halved, b128 ph1. Block per (z,o). ----------------
__global__ __launch_bounds__(256) void k_stage1(const float2* __restrict__ X,
                                                const float2* __restrict__ Psi1,
                                                const float* __restrict__ d1w,
                                                const float* __restrict__ d12w,
                                                const float2* __restrict__ Tg,
                                                float2* __restrict__ Am) {
  __shared__ float2 Xs[NL1*NMP1];                      // 100
  __shared__ float2 Ps[NL1*NM1];                       // 190
  __shared__ __align__(16) float2 XPp[NL1*NMP1*20];    // 2000: X*Ps padded n-col 19 = 0
  __shared__ __align__(16) float2 Etab[940];           // all 4 twiddle tables
  __shared__ __align__(16) float2 bufA[NBC*200];       // Fh[bb][mp][19] (950) / yb floats (2000f)
  __shared__ __align__(16) float2 bufB[NBC*200];       // Tt[bb][mp][20] (1000) / Uu (600)
  __shared__ float2 yfs[NBC*NMP2*NM2];                 // 330
  __shared__ float2 Fxa[NL2*NMP2*NM2];                 // 396

  const int z = blockIdx.x, o = blockIdx.y, t = threadIdx.x;
  const float2* EsynT = Etab + TW_SYNT;   // [n][g]
  const float2* EsynA = Etab + TW_SYNA;   // [a][mp]
  const float2* EanaA = Etab + TW_ANAA;   // [a][m2p]
  const float2* EanaG = Etab + TW_ANAG;   // [g][n2i]

  for (int i = t; i < 940; i += 256) Etab[i] = Tg[i];
  for (int i = t; i < NL1*NMP1; i += 256) {
    int l = i/NMP1, mp = i%NMP1;
    Xs[i] = X[(l*BATCH + z)*NMP1 + mp];
  }
  for (int i = t; i < NL1*NM1; i += 256) {
    int l = i/NM1, mi = i%NM1;
    Ps[i] = Psi1[(l*F1C + o)*NM1 + mi];
  }
  for (int i = t; i < NL2*NMP2*NM2; i += 256) Fxa[i] = make_float2(0.f, 0.f);
  __syncthreads();

  // XPp[l][mp][n<20] = Xs[l][mp]*Ps[l][n] (0 at n=19)
  for (int i = t; i < NL1*NMP1*20; i += 256) {
    int n = i % 20; int r = i/20; int mp = r % NMP1; int l = r/NMP1;
    float2 v = make_float2(0.f, 0.f);
    if (n < NM1) {
      float2 xa = Xs[l*NMP1+mp], pp = Ps[l*NM1+n];
      v = make_float2(xa.x*pp.x - xa.y*pp.y, xa.x*pp.y + xa.y*pp.x);
    }
    XPp[i] = v;
  }
  __syncthreads();

  float2* Fh = bufA;           // [bb][mp][19]
  float2* Tt = bufB;           // [bb][mp][20]
  float*  yb = (float*)bufA;   // [bb][a][20] floats
  float2* Uu = bufB;           // [bb][m2p][20]

  for (int c = 0; c < NB1/NBC; ++c) {
    const int b0 = c*NBC;
    // ph1 (quad): Fh[bb][mp][n0..] = sum_l XPp * d1w, 4 n per thread (250 items)
    for (int i = t; i < NBC*NMP1*5; i += 256) {
      int q = i % 5; int r = i/5; int mp = r % NMP1; int bb = r/NMP1;
      int n0 = q*4;
      const float* dw = &d1w[(b0+bb)*(NM1*NM1) + (mp+9)*NM1 + n0];
      const float2* xp = &XPp[mp*20 + n0];
      float2 a0 = {0.f,0.f}, a1 = {0.f,0.f}, a2 = {0.f,0.f}, a3 = {0.f,0.f};
      #pragma unroll
      for (int l = 0; l < NL1; ++l) {
        const float* dwl = dw + l*(NB1*NM1*NM1);
        float w0 = dwl[0], w1 = dwl[1], w2 = dwl[2], w3 = dwl[3];
        float4 xa = *(const float4*)&xp[l*(NMP1*20)];
        float4 xb = *(const float4*)&xp[l*(NMP1*20) + 2];
        a0.x = fmaf(w0, xa.x, a0.x); a0.y = fmaf(w0, xa.y, a0.y);
        a1.x = fmaf(w1, xa.z, a1.x); a1.y = fmaf(w1, xa.w, a1.y);
        a2.x = fmaf(w2, xb.x, a2.x); a2.y = fmaf(w2, xb.y, a2.y);
        a3.x = fmaf(w3, xb.z, a3.x); a3.y = fmaf(w3, xb.w, a3.y);
      }
      float2* fr = &Fh[(bb*NMP1 + mp)*NM1 + n0];
      fr[0] = a0; fr[1] = a1; fr[2] = a2;
      if (n0 + 3 < NM1) fr[3] = a3;
    }
    __syncthreads();
    // ph2: Tt[bb][mp][g] = sum_n Fh[bb][mp][n]*EsynT[n][g], 4 g per thread (250 items)
    for (int i = t; i < NBC*NMP1*5; i += 256) {
      int gq = i % 5; int r = i / 5; int mp = r % NMP1; int bb = r / NMP1;
      int g0 = gq*4;
      const float2* fh = &Fh[(bb*NMP1 + mp)*NM1];
      float2 a0 = {0.f,0.f}, a1 = {0.f,0.f}, a2 = {0.f,0.f}, a3 = {0.f,0.f};
      #pragma unroll
      for (int n = 0; n < NM1; ++n) {
        float2 f = fh[n];
        float4 e01 = *(const float4*)&EsynT[n*NB1 + g0];
        float4 e23 = *(const float4*)&EsynT[n*NB1 + g0 + 2];
        a0.x += f.x*e01.x - f.y*e01.y; a0.y += f.x*e01.y + f.y*e01.x;
        a1.x += f.x*e01.z - f.y*e01.w; a1.y += f.x*e01.w + f.y*e01.z;
        a2.x += f.x*e23.x - f.y*e23.y; a2.y += f.x*e23.y + f.y*e23.x;
        a3.x += f.x*e23.z - f.y*e23.w; a3.y += f.x*e23.w + f.y*e23.z;
      }
      float2* tr = &Tt[(bb*NMP1 + mp)*NB1 + g0];
      tr[0] = a0; tr[1] = a1; tr[2] = a2; tr[3] = a3;
    }
    __syncthreads();
    // ph3: y[bb][a][g] = relu( Tt[bb][0][g].x + 2*sum_{mp>=1} Re(EsynA[a][mp]*Tt[bb][mp][g]) )
    for (int i = t; i < NBC*10*5; i += 256) {
      int gq = i % 5; int r = i / 5; int ap = r % 10; int bb = r / 10;
      int a0 = ap*2, g0 = gq*4;
      float4 t01 = *(const float4*)&Tt[(bb*NMP1)*NB1 + g0];
      float4 t23 = *(const float4*)&Tt[(bb*NMP1)*NB1 + g0 + 2];
      float s00=0.f,s01=0.f,s02=0.f,s03=0.f, s10=0.f,s11=0.f,s12=0.f,s13=0.f;
      #pragma unroll
      for (int mp = 1; mp < NMP1; ++mp) {
        float4 u01 = *(const float4*)&Tt[(bb*NMP1 + mp)*NB1 + g0];
        float4 u23 = *(const float4*)&Tt[(bb*NMP1 + mp)*NB1 + g0 + 2];
        float2 e0 = EsynA[a0*NMP1 + mp];
        float2 e1 = EsynA[(a0+1)*NMP1 + mp];
        s00 += e0.x*u01.x - e0.y*u01.y;
        s01 += e0.x*u01.z - e0.y*u01.w;
        s02 += e0.x*u23.x - e0.y*u23.y;
        s03 += e0.x*u23.z - e0.y*u23.w;
        s10 += e1.x*u01.x - e1.y*u01.y;
        s11 += e1.x*u01.z - e1.y*u01.w;
        s12 += e1.x*u23.x - e1.y*u23.y;
        s13 += e1.x*u23.z - e1.y*u23.w;
      }
      float* y0 = &yb[(bb*NB1 + a0)*NB1 + g0];
      float* y1 = &yb[(bb*NB1 + a0 + 1)*NB1 + g0];
      y0[0]=fmaxf(fmaf(2.f,s00,t01.x),0.f); y0[1]=fmaxf(fmaf(2.f,s01,t01.z),0.f);
      y0[2]=fmaxf(fmaf(2.f,s02,t23.x),0.f); y0[3]=fmaxf(fmaf(2.f,s03,t23.z),0.f);
      y1[0]=fmaxf(fmaf(2.f,s10,t01.x),0.f); y1[1]=fmaxf(fmaf(2.f,s11,t01.z),0.f);
      y1[2]=fmaxf(fmaf(2.f,s12,t23.x),0.f); y1[3]=fmaxf(fmaf(2.f,s13,t23.z),0.f);
    }
    __syncthreads();
    // ph4: U[bb][m2p][g] = sum_a y[bb][a][g]*EanaA[a][m2p]
    for (int i = t; i < NBC*NMP2*5; i += 256) {
      int gq = i % 5; int r = i / 5; int m2p = r % NMP2; int bb = r / NMP2;
      int g0 = gq*4;
      float2 u0 = {0.f,0.f}, u1 = {0.f,0.f}, u2 = {0.f,0.f}, u3 = {0.f,0.f};
      #pragma unroll
      for (int aa = 0; aa < NB1; ++aa) {
        float4 y4 = *(const float4*)&yb[(bb*NB1 + aa)*NB1 + g0];
        float2 e = EanaA[aa*NMP2 + m2p];
        u0.x = fmaf(y4.x, e.x, u0.x); u0.y = fmaf(y4.x, e.y, u0.y);
        u1.x = fmaf(y4.y, e.x, u1.x); u1.y = fmaf(y4.y, e.y, u1.y);
        u2.x = fmaf(y4.z, e.x, u2.x); u2.y = fmaf(y4.z, e.y, u2.y);
        u3.x = fmaf(y4.w, e.x, u3.x); u3.y = fmaf(y4.w, e.y, u3.y);
      }
      float2* ur = &Uu[(bb*NMP2 + m2p)*NB1 + g0];
      ur[0] = u0; ur[1] = u1; ur[2] = u2; ur[3] = u3;
    }
    __syncthreads();
    // ph5: yf[bb][m2p][n2] = sum_g U[bb][m2p][g]*EanaG[g][n2]
    for (int i = t; i < NBC*NMP2*6; i += 256) {
      int p = i % 6; int r = i / 6; int m2p = r % NMP2; int bb = r / NMP2;
      int n0 = p*2;
      const float2* ur = &Uu[(bb*NMP2 + m2p)*NB1];
      float2 acc0 = {0.f,0.f}, acc1 = {0.f,0.f};
      #pragma unroll
      for (int g = 0; g < NB1; ++g) {
        float2 u = ur[g];
        float4 e = *(const float4*)&EanaG[g*12 + n0];
        acc0.x += u.x*e.x - u.y*e.y; acc0.y += u.x*e.y + u.y*e.x;
        acc1.x += u.x*e.z - u.y*e.w; acc1.y += u.x*e.w + u.y*e.z;
      }
      yfs[(bb*NMP2 + m2p)*NM2 + n0] = acc0;
      if (n0 + 1 < NM2) yfs[(bb*NMP2 + m2p)*NM2 + n0 + 1] = acc1;
    }
    __syncthreads();
    // ph6: Fxa[l2][m2p][n2i] += sum_bb d12w * yf (m2>=0 only)
    for (int i = t; i < NL2*NMP2*NM2; i += 256) {
      int l2 = i/(NMP2*NM2); int r = i%(NMP2*NM2);
      int mnf = r + 5*NM2;
      float2 acc = Fxa[i];
      #pragma unroll
      for (int bb = 0; bb < NBC; ++bb) {
        float w = d12w[(l2*NB1 + b0 + bb)*(NM2*NM2) + mnf];
        float2 v = yfs[bb*(NMP2*NM2) + r];
        acc.x = fmaf(w, v.x, acc.x); acc.y = fmaf(w, v.y, acc.y);
      }
      Fxa[i] = acc;
    }
    __syncthreads();
  }
  for (int i = t; i < NL2*NMP2*NM2; i += 256) {
    int l2 = i/(NMP2*NM2); int r = i%(NMP2*NM2);
    int mp = r/NM2, n = r%NM2;
    Am[(size_t)l2*GEMM_MH*GEMM_K + (z*NMP2 + mp)*GEMM_K + o*NM2 + n] = Fxa[i];
  }
}

// ---------------- K5: per-l complex GEMM C[l][768][440] = A[l][768][220] * B[l][220][440] ----------------
__global__ __launch_bounds__(256) void k_so3mm(const float2* __restrict__ A,
                                               const float2* __restrict__ B,
                                               float2* __restrict__ C) {
  __shared__ float2 As[GM*ASTR];   // [m][k], padded stride
  __shared__ float2 Bs[GK*GN];     // interleaved [kk][j][tn]
  const int l = blockIdx.z;
  const int row0 = blockIdx.x*GM, col0 = blockIdx.y*GN;
  const int t = threadIdx.x;
  const float2* Ag = A + (size_t)l*GEMM_MH*GEMM_K;
  const float2* Bg = B + (size_t)l*GEMM_K*GEMM_N;
  float2* Cg = C + (size_t)l*GEMM_MH*GEMM_N;
  const int tn = t & 31, tm = t >> 5;   // 8 tm x 32 tn, acc 4x2
  float2 acc[4][2];
  #pragma unroll
  for (int i = 0; i < 4; ++i)
    #pragma unroll
    for (int j = 0; j < 2; ++j) acc[i][j] = make_float2(0.f, 0.f);

  for (int k0 = 0; k0 < GEMM_K; k0 += GK) {
    for (int i = t; i < GM*GK; i += 256) {
      int r = i/GK, kk = i%GK;
      As[r*ASTR + kk] = Ag[(size_t)(row0 + r)*GEMM_K + k0 + kk];
    }
    for (int i = t; i < GK*GN; i += 256) {
      int kk = i/GN, cc = i%GN;
      int col = col0 + cc;
      float2 v = (col < GEMM_N) ? Bg[(size_t)(k0 + kk)*GEMM_N + col] : make_float2(0.f, 0.f);
      Bs[(kk*2 + (cc & 1))*32 + (cc >> 1)] = v;
    }
    __syncthreads();
    #pragma unroll
    for (int kk = 0; kk < GK; ++kk) {
      float2 a[4], b[2];
      #pragma unroll
      for (int i = 0; i < 4; ++i) a[i] = As[(tm*4 + i)*ASTR + kk];
      #pragma unroll
      for (int j = 0; j < 2; ++j) b[j] = Bs[(kk*2 + j)*32 + tn];
      #pragma unroll
      for (int i = 0; i < 4; ++i)
        #pragma unroll
        for (int j = 0; j < 2; ++j) {
          acc[i][j].x = fmaf(a[i].x, b[j].x, acc[i][j].x);
          acc[i][j].x = fmaf(-a[i].y, b[j].y, acc[i][j].x);
          acc[i][j].y = fmaf(a[i].x, b[j].y, acc[i][j].y);
          acc[i][j].y = fmaf(a[i].y, b[j].x, acc[i][j].y);
        }
    }
    __syncthreads();
  }
  #pragma unroll
  for (int i = 0; i < 4; ++i) {
    int r = row0 + tm*4 + i;
    int cbase = col0 + tn*2;
    if (cbase < GEMM_N) {
      float4 v = make_float4(acc[i][0].x, acc[i][0].y, acc[i][1].x, acc[i][1].y);
      *(float4*)&Cg[(size_t)r*GEMM_N + cbase] = v;
    }
  }
}

// ---------------- K6: fused stage 2 tail. Block per (z,o). Hermitian C reconstruction. ----------------
__global__ __launch_bounds__(256) void k_stage2(const float2* __restrict__ C,
                                                const float* __restrict__ d2w,
                                                const float* __restrict__ w2n,
                                                const float2* __restrict__ Tg,
                                                float* __restrict__ feat) {
  __shared__ float2 Fos[NL2*NM2*NM2];
  __shared__ float2 Fh2[NB2*NM2*NM2];
  __shared__ float2 T2[NB2*NB2*NM2];
  __shared__ float2 Esyn2[NB2*NM2];
  __shared__ float w2s[NB2];
  __shared__ float red[256];
  const int z = blockIdx.x, o = blockIdx.y, t = threadIdx.x;
  for (int i = t; i < NB2*NM2; i += 256) Esyn2[i] = Tg[TW_S2 + i];
  if (t < NB2) w2s[t] = w2n[t];
  for (int i = t; i < NL2*NM2*NM2; i += 256) {
    int l = i/(NM2*NM2); int mn = i%(NM2*NM2);
    int m = mn/NM2, n = mn%NM2;
    float2 v;
    if (m >= 5) {
      v = C[(size_t)l*GEMM_MH*GEMM_N + (size_t)(z*NMP2 + m - 5)*GEMM_N + o*NM2 + n];
    } else {
      float2 cc = C[(size_t)l*GEMM_MH*GEMM_N + (size_t)(z*NMP2 + 5 - m)*GEMM_N + o*NM2 + (10 - n)];
      float s = ((m - n) & 1) ? -1.f : 1.f;
      v = make_float2(s*cc.x, -s*cc.y);
    }
    Fos[i] = v;
  }
  __syncthreads();
  for (int i = t; i < NB2*NM2*NM2; i += 256) {
    int b = i/(NM2*NM2); int mn = i%(NM2*NM2);
    float re = 0.f, im = 0.f;
    #pragma unroll
    for (int l = 0; l < NL2; ++l) {
      float w = d2w[(l*NB2 + b)*(NM2*NM2) + mn];
      float2 v = Fos[l*(NM2*NM2) + mn];
      re = fmaf(w, v.x, re); im = fmaf(w, v.y, im);
    }
    Fh2[i] = make_float2(re, im);
  }
  __syncthreads();
  for (int i = t; i < NB2*NB2*NM2; i += 256) {
    int ni = i % NM2; int r = i / NM2; int aa = r % NB2; int b = r / NB2;
    const float2* fh = &Fh2[b*(NM2*NM2) + ni];
    float re = 0.f, im = 0.f;
    #pragma unroll
    for (int mi = 0; mi < NM2; ++mi) {
      float2 f = fh[mi*NM2]; float2 e = Esyn2[aa*NM2+mi];
      re += e.x*f.x - e.y*f.y;
      im += e.x*f.y + e.y*f.x;
    }
    T2[i] = make_float2(re, im);
  }
  __syncthreads();
  float accT = 0.f;
  for (int i = t; i < NB2*NB2*NB2; i += 256) {
    int g = i % NB2; int r = i / NB2; int aa = r % NB2; int b = r / NB2;
    const float2* trow = &T2[(b*NB2 + aa)*NM2];
    float v = 0.f;
    #pragma unroll
    for (int ni = 0; ni < NM2; ++ni) {
      float2 tv = trow[ni]; float2 e = Esyn2[g*NM2+ni];
      v += e.x*tv.x - e.y*tv.y;
    }
    accT += w2s[b]*fmaxf(v, 0.f);
  }
  red[t] = accT;
  __syncthreads();
  for (int s = 128; s > 0; s >>= 1) {
    if (t < s) red[t] += red[t + s];
    __syncthreads();
  }
  if (t == 0) feat[z*F2C + o] = red[0] / (float)(NB2*NB2);
}

// ---------------- K7: linear head ----------------
__global__ void k_head(const float* __restrict__ feat, const float* __restrict__ w_lin,
                       const float* __restrict__ b_lin, float* __restrict__ out) {
  int idx = blockIdx.x*blockDim.x + threadIdx.x;
  if (idx >= BATCH*10) return;
  int z = idx/10, f = idx%10;
  float acc = b_lin[f];
  for (int o = 0; o < F2C; ++o) acc = fmaf(feat[z*F2C + o], w_lin[f*F2C + o], acc);
  out[idx] = acc;
}

extern "C" void kernel_launch(void* const* d_in, const int* in_sizes, int n_in,
                              void* d_out, int out_size, void* d_ws, size_t ws_size,
                              hipStream_t stream) {
  const float* x     = (const float*)d_in[0];
  const float* psi1  = (const float*)d_in[1];
  const float* psi2  = (const float*)d_in[2];
  const float* w_lin = (const float*)d_in[3];
  const float* b_lin = (const float*)d_in[4];
  float* out = (float*)d_out;
  float* ws  = (float*)d_ws;

  size_t off = 0;
  auto alloc = [&](size_t nfloats) { size_t o = off; off += (nfloats + 15) & ~(size_t)15; return o; };
  double* dhw30 = (double*)(ws + alloc(2*60));
  double* dhw10 = (double*)(ws + alloc(2*20));
  double* dhw6  = (double*)(ws + alloc(2*12));
  float2* Tglob = (float2*)(ws + alloc(2*TW_TOT));
  float*  wd_s2 = ws + alloc(N_WDS2);
  float2* Y1    = (float2*)(ws + alloc(2*(size_t)N_Y1));
  float*  d1w   = ws + alloc(N_D1W);
  float*  d12w  = ws + alloc(N_D12W);
  float2* D2    = (float2*)(ws + alloc(2*(size_t)N_D2));
  float*  d2w   = ws + alloc(N_D2W);
  float*  w2n   = ws + alloc(N_W2N);
  float2* X     = (float2*)(ws + alloc(2*(size_t)NL1*BATCH*NMP1));
  float2* Psi1p = (float2*)(ws + alloc(2*(size_t)NL1*F1C*NM1));
  float2* Bmat  = (float2*)(ws + alloc(2*(size_t)NL2*GEMM_K*GEMM_N));
  float2* Amat  = (float2*)(ws + alloc(2*(size_t)NL2*GEMM_MH*GEMM_K));
  float2* Cmat  = (float2*)(ws + alloc(2*(size_t)NL2*GEMM_MH*GEMM_N));
  float*  featp = ws + alloc((size_t)BATCH*F2C);
  if (ws_size < off*sizeof(float)) return;

  const int total_c = N_WDS2 + N_Y1 + N_D1W + N_D12W + N_D2 + N_D2W + N_W2N;
  k_weights<<<1, 256, 0, stream>>>(dhw30, dhw10, dhw6, Tglob);
  k_consts<<<(total_c + 255)/256, 256, 0, stream>>>(dhw30, dhw10, dhw6,
                                                    wd_s2, Y1, d1w, d12w, D2, d2w, w2n);
  k_s2fft<<<BATCH, 256, 0, stream>>>(x, wd_s2, Tglob, X);
  k_psi1<<<(NL1*F1C*NM1 + 255)/256, 256, 0, stream>>>(psi1, Y1, Psi1p);
  k_psi2<<<dim3(F1C*F2C/P2IO, NL2), 256, 0, stream>>>(psi2, D2, Bmat);
  k_stage1<<<dim3(BATCH, F1C), 256, 0, stream>>>(X, Psi1p, d1w, d12w, Tglob, Amat);
  k_so3mm<<<dim3(GEMM_MH/GM, (GEMM_N + GN - 1)/GN, NL2), 256, 0, stream>>>(Amat, Bmat, Cmat);
  k_stage2<<<dim3(BATCH, F2C), 256, 0, stream>>>(Cmat, d2w, w2n, Tglob, featp);
  k_head<<<(BATCH*10 + 255)/256, 256, 0, stream>>>(featp, w_lin, b_lin, out);
}

// Round 8
// 323.902 us; speedup vs baseline: 3.4059x; 1.0026x over previous
//
#include <hip/hip_runtime.h>
#include <math.h>

#define PI_D 3.14159265358979323846
#define PI_F 3.14159265358979f

#define BATCH 128
#define NM1 19    // full m range for B1 (m in [-9,9])
#define NMP1 10   // nonneg m freqs (m in [0,9])
#define NM2 11    // full freqs for B2 (m in [-5,5])
#define NMP2 6    // nonneg (m2 in [0,5])
#define NB_IN 60
#define NB1 20
#define NB2 12
#define NL1 10
#define NL2 6
#define F1C 20
#define F2C 40
#define NBC 5

// GEMM dims for so3mm: per-l, C[M][N] += A[M][K]*B[K][N] complex, Hermitian-halved M
#define GEMM_MH (BATCH*NMP2)  // 768
#define GEMM_N (F2C*NM2)      // 440
#define GEMM_K (F1C*NM2)      // 220
#define GM 32
#define GN 64
#define GK 20
#define ASTR 21               // padded As row stride

// twiddle table global layout (float2 offsets)
#define TW_SYNT 0       // [19][20] e^{+i 2pi g(n-9)/20}
#define TW_SYNA 380     // [20][10] e^{+i 2pi a mp/20}
#define TW_ANAA 580     // [20][6]  e^{-i 2pi a m2p/20}
#define TW_ANAG 700     // [20][12] e^{-i 2pi g(n2i-5)/20}, col 11 = 0
#define TW_S2   940     // [12][11] e^{+i 2pi k(mi-5)/12}
#define TW_60   1072    // [60][10] e^{-i 2pi a mp/60}
#define TW_TOT  1672

// constant tensor element counts
#define N_WDS2 (NL1*NB_IN*NM1)     // 11400 f32
#define N_Y1   (NL1*24*NM1)        // 4560 cplx
#define N_D1W  (NL1*NB1*NM1*NM1)   // 72200 f32
#define N_D12W (NL2*NB1*NM2*NM2)   // 14520 f32
#define N_D2   (NL2*144*NM2*NM2)   // 104544 cplx
#define N_D2W  (NL2*NB2*NM2*NM2)   // 8712 f32
#define N_W2N  (NB2)               // 12 f32

// ---------------- fp32 Wigner-d helpers (error ~1e-6 rel; tolerance is 2e-2) ----------------
__device__ __forceinline__ float ipow_f(float x, int e) {
  float r = 1.f;
  for (int i = 0; i < e; ++i) r *= x;
  return r;
}

__device__ float wigdf(const float* lf, int l, int m, int n, float beta) {
  if (m < -l || m > l || n < -l || n > l) return 0.f;
  float cb = cosf(0.5f*beta), sb = sinf(0.5f*beta);
  float pref = 0.5f*(lf[l+m]+lf[l-m]+lf[l+n]+lf[l-n]);
  int s0 = (n-m) > 0 ? (n-m) : 0;
  int s1 = (l+n) < (l-m) ? (l+n) : (l-m);
  float acc = 0.f;
  for (int s = s0; s <= s1; ++s) {
    float lc = pref - (lf[l+n-s]+lf[s]+lf[m-n+s]+lf[l-m-s]);
    float tt = expf(lc) * ipow_f(cb, 2*l+n-m-2*s) * ipow_f(sb, m-n+2*s);
    acc += ((m-n+s) & 1) ? -tt : tt;
  }
  return acc;
}

__device__ __forceinline__ float dh_beta_f(int b, int k) {
  return (float)(PI_D*(2*k+1)/(4.0*b));
}

__device__ float dh_w_f(int b, int k) {
  float beta = dh_beta_f(b, k), s = 0.f;
  for (int j = 0; j < b; ++j) s += sinf((2.f*(float)j+1.f)*beta)/(2.f*(float)j+1.f);
  return (2.f/(float)b)*sinf(beta)*s;
}

// ---------------- constants kernel (fp32, weights+twiddles merged) ----------------
__global__ __launch_bounds__(256) void k_consts(float2* __restrict__ Tg,
                         float* __restrict__ wd_s2, float2* __restrict__ Y1,
                         float* __restrict__ d1w, float* __restrict__ d12w,
                         float2* __restrict__ D2, float* __restrict__ d2w,
                         float* __restrict__ w2n) {
  __shared__ float lf[41];
  __shared__ float dhw30[60], dhw10[20], dhw6[12];
  int t = threadIdx.x;
  if (t < 41) lf[t] = (float)lgamma((double)t + 1.0);
  else if (t < 101) dhw30[t-41] = dh_w_f(30, t-41);
  else if (t < 121) dhw10[t-101] = dh_w_f(10, t-101);
  else if (t < 133) dhw6[t-121] = dh_w_f(6, t-121);
  __syncthreads();

  // block 0 also emits the twiddle tables (fp32, integer-mod phases)
  if (blockIdx.x == 0) {
    for (int i = t; i < TW_TOT; i += 256) {
      float2 v;
      if (i < TW_SYNA) {
        int j = i, n = j/NB1, g = j%NB1;
        int r = (g*(n-9)) % NB1; if (r < 0) r += NB1;
        float s, c; sincosf(2.f*PI_F*(float)r/(float)NB1, &s, &c);
        v = make_float2(c, s);
      } else if (i < TW_ANAA) {
        int j = i - TW_SYNA, a = j/NMP1, mp = j%NMP1;
        int r = (a*mp) % NB1;
        float s, c; sincosf(2.f*PI_F*(float)r/(float)NB1, &s, &c);
        v = make_float2(c, s);
      } else if (i < TW_ANAG) {
        int j = i - TW_ANAA, a = j/NMP2, m2p = j%NMP2;
        int r = (a*m2p) % NB1;
        float s, c; sincosf(2.f*PI_F*(float)r/(float)NB1, &s, &c);
        v = make_float2(c, -s);
      } else if (i < TW_S2) {
        int j = i - TW_ANAG, g = j/12, cI = j%12;
        if (cI == 11) v = make_float2(0.f, 0.f);
        else {
          int r = (g*(cI-5)) % NB1; if (r < 0) r += NB1;
          float s, c; sincosf(2.f*PI_F*(float)r/(float)NB1, &s, &c);
          v = make_float2(c, -s);
        }
      } else if (i < TW_60) {
        int j = i - TW_S2, k = j/NM2, mi = j%NM2;
        int r = (k*(mi-5)) % NB2; if (r < 0) r += NB2;
        float s, c; sincosf(2.f*PI_F*(float)r/(float)NB2, &s, &c);
        v = make_float2(c, s);
      } else {
        int j = i - TW_60, a = j/NMP1, mp = j%NMP1;
        int r = (a*mp) % NB_IN;
        float s, c; sincosf(2.f*PI_F*(float)r/(float)NB_IN, &s, &c);
        v = make_float2(c, -s);
      }
      Tg[i] = v;
    }
  }

  int gid = blockIdx.x*blockDim.x + t;

  if (gid < N_WDS2) {
    int l = gid/(NB_IN*NM1); int r = gid%(NB_IN*NM1); int k = r/NM1; int mi = r%NM1;
    int m = mi - 9;
    wd_s2[gid] = dhw30[k] * wigdf(lf, l, m, 0, dh_beta_f(30,k));
    return;
  }
  gid -= N_WDS2;
  if (gid < N_Y1) {
    int l = gid/(24*NM1); int r = gid%(24*NM1); int p = r/NM1; int mi = r%NM1;
    int m = mi - 9;
    float beta = (float)((double)(p/8 + 1) * PI_D/24.0);
    int pa = p%8;
    int rr = (-(m*pa)) % 8; if (rr < 0) rr += 8;
    float d = wigdf(lf, l, m, 0, beta);
    float s, c; sincosf(2.f*PI_F*(float)rr/8.f, &s, &c);
    Y1[gid] = make_float2(d*c, d*s);
    return;
  }
  gid -= N_Y1;
  if (gid < N_D1W) {
    int l = gid/(NB1*NM1*NM1); int r = gid%(NB1*NM1*NM1); int j = r/(NM1*NM1); int rr = r%(NM1*NM1);
    int m = rr/NM1 - 9, n = rr%NM1 - 9;
    d1w[gid] = (float)(2*l+1) * wigdf(lf, l, m, n, dh_beta_f(10,j));
    return;
  }
  gid -= N_D1W;
  if (gid < N_D12W) {
    int l = gid/(NB1*NM2*NM2); int r = gid%(NB1*NM2*NM2); int j = r/(NM2*NM2); int rr = r%(NM2*NM2);
    int m = rr/NM2 - 5, n = rr%NM2 - 5;
    d12w[gid] = dhw10[j] * wigdf(lf, l, m, n, dh_beta_f(10,j));
    return;
  }
  gid -= N_D12W;
  if (gid < N_D2) {
    int l = gid/(144*NM2*NM2); int r = gid%(144*NM2*NM2); int p = r/(NM2*NM2); int rr = r%(NM2*NM2);
    int m = rr/NM2 - 5, n = rr%NM2 - 5;
    float beta = (float)((double)(p/48 + 1) * PI_D/24.0);
    int pa = (p/6)%8, pg = p%6;
    // phase = -(m*2pi*pa/8 + n*2pi*pg/6) = -2pi*(3*m*pa + 4*n*pg)/24
    int rr24 = (-(3*m*pa + 4*n*pg)) % 24; if (rr24 < 0) rr24 += 24;
    float d = wigdf(lf, l, m, n, beta);
    float s, c; sincosf(2.f*PI_F*(float)rr24/24.f, &s, &c);
    D2[gid] = make_float2(d*c, d*s);
    return;
  }
  gid -= N_D2;
  if (gid < N_D2W) {
    int l = gid/(NB2*NM2*NM2); int r = gid%(NB2*NM2*NM2); int j = r/(NM2*NM2); int rr = r%(NM2*NM2);
    int m = rr/NM2 - 5, n = rr%NM2 - 5;
    d2w[gid] = (float)(2*l+1) * wigdf(lf, l, m, n, dh_beta_f(6,j));
    return;
  }
  gid -= N_D2W;
  if (gid < N_W2N) {
    float s = 0.f;
    for (int j = 0; j < NB2; ++j) s += dhw6[j];
    w2n[gid] = dhw6[gid]/s;
    return;
  }
}

// ---------------- K1: azimuthal DFT (60pt, 10 nonneg freqs) + Legendre -> X[10][128][10] ----------------
__global__ __launch_bounds__(256) void k_s2fft(const float* __restrict__ x,
                                               const float* __restrict__ wd_s2,
                                               const float2* __restrict__ Tg,
                                               float2* __restrict__ X) {
  __shared__ float xs[3600];
  __shared__ float2 xf[NB_IN*NMP1];
  __shared__ float2 tw60[NB_IN*NMP1];
  const int z = blockIdx.x, t = threadIdx.x;
  for (int i = t; i < NB_IN*NMP1; i += 256) tw60[i] = Tg[TW_60 + i];
  for (int i = t; i < 3600; i += 256) xs[i] = x[z*3600 + i];
  __syncthreads();
  for (int i = t; i < NB_IN*NMP1; i += 256) {
    int k = i/NMP1, mp = i%NMP1;
    float re = 0.f, im = 0.f;
    const float* xrow = &xs[k*NB_IN];
    for (int a = 0; a < NB_IN; ++a) {
      float v = xrow[a];
      float2 e = tw60[a*NMP1 + mp];
      re = fmaf(v, e.x, re);
      im = fmaf(v, e.y, im);
    }
    xf[i] = make_float2(re, im);
  }
  __syncthreads();
  for (int i = t; i < NL1*NMP1; i += 256) {
    int l = i/NMP1, mp = i%NMP1;
    float re = 0.f, im = 0.f;
    for (int k = 0; k < NB_IN; ++k) {
      float w = wd_s2[(l*NB_IN+k)*NM1 + mp + 9];
      float2 v = xf[k*NMP1 + mp];
      re = fmaf(w, v.x, re); im = fmaf(w, v.y, im);
    }
    X[(l*BATCH + z)*NMP1 + mp] = make_float2(re, im);
  }
}

// ---------------- K2: Psi1[l][o][m] = sum_g psi1[0][o][g] * Y1[l][g][m] ----------------
__global__ void k_psi1(const float* __restrict__ psi1, const float2* __restrict__ Y1,
                       float2* __restrict__ Psi1) {
  int idx = blockIdx.x*blockDim.x + threadIdx.x;
  if (idx >= NL1*F1C*NM1) return;
  int l = idx/(F1C*NM1); int r = idx%(F1C*NM1); int o = r/NM1; int mi = r%NM1;
  float re = 0.f, im = 0.f;
  for (int g = 0; g < 24; ++g) {
    float w = psi1[o*24 + g];
    float2 y = Y1[(l*24+g)*NM1 + mi];
    re = fmaf(w, y.x, re); im = fmaf(w, y.y, im);
  }
  Psi1[idx] = make_float2(re, im);
}

// ---------------- K3: LDS-tiled: B[l][(i*11+k)][(o*11+n)] = sum_g psi2[io][g]*D2[l][g][kn] ----------------
#define P2IO 40
#define P2GC 24
__global__ __launch_bounds__(256) void k_psi2(const float* __restrict__ psi2,
                                              const float2* __restrict__ D2,
                                              float2* __restrict__ Bm) {
  __shared__ __align__(16) float2 Ds[P2GC*122];
  __shared__ float Ws[P2IO*P2GC];
  const int io0 = blockIdx.x*P2IO, l = blockIdx.y, t = threadIdx.x;
  const int tio = t/31, tmn = t%31;
  const int mn0 = tmn*4;
  float2 acc[5][4];
  #pragma unroll
  for (int i = 0; i < 5; ++i)
    #pragma unroll
    for (int j = 0; j < 4; ++j) acc[i][j] = make_float2(0.f, 0.f);

  for (int gc = 0; gc < 144; gc += P2GC) {
    for (int i = t; i < P2GC*121; i += 256) {
      int g = i/121, mn = i%121;
      Ds[g*122 + mn] = D2[(size_t)(l*144 + gc + g)*121 + mn];
    }
    for (int i = t; i < P2IO*P2GC; i += 256) {
      int io = i/P2GC, g = i%P2GC;
      Ws[i] = psi2[(io0 + io)*144 + gc + g];
    }
    __syncthreads();
    if (tio < 8) {
      for (int g = 0; g < P2GC; ++g) {
        float4 d01 = *(const float4*)&Ds[g*122 + mn0];
        float4 d23 = *(const float4*)&Ds[g*122 + mn0 + 2];
        float w0 = Ws[(tio*5 + 0)*P2GC + g];
        float w1 = Ws[(tio*5 + 1)*P2GC + g];
        float w2 = Ws[(tio*5 + 2)*P2GC + g];
        float w3 = Ws[(tio*5 + 3)*P2GC + g];
        float w4 = Ws[(tio*5 + 4)*P2GC + g];
        float dx[4] = {d01.x, d01.z, d23.x, d23.z};
        float dy[4] = {d01.y, d01.w, d23.y, d23.w};
        float wv[5] = {w0, w1, w2, w3, w4};
        #pragma unroll
        for (int i = 0; i < 5; ++i)
          #pragma unroll
          for (int j = 0; j < 4; ++j) {
            acc[i][j].x = fmaf(wv[i], dx[j], acc[i][j].x);
            acc[i][j].y = fmaf(wv[i], dy[j], acc[i][j].y);
          }
      }
    }
    __syncthreads();
  }
  if (tio < 8) {
    #pragma unroll
    for (int i = 0; i < 5; ++i) {
      int io = io0 + tio*5 + i;
      int ii = io/F2C, oo = io%F2C;
      #pragma unroll
      for (int j = 0; j < 4; ++j) {
        int mn = mn0 + j;
        if (mn < 121) {
          int k = mn/NM2, n = mn%NM2;
          Bm[(size_t)l*GEMM_K*GEMM_N + (ii*NM2 + k)*GEMM_N + oo*NM2 + n] = acc[i][j];
        }
      }
    }
  }
}

// ---------------- K4: fused stage 1, Hermitian-halved, split-l XP (4 blocks/CU). ----------------
__global__ __launch_bounds__(256) void k_stage1(const float2* __restrict__ X,
                                                const float2* __restrict__ Psi1,
                                                const float* __restrict__ d1w,
                                                const float* __restrict__ d12w,
                                                const float2* __restrict__ Tg,
                                                float2* __restrict__ Am) {
  __shared__ float2 Xs[NL1*NMP1];                      // 100
  __shared__ float2 Ps[NL1*NM1];                       // 190
  __shared__ __align__(16) float2 XPh[5*NMP1*20];      // 1000: half-l X*Ps, padded n-col 19 = 0
  __shared__ __align__(16) float2 Etab[940];
  __shared__ __align__(16) float2 bufA[NBC*200];       // Fh[bb][mp][19] (950) / yb floats (2000f)
  __shared__ __align__(16) float2 bufB[NBC*200];       // Tt[bb][mp][20] (1000) / Uu (600)
  __shared__ float2 yfs[NBC*NMP2*NM2];                 // 330
  __shared__ float2 Fxa[NL2*NMP2*NM2];                 // 396

  const int z = blockIdx.x, o = blockIdx.y, t = threadIdx.x;
  const float2* EsynT = Etab + TW_SYNT;
  const float2* EsynA = Etab + TW_SYNA;
  const float2* EanaA = Etab + TW_ANAA;
  const float2* EanaG = Etab + TW_ANAG;

  for (int i = t; i < 940; i += 256) Etab[i] = Tg[i];
  for (int i = t; i < NL1*NMP1; i += 256) {
    int l = i/NMP1, mp = i%NMP1;
    Xs[i] = X[(l*BATCH + z)*NMP1 + mp];
  }
  for (int i = t; i < NL1*NM1; i += 256) {
    int l = i/NM1, mi = i%NM1;
    Ps[i] = Psi1[(l*F1C + o)*NM1 + mi];
  }
  for (int i = t; i < NL2*NMP2*NM2; i += 256) Fxa[i] = make_float2(0.f, 0.f);
  __syncthreads();

  float2* Fh = bufA;
  float2* Tt = bufB;
  float*  yb = (float*)bufA;
  float2* Uu = bufB;

  for (int c = 0; c < NB1/NBC; ++c) {
    const int b0 = c*NBC;
    // ph1 in two l-halves: build XPh then accumulate
    #pragma unroll
    for (int lh = 0; lh < 2; ++lh) {
      const int l0 = lh*5;
      for (int i = t; i < 5*NMP1*20; i += 256) {
        int n = i % 20; int r = i/20; int mp = r % NMP1; int ll = r/NMP1;
        float2 v = make_float2(0.f, 0.f);
        if (n < NM1) {
          float2 xa = Xs[(l0+ll)*NMP1+mp], pp = Ps[(l0+ll)*NM1+n];
          v = make_float2(xa.x*pp.x - xa.y*pp.y, xa.x*pp.y + xa.y*pp.x);
        }
        XPh[i] = v;
      }
      __syncthreads();
      for (int i = t; i < NBC*NMP1*5; i += 256) {
        int q = i % 5; int r = i/5; int mp = r % NMP1; int bb = r/NMP1;
        int n0 = q*4;
        const float* dw = &d1w[(b0+bb)*(NM1*NM1) + (mp+9)*NM1 + n0];
        const float2* xp = &XPh[mp*20 + n0];
        float2 a0, a1, a2, a3;
        float2* fr = &Fh[(bb*NMP1 + mp)*NM1 + n0];
        if (lh == 0) { a0 = a1 = a2 = a3 = make_float2(0.f, 0.f); }
        else {
          a0 = fr[0]; a1 = fr[1]; a2 = fr[2];
          a3 = (n0 + 3 < NM1) ? fr[3] : make_float2(0.f, 0.f);
        }
        #pragma unroll
        for (int ll = 0; ll < 5; ++ll) {
          const float* dwl = dw + (l0+ll)*(NB1*NM1*NM1);
          float w0 = dwl[0], w1 = dwl[1], w2 = dwl[2], w3 = dwl[3];
          float4 xa = *(const float4*)&xp[ll*(NMP1*20)];
          float4 xb = *(const float4*)&xp[ll*(NMP1*20) + 2];
          a0.x = fmaf(w0, xa.x, a0.x); a0.y = fmaf(w0, xa.y, a0.y);
          a1.x = fmaf(w1, xa.z, a1.x); a1.y = fmaf(w1, xa.w, a1.y);
          a2.x = fmaf(w2, xb.x, a2.x); a2.y = fmaf(w2, xb.y, a2.y);
          a3.x = fmaf(w3, xb.z, a3.x); a3.y = fmaf(w3, xb.w, a3.y);
        }
        fr[0] = a0; fr[1] = a1; fr[2] = a2;
        if (n0 + 3 < NM1) fr[3] = a3;
      }
      __syncthreads();
    }
    // ph2: Tt[bb][mp][g] = sum_n Fh[bb][mp][n]*EsynT[n][g]
    for (int i = t; i < NBC*NMP1*5; i += 256) {
      int gq = i % 5; int r = i / 5; int mp = r % NMP1; int bb = r / NMP1;
      int g0 = gq*4;
      const float2* fh = &Fh[(bb*NMP1 + mp)*NM1];
      float2 a0 = {0.f,0.f}, a1 = {0.f,0.f}, a2 = {0.f,0.f}, a3 = {0.f,0.f};
      #pragma unroll
      for (int n = 0; n < NM1; ++n) {
        float2 f = fh[n];
        float4 e01 = *(const float4*)&EsynT[n*NB1 + g0];
        float4 e23 = *(const float4*)&EsynT[n*NB1 + g0 + 2];
        a0.x += f.x*e01.x - f.y*e01.y; a0.y += f.x*e01.y + f.y*e01.x;
        a1.x += f.x*e01.z - f.y*e01.w; a1.y += f.x*e01.w + f.y*e01.z;
        a2.x += f.x*e23.x - f.y*e23.y; a2.y += f.x*e23.y + f.y*e23.x;
        a3.x += f.x*e23.z - f.y*e23.w; a3.y += f.x*e23.w + f.y*e23.z;
      }
      float2* tr = &Tt[(bb*NMP1 + mp)*NB1 + g0];
      tr[0] = a0; tr[1] = a1; tr[2] = a2; tr[3] = a3;
    }
    __syncthreads();
    // ph3: y = relu( Tt[mp=0].x + 2*sum Re(EsynA*Tt) )
    for (int i = t; i < NBC*10*5; i += 256) {
      int gq = i % 5; int r = i / 5; int ap = r % 10; int bb = r / 10;
      int a0 = ap*2, g0 = gq*4;
      float4 t01 = *(const float4*)&Tt[(bb*NMP1)*NB1 + g0];
      float4 t23 = *(const float4*)&Tt[(bb*NMP1)*NB1 + g0 + 2];
      float s00=0.f,s01=0.f,s02=0.f,s03=0.f, s10=0.f,s11=0.f,s12=0.f,s13=0.f;
      #pragma unroll
      for (int mp = 1; mp < NMP1; ++mp) {
        float4 u01 = *(const float4*)&Tt[(bb*NMP1 + mp)*NB1 + g0];
        float4 u23 = *(const float4*)&Tt[(bb*NMP1 + mp)*NB1 + g0 + 2];
        float2 e0 = EsynA[a0*NMP1 + mp];
        float2 e1 = EsynA[(a0+1)*NMP1 + mp];
        s00 += e0.x*u01.x - e0.y*u01.y;
        s01 += e0.x*u01.z - e0.y*u01.w;
        s02 += e0.x*u23.x - e0.y*u23.y;
        s03 += e0.x*u23.z - e0.y*u23.w;
        s10 += e1.x*u01.x - e1.y*u01.y;
        s11 += e1.x*u01.z - e1.y*u01.w;
        s12 += e1.x*u23.x - e1.y*u23.y;
        s13 += e1.x*u23.z - e1.y*u23.w;
      }
      float* y0 = &yb[(bb*NB1 + a0)*NB1 + g0];
      float* y1 = &yb[(bb*NB1 + a0 + 1)*NB1 + g0];
      y0[0]=fmaxf(fmaf(2.f,s00,t01.x),0.f); y0[1]=fmaxf(fmaf(2.f,s01,t01.z),0.f);
      y0[2]=fmaxf(fmaf(2.f,s02,t23.x),0.f); y0[3]=fmaxf(fmaf(2.f,s03,t23.z),0.f);
      y1[0]=fmaxf(fmaf(2.f,s10,t01.x),0.f); y1[1]=fmaxf(fmaf(2.f,s11,t01.z),0.f);
      y1[2]=fmaxf(fmaf(2.f,s12,t23.x),0.f); y1[3]=fmaxf(fmaf(2.f,s13,t23.z),0.f);
    }
    __syncthreads();
    // ph4: U[bb][m2p][g] = sum_a y[bb][a][g]*EanaA[a][m2p]
    for (int i = t; i < NBC*NMP2*5; i += 256) {
      int gq = i % 5; int r = i / 5; int m2p = r % NMP2; int bb = r / NMP2;
      int g0 = gq*4;
      float2 u0 = {0.f,0.f}, u1 = {0.f,0.f}, u2 = {0.f,0.f}, u3 = {0.f,0.f};
      #pragma unroll
      for (int aa = 0; aa < NB1; ++aa) {
        float4 y4 = *(const float4*)&yb[(bb*NB1 + aa)*NB1 + g0];
        float2 e = EanaA[aa*NMP2 + m2p];
        u0.x = fmaf(y4.x, e.x, u0.x); u0.y = fmaf(y4.x, e.y, u0.y);
        u1.x = fmaf(y4.y, e.x, u1.x); u1.y = fmaf(y4.y, e.y, u1.y);
        u2.x = fmaf(y4.z, e.x, u2.x); u2.y = fmaf(y4.z, e.y, u2.y);
        u3.x = fmaf(y4.w, e.x, u3.x); u3.y = fmaf(y4.w, e.y, u3.y);
      }
      float2* ur = &Uu[(bb*NMP2 + m2p)*NB1 + g0];
      ur[0] = u0; ur[1] = u1; ur[2] = u2; ur[3] = u3;
    }
    __syncthreads();
    // ph5: yf[bb][m2p][n2] = sum_g U[bb][m2p][g]*EanaG[g][n2]
    for (int i = t; i < NBC*NMP2*6; i += 256) {
      int p = i % 6; int r = i / 6; int m2p = r % NMP2; int bb = r / NMP2;
      int n0 = p*2;
      const float2* ur = &Uu[(bb*NMP2 + m2p)*NB1];
      float2 acc0 = {0.f,0.f}, acc1 = {0.f,0.f};
      #pragma unroll
      for (int g = 0; g < NB1; ++g) {
        float2 u = ur[g];
        float4 e = *(const float4*)&EanaG[g*12 + n0];
        acc0.x += u.x*e.x - u.y*e.y; acc0.y += u.x*e.y + u.y*e.x;
        acc1.x += u.x*e.z - u.y*e.w; acc1.y += u.x*e.w + u.y*e.z;
      }
      yfs[(bb*NMP2 + m2p)*NM2 + n0] = acc0;
      if (n0 + 1 < NM2) yfs[(bb*NMP2 + m2p)*NM2 + n0 + 1] = acc1;
    }
    __syncthreads();
    // ph6: Fxa += sum_bb d12w * yf (m2>=0 only)
    for (int i = t; i < NL2*NMP2*NM2; i += 256) {
      int l2 = i/(NMP2*NM2); int r = i%(NMP2*NM2);
      int mnf = r + 5*NM2;
      float2 acc = Fxa[i];
      #pragma unroll
      for (int bb = 0; bb < NBC; ++bb) {
        float w = d12w[(l2*NB1 + b0 + bb)*(NM2*NM2) + mnf];
        float2 v = yfs[bb*(NMP2*NM2) + r];
        acc.x = fmaf(w, v.x, acc.x); acc.y = fmaf(w, v.y, acc.y);
      }
      Fxa[i] = acc;
    }
    __syncthreads();
  }
  for (int i = t; i < NL2*NMP2*NM2; i += 256) {
    int l2 = i/(NMP2*NM2); int r = i%(NMP2*NM2);
    int mp = r/NM2, n = r%NM2;
    Am[(size_t)l2*GEMM_MH*GEMM_K + (z*NMP2 + mp)*GEMM_K + o*NM2 + n] = Fxa[i];
  }
}

// ---------------- K5: per-l complex GEMM C[l][768][440] = A[l][768][220] * B[l][220][440] ----------------
__global__ __launch_bounds__(256) void k_so3mm(const float2* __restrict__ A,
                                               const float2* __restrict__ B,
                                               float2* __restrict__ C) {
  __shared__ float2 As[GM*ASTR];
  __shared__ float2 Bs[GK*GN];
  const int l = blockIdx.z;
  const int row0 = blockIdx.x*GM, col0 = blockIdx.y*GN;
  const int t = threadIdx.x;
  const float2* Ag = A + (size_t)l*GEMM_MH*GEMM_K;
  const float2* Bg = B + (size_t)l*GEMM_K*GEMM_N;
  float2* Cg = C + (size_t)l*GEMM_MH*GEMM_N;
  const int tn = t & 31, tm = t >> 5;
  float2 acc[4][2];
  #pragma unroll
  for (int i = 0; i < 4; ++i)
    #pragma unroll
    for (int j = 0; j < 2; ++j) acc[i][j] = make_float2(0.f, 0.f);

  for (int k0 = 0; k0 < GEMM_K; k0 += GK) {
    for (int i = t; i < GM*GK; i += 256) {
      int r = i/GK, kk = i%GK;
      As[r*ASTR + kk] = Ag[(size_t)(row0 + r)*GEMM_K + k0 + kk];
    }
    for (int i = t; i < GK*GN; i += 256) {
      int kk = i/GN, cc = i%GN;
      int col = col0 + cc;
      float2 v = (col < GEMM_N) ? Bg[(size_t)(k0 + kk)*GEMM_N + col] : make_float2(0.f, 0.f);
      Bs[(kk*2 + (cc & 1))*32 + (cc >> 1)] = v;
    }
    __syncthreads();
    #pragma unroll
    for (int kk = 0; kk < GK; ++kk) {
      float2 a[4], b[2];
      #pragma unroll
      for (int i = 0; i < 4; ++i) a[i] = As[(tm*4 + i)*ASTR + kk];
      #pragma unroll
      for (int j = 0; j < 2; ++j) b[j] = Bs[(kk*2 + j)*32 + tn];
      #pragma unroll
      for (int i = 0; i < 4; ++i)
        #pragma unroll
        for (int j = 0; j < 2; ++j) {
          acc[i][j].x = fmaf(a[i].x, b[j].x, acc[i][j].x);
          acc[i][j].x = fmaf(-a[i].y, b[j].y, acc[i][j].x);
          acc[i][j].y = fmaf(a[i].x, b[j].y, acc[i][j].y);
          acc[i][j].y = fmaf(a[i].y, b[j].x, acc[i][j].y);
        }
    }
    __syncthreads();
  }
  #pragma unroll
  for (int i = 0; i < 4; ++i) {
    int r = row0 + tm*4 + i;
    int cbase = col0 + tn*2;
    if (cbase < GEMM_N) {
      float4 v = make_float4(acc[i][0].x, acc[i][0].y, acc[i][1].x, acc[i][1].y);
      *(float4*)&Cg[(size_t)r*GEMM_N + cbase] = v;
    }
  }
}

// ---------------- K6: fused stage 2 tail. Hermitian C reconstruction; shfl reduce. ----------------
__global__ __launch_bounds__(256) void k_stage2(const float2* __restrict__ C,
                                                const float* __restrict__ d2w,
                                                const float* __restrict__ w2n,
                                                const float2* __restrict__ Tg,
                                                float* __restrict__ feat) {
  __shared__ float2 Fos[NL2*NM2*NM2];
  __shared__ float2 Fh2[NB2*NM2*NM2];
  __shared__ float2 T2[NB2*NB2*NM2];
  __shared__ float2 Esyn2[NB2*NM2];
  __shared__ float w2s[NB2];
  __shared__ float wred[4];
  const int z = blockIdx.x, o = blockIdx.y, t = threadIdx.x;
  for (int i = t; i < NB2*NM2; i += 256) Esyn2[i] = Tg[TW_S2 + i];
  if (t < NB2) w2s[t] = w2n[t];
  for (int i = t; i < NL2*NM2*NM2; i += 256) {
    int l = i/(NM2*NM2); int mn = i%(NM2*NM2);
    int m = mn/NM2, n = mn%NM2;
    float2 v;
    if (m >= 5) {
      v = C[(size_t)l*GEMM_MH*GEMM_N + (size_t)(z*NMP2 + m - 5)*GEMM_N + o*NM2 + n];
    } else {
      float2 cc = C[(size_t)l*GEMM_MH*GEMM_N + (size_t)(z*NMP2 + 5 - m)*GEMM_N + o*NM2 + (10 - n)];
      float s = ((m - n) & 1) ? -1.f : 1.f;
      v = make_float2(s*cc.x, -s*cc.y);
    }
    Fos[i] = v;
  }
  __syncthreads();
  for (int i = t; i < NB2*NM2*NM2; i += 256) {
    int b = i/(NM2*NM2); int mn = i%(NM2*NM2);
    float re = 0.f, im = 0.f;
    #pragma unroll
    for (int l = 0; l < NL2; ++l) {
      float w = d2w[(l*NB2 + b)*(NM2*NM2) + mn];
      float2 v = Fos[l*(NM2*NM2) + mn];
      re = fmaf(w, v.x, re); im = fmaf(w, v.y, im);
    }
    Fh2[i] = make_float2(re, im);
  }
  __syncthreads();
  for (int i = t; i < NB2*NB2*NM2; i += 256) {
    int ni = i % NM2; int r = i / NM2; int aa = r % NB2; int b = r / NB2;
    const float2* fh = &Fh2[b*(NM2*NM2) + ni];
    float re = 0.f, im = 0.f;
    #pragma unroll
    for (int mi = 0; mi < NM2; ++mi) {
      float2 f = fh[mi*NM2]; float2 e = Esyn2[aa*NM2+mi];
      re += e.x*f.x - e.y*f.y;
      im += e.x*f.y + e.y*f.x;
    }
    T2[i] = make_float2(re, im);
  }
  __syncthreads();
  float accT = 0.f;
  for (int i = t; i < NB2*NB2*NB2; i += 256) {
    int g = i % NB2; int r = i / NB2; int aa = r % NB2; int b = r / NB2;
    const float2* trow = &T2[(b*NB2 + aa)*NM2];
    float v = 0.f;
    #pragma unroll
    for (int ni = 0; ni < NM2; ++ni) {
      float2 tv = trow[ni]; float2 e = Esyn2[g*NM2+ni];
      v += e.x*tv.x - e.y*tv.y;
    }
    accT += w2s[b]*fmaxf(v, 0.f);
  }
  #pragma unroll
  for (int off = 32; off > 0; off >>= 1) accT += __shfl_down(accT, off);
  if ((t & 63) == 0) wred[t >> 6] = accT;
  __syncthreads();
  if (t == 0) feat[z*F2C + o] = (wred[0]+wred[1]+wred[2]+wred[3]) / (float)(NB2*NB2);
}

// ---------------- K7: linear head ----------------
__global__ void k_head(const float* __restrict__ feat, const float* __restrict__ w_lin,
                       const float* __restrict__ b_lin, float* __restrict__ out) {
  int idx = blockIdx.x*blockDim.x + threadIdx.x;
  if (idx >= BATCH*10) return;
  int z = idx/10, f = idx%10;
  float acc = b_lin[f];
  for (int o = 0; o < F2C; ++o) acc = fmaf(feat[z*F2C + o], w_lin[f*F2C + o], acc);
  out[idx] = acc;
}

extern "C" void kernel_launch(void* const* d_in, const int* in_sizes, int n_in,
                              void* d_out, int out_size, void* d_ws, size_t ws_size,
                              hipStream_t stream) {
  const float* x     = (const float*)d_in[0];
  const float* psi1  = (const float*)d_in[1];
  const float* psi2  = (const float*)d_in[2];
  const float* w_lin = (const float*)d_in[3];
  const float* b_lin = (const float*)d_in[4];
  float* out = (float*)d_out;
  float* ws  = (float*)d_ws;

  size_t off = 0;
  auto alloc = [&](size_t nfloats) { size_t o = off; off += (nfloats + 15) & ~(size_t)15; return o; };
  float2* Tglob = (float2*)(ws + alloc(2*TW_TOT));
  float*  wd_s2 = ws + alloc(N_WDS2);
  float2* Y1    = (float2*)(ws + alloc(2*(size_t)N_Y1));
  float*  d1w   = ws + alloc(N_D1W);
  float*  d12w  = ws + alloc(N_D12W);
  float2* D2    = (float2*)(ws + alloc(2*(size_t)N_D2));
  float*  d2w   = ws + alloc(N_D2W);
  float*  w2n   = ws + alloc(N_W2N);
  float2* X     = (float2*)(ws + alloc(2*(size_t)NL1*BATCH*NMP1));
  float2* Psi1p = (float2*)(ws + alloc(2*(size_t)NL1*F1C*NM1));
  float2* Bmat  = (float2*)(ws + alloc(2*(size_t)NL2*GEMM_K*GEMM_N));
  float2* Amat  = (float2*)(ws + alloc(2*(size_t)NL2*GEMM_MH*GEMM_K));
  float2* Cmat  = (float2*)(ws + alloc(2*(size_t)NL2*GEMM_MH*GEMM_N));
  float*  featp = ws + alloc((size_t)BATCH*F2C);
  if (ws_size < off*sizeof(float)) return;

  const int total_c = N_WDS2 + N_Y1 + N_D1W + N_D12W + N_D2 + N_D2W + N_W2N;
  k_consts<<<(total_c + 255)/256, 256, 0, stream>>>(Tglob, wd_s2, Y1, d1w, d12w, D2, d2w, w2n);
  k_s2fft<<<BATCH, 256, 0, stream>>>(x, wd_s2, Tglob, X);
  k_psi1<<<(NL1*F1C*NM1 + 255)/256, 256, 0, stream>>>(psi1, Y1, Psi1p);
  k_psi2<<<dim3(F1C*F2C/P2IO, NL2), 256, 0, stream>>>(psi2, D2, Bmat);
  k_stage1<<<dim3(BATCH, F1C), 256, 0, stream>>>(X, Psi1p, d1w, d12w, Tglob, Amat);
  k_so3mm<<<dim3(GEMM_MH/GM, (GEMM_N + GN - 1)/GN, NL2), 256, 0, stream>>>(Amat, Bmat, Cmat);
  k_stage2<<<dim3(BATCH, F2C), 256, 0, stream>>>(Cmat, d2w, w2n, Tglob, featp);
  k_head<<<(BATCH*10 + 255)/256, 256, 0, stream>>>(featp, w_lin, b_lin, out);
}

// Round 9
// 320.535 us; speedup vs baseline: 3.4417x; 1.0105x over previous
//
#include <hip/hip_runtime.h>
#include <math.h>

#define PI_D 3.14159265358979323846
#define PI_F 3.14159265358979f

#define BATCH 128
#define NM1 19    // full m range for B1 (m in [-9,9])
#define NMP1 10   // nonneg m freqs (m in [0,9])
#define NM2 11    // full freqs for B2 (m in [-5,5])
#define NMP2 6    // nonneg (m2 in [0,5])
#define NB_IN 60
#define NB1 20
#define NB2 12
#define NL1 10
#define NL2 6
#define F1C 20
#define F2C 40
#define NBC 5

// GEMM dims for so3mm: per-l, C[M][N] += A[M][K]*B[K][N] complex, Hermitian-halved M
#define GEMM_MH (BATCH*NMP2)  // 768
#define GEMM_N (F2C*NM2)      // 440
#define GEMM_K (F1C*NM2)      // 220
#define GM 64
#define GN 64
#define GK 20
#define ASTR 21               // padded As row stride

// twiddle table global layout (float2 offsets)
#define TW_SYNT 0       // [19][20] e^{+i 2pi g(n-9)/20}
#define TW_SYNA 380     // [20][10] e^{+i 2pi a mp/20}
#define TW_ANAA 580     // [20][6]  e^{-i 2pi a m2p/20}
#define TW_ANAG 700     // [20][12] e^{-i 2pi g(n2i-5)/20}, col 11 = 0
#define TW_S2   940     // [12][11] e^{+i 2pi k(mi-5)/12}
#define TW_60   1072    // [60][10] e^{-i 2pi a mp/60}
#define TW_TOT  1672

// constant tensor element counts
#define N_WDS2 (NL1*NB_IN*NM1)     // 11400 f32
#define N_Y1   (NL1*24*NM1)        // 4560 cplx
#define N_D1W  (NL1*NB1*NM1*NM1)   // 72200 f32
#define N_D12W (NL2*NB1*NM2*NM2)   // 14520 f32
#define N_D2   (NL2*144*NM2*NM2)   // 104544 cplx
#define N_D2W  (NL2*NB2*NM2*NM2)   // 8712 f32
#define N_W2N  (NB2)               // 12 f32

// ---------------- fp32 Wigner-d helpers (error ~1e-6 rel; tolerance is 2e-2) ----------------
__device__ __forceinline__ float ipow_f(float x, int e) {
  float r = 1.f;
  for (int i = 0; i < e; ++i) r *= x;
  return r;
}

__device__ float wigdf(const float* lf, int l, int m, int n, float beta) {
  if (m < -l || m > l || n < -l || n > l) return 0.f;
  float cb = cosf(0.5f*beta), sb = sinf(0.5f*beta);
  float pref = 0.5f*(lf[l+m]+lf[l-m]+lf[l+n]+lf[l-n]);
  int s0 = (n-m) > 0 ? (n-m) : 0;
  int s1 = (l+n) < (l-m) ? (l+n) : (l-m);
  float acc = 0.f;
  for (int s = s0; s <= s1; ++s) {
    float lc = pref - (lf[l+n-s]+lf[s]+lf[m-n+s]+lf[l-m-s]);
    float tt = expf(lc) * ipow_f(cb, 2*l+n-m-2*s) * ipow_f(sb, m-n+2*s);
    acc += ((m-n+s) & 1) ? -tt : tt;
  }
  return acc;
}

__device__ __forceinline__ float dh_beta_f(int b, int k) {
  return (float)(PI_D*(2*k+1)/(4.0*b));
}

__device__ float dh_w_f(int b, int k) {
  float beta = dh_beta_f(b, k), s = 0.f;
  for (int j = 0; j < b; ++j) s += sinf((2.f*(float)j+1.f)*beta)/(2.f*(float)j+1.f);
  return (2.f/(float)b)*sinf(beta)*s;
}

// ---------------- constants kernel (fp32, weights+twiddles merged) ----------------
__global__ __launch_bounds__(256) void k_consts(float2* __restrict__ Tg,
                         float* __restrict__ wd_s2, float2* __restrict__ Y1,
                         float* __restrict__ d1w, float* __restrict__ d12w,
                         float2* __restrict__ D2, float* __restrict__ d2w,
                         float* __restrict__ w2n) {
  __shared__ float lf[41];
  __shared__ float dhw30[60], dhw10[20], dhw6[12];
  int t = threadIdx.x;
  if (t < 41) lf[t] = (float)lgamma((double)t + 1.0);
  else if (t < 101) dhw30[t-41] = dh_w_f(30, t-41);
  else if (t < 121) dhw10[t-101] = dh_w_f(10, t-101);
  else if (t < 133) dhw6[t-121] = dh_w_f(6, t-121);
  __syncthreads();

  if (blockIdx.x == 0) {
    for (int i = t; i < TW_TOT; i += 256) {
      float2 v;
      if (i < TW_SYNA) {
        int j = i, n = j/NB1, g = j%NB1;
        int r = (g*(n-9)) % NB1; if (r < 0) r += NB1;
        float s, c; sincosf(2.f*PI_F*(float)r/(float)NB1, &s, &c);
        v = make_float2(c, s);
      } else if (i < TW_ANAA) {
        int j = i - TW_SYNA, a = j/NMP1, mp = j%NMP1;
        int r = (a*mp) % NB1;
        float s, c; sincosf(2.f*PI_F*(float)r/(float)NB1, &s, &c);
        v = make_float2(c, s);
      } else if (i < TW_ANAG) {
        int j = i - TW_ANAA, a = j/NMP2, m2p = j%NMP2;
        int r = (a*m2p) % NB1;
        float s, c; sincosf(2.f*PI_F*(float)r/(float)NB1, &s, &c);
        v = make_float2(c, -s);
      } else if (i < TW_S2) {
        int j = i - TW_ANAG, g = j/12, cI = j%12;
        if (cI == 11) v = make_float2(0.f, 0.f);
        else {
          int r = (g*(cI-5)) % NB1; if (r < 0) r += NB1;
          float s, c; sincosf(2.f*PI_F*(float)r/(float)NB1, &s, &c);
          v = make_float2(c, -s);
        }
      } else if (i < TW_60) {
        int j = i - TW_S2, k = j/NM2, mi = j%NM2;
        int r = (k*(mi-5)) % NB2; if (r < 0) r += NB2;
        float s, c; sincosf(2.f*PI_F*(float)r/(float)NB2, &s, &c);
        v = make_float2(c, s);
      } else {
        int j = i - TW_60, a = j/NMP1, mp = j%NMP1;
        int r = (a*mp) % NB_IN;
        float s, c; sincosf(2.f*PI_F*(float)r/(float)NB_IN, &s, &c);
        v = make_float2(c, -s);
      }
      Tg[i] = v;
    }
  }

  int gid = blockIdx.x*blockDim.x + t;

  if (gid < N_WDS2) {
    int l = gid/(NB_IN*NM1); int r = gid%(NB_IN*NM1); int k = r/NM1; int mi = r%NM1;
    int m = mi - 9;
    wd_s2[gid] = dhw30[k] * wigdf(lf, l, m, 0, dh_beta_f(30,k));
    return;
  }
  gid -= N_WDS2;
  if (gid < N_Y1) {
    int l = gid/(24*NM1); int r = gid%(24*NM1); int p = r/NM1; int mi = r%NM1;
    int m = mi - 9;
    float beta = (float)((double)(p/8 + 1) * PI_D/24.0);
    int pa = p%8;
    int rr = (-(m*pa)) % 8; if (rr < 0) rr += 8;
    float d = wigdf(lf, l, m, 0, beta);
    float s, c; sincosf(2.f*PI_F*(float)rr/8.f, &s, &c);
    Y1[gid] = make_float2(d*c, d*s);
    return;
  }
  gid -= N_Y1;
  if (gid < N_D1W) {
    int l = gid/(NB1*NM1*NM1); int r = gid%(NB1*NM1*NM1); int j = r/(NM1*NM1); int rr = r%(NM1*NM1);
    int m = rr/NM1 - 9, n = rr%NM1 - 9;
    d1w[gid] = (float)(2*l+1) * wigdf(lf, l, m, n, dh_beta_f(10,j));
    return;
  }
  gid -= N_D1W;
  if (gid < N_D12W) {
    int l = gid/(NB1*NM2*NM2); int r = gid%(NB1*NM2*NM2); int j = r/(NM2*NM2); int rr = r%(NM2*NM2);
    int m = rr/NM2 - 5, n = rr%NM2 - 5;
    d12w[gid] = dhw10[j] * wigdf(lf, l, m, n, dh_beta_f(10,j));
    return;
  }
  gid -= N_D12W;
  if (gid < N_D2) {
    int l = gid/(144*NM2*NM2); int r = gid%(144*NM2*NM2); int p = r/(NM2*NM2); int rr = r%(NM2*NM2);
    int m = rr/NM2 - 5, n = rr%NM2 - 5;
    float beta = (float)((double)(p/48 + 1) * PI_D/24.0);
    int pa = (p/6)%8, pg = p%6;
    int rr24 = (-(3*m*pa + 4*n*pg)) % 24; if (rr24 < 0) rr24 += 24;
    float d = wigdf(lf, l, m, n, beta);
    float s, c; sincosf(2.f*PI_F*(float)rr24/24.f, &s, &c);
    D2[gid] = make_float2(d*c, d*s);
    return;
  }
  gid -= N_D2;
  if (gid < N_D2W) {
    int l = gid/(NB2*NM2*NM2); int r = gid%(NB2*NM2*NM2); int j = r/(NM2*NM2); int rr = r%(NM2*NM2);
    int m = rr/NM2 - 5, n = rr%NM2 - 5;
    d2w[gid] = (float)(2*l+1) * wigdf(lf, l, m, n, dh_beta_f(6,j));
    return;
  }
  gid -= N_D2W;
  if (gid < N_W2N) {
    float s = 0.f;
    for (int j = 0; j < NB2; ++j) s += dhw6[j];
    w2n[gid] = dhw6[gid]/s;
    return;
  }
}

// ---------------- K1: azimuthal DFT (60pt, 10 nonneg freqs) + Legendre -> X[10][128][10] ----------------
__global__ __launch_bounds__(256) void k_s2fft(const float* __restrict__ x,
                                               const float* __restrict__ wd_s2,
                                               const float2* __restrict__ Tg,
                                               float2* __restrict__ X) {
  __shared__ float xs[3600];
  __shared__ float2 xf[NB_IN*NMP1];
  __shared__ float2 tw60[NB_IN*NMP1];
  const int z = blockIdx.x, t = threadIdx.x;
  for (int i = t; i < NB_IN*NMP1; i += 256) tw60[i] = Tg[TW_60 + i];
  for (int i = t; i < 3600; i += 256) xs[i] = x[z*3600 + i];
  __syncthreads();
  for (int i = t; i < NB_IN*NMP1; i += 256) {
    int k = i/NMP1, mp = i%NMP1;
    float re = 0.f, im = 0.f;
    const float* xrow = &xs[k*NB_IN];
    for (int a = 0; a < NB_IN; ++a) {
      float v = xrow[a];
      float2 e = tw60[a*NMP1 + mp];
      re = fmaf(v, e.x, re);
      im = fmaf(v, e.y, im);
    }
    xf[i] = make_float2(re, im);
  }
  __syncthreads();
  for (int i = t; i < NL1*NMP1; i += 256) {
    int l = i/NMP1, mp = i%NMP1;
    float re = 0.f, im = 0.f;
    for (int k = 0; k < NB_IN; ++k) {
      float w = wd_s2[(l*NB_IN+k)*NM1 + mp + 9];
      float2 v = xf[k*NMP1 + mp];
      re = fmaf(w, v.x, re); im = fmaf(w, v.y, im);
    }
    X[(l*BATCH + z)*NMP1 + mp] = make_float2(re, im);
  }
}

// ---------------- K2: Psi1[l][o][m] = sum_g psi1[0][o][g] * Y1[l][g][m] ----------------
__global__ void k_psi1(const float* __restrict__ psi1, const float2* __restrict__ Y1,
                       float2* __restrict__ Psi1) {
  int idx = blockIdx.x*blockDim.x + threadIdx.x;
  if (idx >= NL1*F1C*NM1) return;
  int l = idx/(F1C*NM1); int r = idx%(F1C*NM1); int o = r/NM1; int mi = r%NM1;
  float re = 0.f, im = 0.f;
  for (int g = 0; g < 24; ++g) {
    float w = psi1[o*24 + g];
    float2 y = Y1[(l*24+g)*NM1 + mi];
    re = fmaf(w, y.x, re); im = fmaf(w, y.y, im);
  }
  Psi1[idx] = make_float2(re, im);
}

// ---------------- K3: LDS-tiled: B[l][(i*11+k)][(o*11+n)] = sum_g psi2[io][g]*D2[l][g][kn] ----------------
#define P2IO 40
#define P2GC 24
__global__ __launch_bounds__(256) void k_psi2(const float* __restrict__ psi2,
                                              const float2* __restrict__ D2,
                                              float2* __restrict__ Bm) {
  __shared__ __align__(16) float2 Ds[P2GC*122];
  __shared__ float Ws[P2IO*P2GC];
  const int io0 = blockIdx.x*P2IO, l = blockIdx.y, t = threadIdx.x;
  const int tio = t/31, tmn = t%31;
  const int mn0 = tmn*4;
  float2 acc[5][4];
  #pragma unroll
  for (int i = 0; i < 5; ++i)
    #pragma unroll
    for (int j = 0; j < 4; ++j) acc[i][j] = make_float2(0.f, 0.f);

  for (int gc = 0; gc < 144; gc += P2GC) {
    for (int i = t; i < P2GC*121; i += 256) {
      int g = i/121, mn = i%121;
      Ds[g*122 + mn] = D2[(size_t)(l*144 + gc + g)*121 + mn];
    }
    for (int i = t; i < P2IO*P2GC; i += 256) {
      int io = i/P2GC, g = i%P2GC;
      Ws[i] = psi2[(io0 + io)*144 + gc + g];
    }
    __syncthreads();
    if (tio < 8) {
      for (int g = 0; g < P2GC; ++g) {
        float4 d01 = *(const float4*)&Ds[g*122 + mn0];
        float4 d23 = *(const float4*)&Ds[g*122 + mn0 + 2];
        float w0 = Ws[(tio*5 + 0)*P2GC + g];
        float w1 = Ws[(tio*5 + 1)*P2GC + g];
        float w2 = Ws[(tio*5 + 2)*P2GC + g];
        float w3 = Ws[(tio*5 + 3)*P2GC + g];
        float w4 = Ws[(tio*5 + 4)*P2GC + g];
        float dx[4] = {d01.x, d01.z, d23.x, d23.z};
        float dy[4] = {d01.y, d01.w, d23.y, d23.w};
        float wv[5] = {w0, w1, w2, w3, w4};
        #pragma unroll
        for (int i = 0; i < 5; ++i)
          #pragma unroll
          for (int j = 0; j < 4; ++j) {
            acc[i][j].x = fmaf(wv[i], dx[j], acc[i][j].x);
            acc[i][j].y = fmaf(wv[i], dy[j], acc[i][j].y);
          }
      }
    }
    __syncthreads();
  }
  if (tio < 8) {
    #pragma unroll
    for (int i = 0; i < 5; ++i) {
      int io = io0 + tio*5 + i;
      int ii = io/F2C, oo = io%F2C;
      #pragma unroll
      for (int j = 0; j < 4; ++j) {
        int mn = mn0 + j;
        if (mn < 121) {
          int k = mn/NM2, n = mn%NM2;
          Bm[(size_t)l*GEMM_K*GEMM_N + (ii*NM2 + k)*GEMM_N + oo*NM2 + n] = acc[i][j];
        }
      }
    }
  }
}

// ---------------- K4: fused stage 1, Hermitian-halved, single XPp build (r7 structure). ----------------
__global__ __launch_bounds__(256) void k_stage1(const float2* __restrict__ X,
                                                const float2* __restrict__ Psi1,
                                                const float* __restrict__ d1w,
                                                const float* __restrict__ d12w,
                                                const float2* __restrict__ Tg,
                                                float2* __restrict__ Am) {
  __shared__ float2 Xs[NL1*NMP1];                      // 100
  __shared__ float2 Ps[NL1*NM1];                       // 190
  __shared__ __align__(16) float2 XPp[NL1*NMP1*20];    // 2000: X*Ps, padded n-col 19 = 0
  __shared__ __align__(16) float2 Etab[940];
  __shared__ __align__(16) float2 bufA[NBC*200];       // Fh[bb][mp][19] (950) / yb floats (2000f)
  __shared__ __align__(16) float2 bufB[NBC*200];       // Tt[bb][mp][20] (1000) / Uu (600)
  __shared__ float2 yfs[NBC*NMP2*NM2];                 // 330
  __shared__ float2 Fxa[NL2*NMP2*NM2];                 // 396

  const int z = blockIdx.x, o = blockIdx.y, t = threadIdx.x;
  const float2* EsynT = Etab + TW_SYNT;
  const float2* EsynA = Etab + TW_SYNA;
  const float2* EanaA = Etab + TW_ANAA;
  const float2* EanaG = Etab + TW_ANAG;

  for (int i = t; i < 940; i += 256) Etab[i] = Tg[i];
  for (int i = t; i < NL1*NMP1; i += 256) {
    int l = i/NMP1, mp = i%NMP1;
    Xs[i] = X[(l*BATCH + z)*NMP1 + mp];
  }
  for (int i = t; i < NL1*NM1; i += 256) {
    int l = i/NM1, mi = i%NM1;
    Ps[i] = Psi1[(l*F1C + o)*NM1 + mi];
  }
  for (int i = t; i < NL2*NMP2*NM2; i += 256) Fxa[i] = make_float2(0.f, 0.f);
  __syncthreads();

  for (int i = t; i < NL1*NMP1*20; i += 256) {
    int n = i % 20; int r = i/20; int mp = r % NMP1; int l = r/NMP1;
    float2 v = make_float2(0.f, 0.f);
    if (n < NM1) {
      float2 xa = Xs[l*NMP1+mp], pp = Ps[l*NM1+n];
      v = make_float2(xa.x*pp.x - xa.y*pp.y, xa.x*pp.y + xa.y*pp.x);
    }
    XPp[i] = v;
  }
  __syncthreads();

  float2* Fh = bufA;
  float2* Tt = bufB;
  float*  yb = (float*)bufA;
  float2* Uu = bufB;

  for (int c = 0; c < NB1/NBC; ++c) {
    const int b0 = c*NBC;
    // ph1 (quad): Fh[bb][mp][n0..] = sum_l XPp * d1w
    for (int i = t; i < NBC*NMP1*5; i += 256) {
      int q = i % 5; int r = i/5; int mp = r % NMP1; int bb = r/NMP1;
      int n0 = q*4;
      const float* dw = &d1w[(b0+bb)*(NM1*NM1) + (mp+9)*NM1 + n0];
      const float2* xp = &XPp[mp*20 + n0];
      float2 a0 = {0.f,0.f}, a1 = {0.f,0.f}, a2 = {0.f,0.f}, a3 = {0.f,0.f};
      #pragma unroll
      for (int l = 0; l < NL1; ++l) {
        const float* dwl = dw + l*(NB1*NM1*NM1);
        float w0 = dwl[0], w1 = dwl[1], w2 = dwl[2], w3 = dwl[3];
        float4 xa = *(const float4*)&xp[l*(NMP1*20)];
        float4 xb = *(const float4*)&xp[l*(NMP1*20) + 2];
        a0.x = fmaf(w0, xa.x, a0.x); a0.y = fmaf(w0, xa.y, a0.y);
        a1.x = fmaf(w1, xa.z, a1.x); a1.y = fmaf(w1, xa.w, a1.y);
        a2.x = fmaf(w2, xb.x, a2.x); a2.y = fmaf(w2, xb.y, a2.y);
        a3.x = fmaf(w3, xb.z, a3.x); a3.y = fmaf(w3, xb.w, a3.y);
      }
      float2* fr = &Fh[(bb*NMP1 + mp)*NM1 + n0];
      fr[0] = a0; fr[1] = a1; fr[2] = a2;
      if (n0 + 3 < NM1) fr[3] = a3;
    }
    __syncthreads();
    // ph2: Tt[bb][mp][g] = sum_n Fh[bb][mp][n]*EsynT[n][g]
    for (int i = t; i < NBC*NMP1*5; i += 256) {
      int gq = i % 5; int r = i / 5; int mp = r % NMP1; int bb = r / NMP1;
      int g0 = gq*4;
      const float2* fh = &Fh[(bb*NMP1 + mp)*NM1];
      float2 a0 = {0.f,0.f}, a1 = {0.f,0.f}, a2 = {0.f,0.f}, a3 = {0.f,0.f};
      #pragma unroll
      for (int n = 0; n < NM1; ++n) {
        float2 f = fh[n];
        float4 e01 = *(const float4*)&EsynT[n*NB1 + g0];
        float4 e23 = *(const float4*)&EsynT[n*NB1 + g0 + 2];
        a0.x += f.x*e01.x - f.y*e01.y; a0.y += f.x*e01.y + f.y*e01.x;
        a1.x += f.x*e01.z - f.y*e01.w; a1.y += f.x*e01.w + f.y*e01.z;
        a2.x += f.x*e23.x - f.y*e23.y; a2.y += f.x*e23.y + f.y*e23.x;
        a3.x += f.x*e23.z - f.y*e23.w; a3.y += f.x*e23.w + f.y*e23.z;
      }
      float2* tr = &Tt[(bb*NMP1 + mp)*NB1 + g0];
      tr[0] = a0; tr[1] = a1; tr[2] = a2; tr[3] = a3;
    }
    __syncthreads();
    // ph3: y = relu( Tt[mp=0].x + 2*sum Re(EsynA*Tt) )
    for (int i = t; i < NBC*10*5; i += 256) {
      int gq = i % 5; int r = i / 5; int ap = r % 10; int bb = r / 10;
      int a0 = ap*2, g0 = gq*4;
      float4 t01 = *(const float4*)&Tt[(bb*NMP1)*NB1 + g0];
      float4 t23 = *(const float4*)&Tt[(bb*NMP1)*NB1 + g0 + 2];
      float s00=0.f,s01=0.f,s02=0.f,s03=0.f, s10=0.f,s11=0.f,s12=0.f,s13=0.f;
      #pragma unroll
      for (int mp = 1; mp < NMP1; ++mp) {
        float4 u01 = *(const float4*)&Tt[(bb*NMP1 + mp)*NB1 + g0];
        float4 u23 = *(const float4*)&Tt[(bb*NMP1 + mp)*NB1 + g0 + 2];
        float2 e0 = EsynA[a0*NMP1 + mp];
        float2 e1 = EsynA[(a0+1)*NMP1 + mp];
        s00 += e0.x*u01.x - e0.y*u01.y;
        s01 += e0.x*u01.z - e0.y*u01.w;
        s02 += e0.x*u23.x - e0.y*u23.y;
        s03 += e0.x*u23.z - e0.y*u23.w;
        s10 += e1.x*u01.x - e1.y*u01.y;
        s11 += e1.x*u01.z - e1.y*u01.w;
        s12 += e1.x*u23.x - e1.y*u23.y;
        s13 += e1.x*u23.z - e1.y*u23.w;
      }
      float* y0 = &yb[(bb*NB1 + a0)*NB1 + g0];
      float* y1 = &yb[(bb*NB1 + a0 + 1)*NB1 + g0];
      y0[0]=fmaxf(fmaf(2.f,s00,t01.x),0.f); y0[1]=fmaxf(fmaf(2.f,s01,t01.z),0.f);
      y0[2]=fmaxf(fmaf(2.f,s02,t23.x),0.f); y0[3]=fmaxf(fmaf(2.f,s03,t23.z),0.f);
      y1[0]=fmaxf(fmaf(2.f,s10,t01.x),0.f); y1[1]=fmaxf(fmaf(2.f,s11,t01.z),0.f);
      y1[2]=fmaxf(fmaf(2.f,s12,t23.x),0.f); y1[3]=fmaxf(fmaf(2.f,s13,t23.z),0.f);
    }
    __syncthreads();
    // ph4: U[bb][m2p][g] = sum_a y[bb][a][g]*EanaA[a][m2p]
    for (int i = t; i < NBC*NMP2*5; i += 256) {
      int gq = i % 5; int r = i / 5; int m2p = r % NMP2; int bb = r / NMP2;
      int g0 = gq*4;
      float2 u0 = {0.f,0.f}, u1 = {0.f,0.f}, u2 = {0.f,0.f}, u3 = {0.f,0.f};
      #pragma unroll
      for (int aa = 0; aa < NB1; ++aa) {
        float4 y4 = *(const float4*)&yb[(bb*NB1 + aa)*NB1 + g0];
        float2 e = EanaA[aa*NMP2 + m2p];
        u0.x = fmaf(y4.x, e.x, u0.x); u0.y = fmaf(y4.x, e.y, u0.y);
        u1.x = fmaf(y4.y, e.x, u1.x); u1.y = fmaf(y4.y, e.y, u1.y);
        u2.x = fmaf(y4.z, e.x, u2.x); u2.y = fmaf(y4.z, e.y, u2.y);
        u3.x = fmaf(y4.w, e.x, u3.x); u3.y = fmaf(y4.w, e.y, u3.y);
      }
      float2* ur = &Uu[(bb*NMP2 + m2p)*NB1 + g0];
      ur[0] = u0; ur[1] = u1; ur[2] = u2; ur[3] = u3;
    }
    __syncthreads();
    // ph5: yf[bb][m2p][n2] = sum_g U[bb][m2p][g]*EanaG[g][n2]
    for (int i = t; i < NBC*NMP2*6; i += 256) {
      int p = i % 6; int r = i / 6; int m2p = r % NMP2; int bb = r / NMP2;
      int n0 = p*2;
      const float2* ur = &Uu[(bb*NMP2 + m2p)*NB1];
      float2 acc0 = {0.f,0.f}, acc1 = {0.f,0.f};
      #pragma unroll
      for (int g = 0; g < NB1; ++g) {
        float2 u = ur[g];
        float4 e = *(const float4*)&EanaG[g*12 + n0];
        acc0.x += u.x*e.x - u.y*e.y; acc0.y += u.x*e.y + u.y*e.x;
        acc1.x += u.x*e.z - u.y*e.w; acc1.y += u.x*e.w + u.y*e.z;
      }
      yfs[(bb*NMP2 + m2p)*NM2 + n0] = acc0;
      if (n0 + 1 < NM2) yfs[(bb*NMP2 + m2p)*NM2 + n0 + 1] = acc1;
    }
    __syncthreads();
    // ph6: Fxa += sum_bb d12w * yf (m2>=0 only)
    for (int i = t; i < NL2*NMP2*NM2; i += 256) {
      int l2 = i/(NMP2*NM2); int r = i%(NMP2*NM2);
      int mnf = r + 5*NM2;
      float2 acc = Fxa[i];
      #pragma unroll
      for (int bb = 0; bb < NBC; ++bb) {
        float w = d12w[(l2*NB1 + b0 + bb)*(NM2*NM2) + mnf];
        float2 v = yfs[bb*(NMP2*NM2) + r];
        acc.x = fmaf(w, v.x, acc.x); acc.y = fmaf(w, v.y, acc.y);
      }
      Fxa[i] = acc;
    }
    __syncthreads();
  }
  for (int i = t; i < NL2*NMP2*NM2; i += 256) {
    int l2 = i/(NMP2*NM2); int r = i%(NMP2*NM2);
    int mp = r/NM2, n = r%NM2;
    Am[(size_t)l2*GEMM_MH*GEMM_K + (z*NMP2 + mp)*GEMM_K + o*NM2 + n] = Fxa[i];
  }
}

// ---------------- K5: per-l complex GEMM, 64x64 tile, 4x4 regs ----------------
__global__ __launch_bounds__(256) void k_so3mm(const float2* __restrict__ A,
                                               const float2* __restrict__ B,
                                               float2* __restrict__ C) {
  __shared__ float2 As[GM*ASTR];   // [m][k], padded stride (conflict-free)
  __shared__ float2 Bs[GK*GN];     // interleaved [kk][j][tn]
  const int l = blockIdx.z;
  const int row0 = blockIdx.x*GM, col0 = blockIdx.y*GN;
  const int t = threadIdx.x;
  const float2* Ag = A + (size_t)l*GEMM_MH*GEMM_K;
  const float2* Bg = B + (size_t)l*GEMM_K*GEMM_N;
  float2* Cg = C + (size_t)l*GEMM_MH*GEMM_N;
  const int tn = t & 15, tm = t >> 4;   // 16x16 threads, 4x4 cplx each
  float2 acc[4][4];
  #pragma unroll
  for (int i = 0; i < 4; ++i)
    #pragma unroll
    for (int j = 0; j < 4; ++j) acc[i][j] = make_float2(0.f, 0.f);

  for (int k0 = 0; k0 < GEMM_K; k0 += GK) {
    for (int i = t; i < GM*GK; i += 256) {
      int r = i/GK, kk = i%GK;
      As[r*ASTR + kk] = Ag[(size_t)(row0 + r)*GEMM_K + k0 + kk];
    }
    for (int i = t; i < GK*GN; i += 256) {
      int kk = i/GN, cc = i%GN;
      int col = col0 + cc;
      float2 v = (col < GEMM_N) ? Bg[(size_t)(k0 + kk)*GEMM_N + col] : make_float2(0.f, 0.f);
      Bs[(kk*4 + (cc & 3))*16 + (cc >> 2)] = v;   // [kk][j][tn]
    }
    __syncthreads();
    #pragma unroll
    for (int kk = 0; kk < GK; ++kk) {
      float2 a[4], b[4];
      #pragma unroll
      for (int i = 0; i < 4; ++i) a[i] = As[(tm*4 + i)*ASTR + kk];
      #pragma unroll
      for (int j = 0; j < 4; ++j) b[j] = Bs[(kk*4 + j)*16 + tn];
      #pragma unroll
      for (int i = 0; i < 4; ++i)
        #pragma unroll
        for (int j = 0; j < 4; ++j) {
          acc[i][j].x = fmaf(a[i].x, b[j].x, acc[i][j].x);
          acc[i][j].x = fmaf(-a[i].y, b[j].y, acc[i][j].x);
          acc[i][j].y = fmaf(a[i].x, b[j].y, acc[i][j].y);
          acc[i][j].y = fmaf(a[i].y, b[j].x, acc[i][j].y);
        }
    }
    __syncthreads();
  }
  #pragma unroll
  for (int i = 0; i < 4; ++i) {
    int r = row0 + tm*4 + i;
    int c0 = col0 + tn*4;
    if (c0 < GEMM_N) {   // GEMM_N%4==0 so all 4 cols valid together
      float4 v0 = make_float4(acc[i][0].x, acc[i][0].y, acc[i][1].x, acc[i][1].y);
      float4 v1 = make_float4(acc[i][2].x, acc[i][2].y, acc[i][3].x, acc[i][3].y);
      *(float4*)&Cg[(size_t)r*GEMM_N + c0] = v0;
      *(float4*)&Cg[(size_t)r*GEMM_N + c0 + 2] = v1;
    }
  }
}

// ---------------- K6: fused stage 2 tail. Hermitian C reconstruction; shfl reduce. ----------------
__global__ __launch_bounds__(256) void k_stage2(const float2* __restrict__ C,
                                                const float* __restrict__ d2w,
                                                const float* __restrict__ w2n,
                                                const float2* __restrict__ Tg,
                                                float* __restrict__ feat) {
  __shared__ float2 Fos[NL2*NM2*NM2];
  __shared__ float2 Fh2[NB2*NM2*NM2];
  __shared__ float2 T2[NB2*NB2*NM2];
  __shared__ float2 Esyn2[NB2*NM2];
  __shared__ float w2s[NB2];
  __shared__ float wred[4];
  const int z = blockIdx.x, o = blockIdx.y, t = threadIdx.x;
  for (int i = t; i < NB2*NM2; i += 256) Esyn2[i] = Tg[TW_S2 + i];
  if (t < NB2) w2s[t] = w2n[t];
  for (int i = t; i < NL2*NM2*NM2; i += 256) {
    int l = i/(NM2*NM2); int mn = i%(NM2*NM2);
    int m = mn/NM2, n = mn%NM2;
    float2 v;
    if (m >= 5) {
      v = C[(size_t)l*GEMM_MH*GEMM_N + (size_t)(z*NMP2 + m - 5)*GEMM_N + o*NM2 + n];
    } else {
      float2 cc = C[(size_t)l*GEMM_MH*GEMM_N + (size_t)(z*NMP2 + 5 - m)*GEMM_N + o*NM2 + (10 - n)];
      float s = ((m - n) & 1) ? -1.f : 1.f;
      v = make_float2(s*cc.x, -s*cc.y);
    }
    Fos[i] = v;
  }
  __syncthreads();
  for (int i = t; i < NB2*NM2*NM2; i += 256) {
    int b = i/(NM2*NM2); int mn = i%(NM2*NM2);
    float re = 0.f, im = 0.f;
    #pragma unroll
    for (int l = 0; l < NL2; ++l) {
      float w = d2w[(l*NB2 + b)*(NM2*NM2) + mn];
      float2 v = Fos[l*(NM2*NM2) + mn];
      re = fmaf(w, v.x, re); im = fmaf(w, v.y, im);
    }
    Fh2[i] = make_float2(re, im);
  }
  __syncthreads();
  for (int i = t; i < NB2*NB2*NM2; i += 256) {
    int ni = i % NM2; int r = i / NM2; int aa = r % NB2; int b = r / NB2;
    const float2* fh = &Fh2[b*(NM2*NM2) + ni];
    float re = 0.f, im = 0.f;
    #pragma unroll
    for (int mi = 0; mi < NM2; ++mi) {
      float2 f = fh[mi*NM2]; float2 e = Esyn2[aa*NM2+mi];
      re += e.x*f.x - e.y*f.y;
      im += e.x*f.y + e.y*f.x;
    }
    T2[i] = make_float2(re, im);
  }
  __syncthreads();
  float accT = 0.f;
  for (int i = t; i < NB2*NB2*NB2; i += 256) {
    int g = i % NB2; int r = i / NB2; int aa = r % NB2; int b = r / NB2;
    const float2* trow = &T2[(b*NB2 + aa)*NM2];
    float v = 0.f;
    #pragma unroll
    for (int ni = 0; ni < NM2; ++ni) {
      float2 tv = trow[ni]; float2 e = Esyn2[g*NM2+ni];
      v += e.x*tv.x - e.y*tv.y;
    }
    accT += w2s[b]*fmaxf(v, 0.f);
  }
  #pragma unroll
  for (int off = 32; off > 0; off >>= 1) accT += __shfl_down(accT, off);
  if ((t & 63) == 0) wred[t >> 6] = accT;
  __syncthreads();
  if (t == 0) feat[z*F2C + o] = (wred[0]+wred[1]+wred[2]+wred[3]) / (float)(NB2*NB2);
}

// ---------------- K7: linear head ----------------
__global__ void k_head(const float* __restrict__ feat, const float* __restrict__ w_lin,
                       const float* __restrict__ b_lin, float* __restrict__ out) {
  int idx = blockIdx.x*blockDim.x + threadIdx.x;
  if (idx >= BATCH*10) return;
  int z = idx/10, f = idx%10;
  float acc = b_lin[f];
  for (int o = 0; o < F2C; ++o) acc = fmaf(feat[z*F2C + o], w_lin[f*F2C + o], acc);
  out[idx] = acc;
}

extern "C" void kernel_launch(void* const* d_in, const int* in_sizes, int n_in,
                              void* d_out, int out_size, void* d_ws, size_t ws_size,
                              hipStream_t stream) {
  const float* x     = (const float*)d_in[0];
  const float* psi1  = (const float*)d_in[1];
  const float* psi2  = (const float*)d_in[2];
  const float* w_lin = (const float*)d_in[3];
  const float* b_lin = (const float*)d_in[4];
  float* out = (float*)d_out;
  float* ws  = (float*)d_ws;

  size_t off = 0;
  auto alloc = [&](size_t nfloats) { size_t o = off; off += (nfloats + 15) & ~(size_t)15; return o; };
  float2* Tglob = (float2*)(ws + alloc(2*TW_TOT));
  float*  wd_s2 = ws + alloc(N_WDS2);
  float2* Y1    = (float2*)(ws + alloc(2*(size_t)N_Y1));
  float*  d1w   = ws + alloc(N_D1W);
  float*  d12w  = ws + alloc(N_D12W);
  float2* D2    = (float2*)(ws + alloc(2*(size_t)N_D2));
  float*  d2w   = ws + alloc(N_D2W);
  float*  w2n   = ws + alloc(N_W2N);
  float2* X     = (float2*)(ws + alloc(2*(size_t)NL1*BATCH*NMP1));
  float2* Psi1p = (float2*)(ws + alloc(2*(size_t)NL1*F1C*NM1));
  float2* Bmat  = (float2*)(ws + alloc(2*(size_t)NL2*GEMM_K*GEMM_N));
  float2* Amat  = (float2*)(ws + alloc(2*(size_t)NL2*GEMM_MH*GEMM_K));
  float2* Cmat  = (float2*)(ws + alloc(2*(size_t)NL2*GEMM_MH*GEMM_N));
  float*  featp = ws + alloc((size_t)BATCH*F2C);
  if (ws_size < off*sizeof(float)) return;

  const int total_c = N_WDS2 + N_Y1 + N_D1W + N_D12W + N_D2 + N_D2W + N_W2N;
  k_consts<<<(total_c + 255)/256, 256, 0, stream>>>(Tglob, wd_s2, Y1, d1w, d12w, D2, d2w, w2n);
  k_s2fft<<<BATCH, 256, 0, stream>>>(x, wd_s2, Tglob, X);
  k_psi1<<<(NL1*F1C*NM1 + 255)/256, 256, 0, stream>>>(psi1, Y1, Psi1p);
  k_psi2<<<dim3(F1C*F2C/P2IO, NL2), 256, 0, stream>>>(psi2, D2, Bmat);
  k_stage1<<<dim3(BATCH, F1C), 256, 0, stream>>>(X, Psi1p, d1w, d12w, Tglob, Amat);
  k_so3mm<<<dim3(GEMM_MH/GM, (GEMM_N + GN - 1)/GN, NL2), 256, 0, stream>>>(Amat, Bmat, Cmat);
  k_stage2<<<dim3(BATCH, F2C), 256, 0, stream>>>(Cmat, d2w, w2n, Tglob, featp);
  k_head<<<(BATCH*10 + 255)/256, 256, 0, stream>>>(featp, w_lin, b_lin, out);
}